// Round 7
// baseline (56091.620 us; speedup 1.0000x reference)
//
#include <hip/hip_runtime.h>
#include <math.h>
#include <stdint.h>

// ---------------------------------------------------------------------------
// DualSpectralDiffusion: faithful replication of the JAX reference.
//  - f64 LAPACK-style eigh (multi-block coalesced sytd2 + D&C w/ slaed2
//    deflation mimicry), sign-faithful vs numpy ssyevd
//  - exact threefry2x32 / jax.random replication (PARTITIONABLE stream)
//  - f32 diffusion loop, noise threefry fused into the update-GEMM epilogue
// ---------------------------------------------------------------------------

#define NT 256
#define SZF 131072          // 512*256 floats per (b) tensor
#define MATSZ 262144        // 512*512
#define NB 8                // sytd2 blocks per matrix (small => cheap barrier)
#define NSYB (4*NB)         // total sytd2 blocks

// ----------------------------- threefry ------------------------------------
__host__ __device__ static inline unsigned rotl32(unsigned v, int r){ return (v<<r)|(v>>(32-r)); }

__host__ __device__ static inline void tf2x32(unsigned k0, unsigned k1,
                                              unsigned x0, unsigned x1,
                                              unsigned* o0, unsigned* o1){
  unsigned ks2 = k0 ^ k1 ^ 0x1BD11BDAu;
  x0 += k0; x1 += k1;
#define TF4(r0,r1,r2,r3) \
  x0 += x1; x1 = rotl32(x1,r0); x1 ^= x0; \
  x0 += x1; x1 = rotl32(x1,r1); x1 ^= x0; \
  x0 += x1; x1 = rotl32(x1,r2); x1 ^= x0; \
  x0 += x1; x1 = rotl32(x1,r3); x1 ^= x0;
  TF4(13,15,26,6)  x0 += k1;  x1 += ks2 + 1u;
  TF4(17,29,16,24) x0 += ks2; x1 += k0 + 2u;
  TF4(13,15,26,6)  x0 += k0;  x1 += k1 + 3u;
  TF4(17,29,16,24) x0 += k1;  x1 += ks2 + 4u;
  TF4(13,15,26,6)  x0 += ks2; x1 += k0 + 5u;
#undef TF4
  *o0 = x0; *o1 = x1;
}

// XLA ErfInv f32 polynomial; matches lax.erf_inv expansion.
__device__ static inline float erfinv_xla(float x){
  float w = -log1pf(-x*x);
  float p;
  if (w < 5.0f){
    w -= 2.5f;
    p = 2.81022636e-08f;
    p = fmaf(p, w, 3.43273939e-07f);
    p = fmaf(p, w, -3.5233877e-06f);
    p = fmaf(p, w, -4.39150654e-06f);
    p = fmaf(p, w, 0.00021858087f);
    p = fmaf(p, w, -0.00125372503f);
    p = fmaf(p, w, -0.00417768164f);
    p = fmaf(p, w, 0.246640727f);
    p = fmaf(p, w, 1.50140941f);
  } else {
    w = sqrtf(w) - 3.0f;
    p = -0.000200214257f;
    p = fmaf(p, w, 0.000100950558f);
    p = fmaf(p, w, 0.00134934322f);
    p = fmaf(p, w, -0.00367342844f);
    p = fmaf(p, w, 0.00573950773f);
    p = fmaf(p, w, -0.0076224613f);
    p = fmaf(p, w, 0.00943887047f);
    p = fmaf(p, w, 1.00167406f);
    p = fmaf(p, w, 2.83297682f);
  }
  return p*x;
}

__device__ static inline float bits_to_normal(unsigned bits){
  const float MINV = -0.99999994f;   // nextafter(-1,0) in f32
  float f = __uint_as_float((bits >> 9) | 0x3f800000u) - 1.0f;
  float u = fmaxf(MINV, fmaf(f, 2.0f, MINV));
  return 1.41421356237309515f * erfinv_xla(u);
}

// ------------------------------- eigh --------------------------------------
// smalls layout (doubles): d[s*512], e[2048+s*512], tau[4096+s*512],
// org[6144+s], rot at 8192+(s*32+merge)*1024 (up to 139264),
// acc ping/pong at 139264 (+2048), col ping/pong at 143360 (+2048),
// barrier counters (unsigned) at double-index 147456.

__global__ void k_prep(double* A64, const float* G){
  size_t i = (size_t)blockIdx.x*256 + threadIdx.x;   // < 4*262144
  A64[i] = (double)G[i];
}

// per-matrix sense-reversing barrier: NB blocks of matrix s participate.
// counters per matrix are cache-line separated (s*32 uints = 128 B apart).
__device__ __forceinline__ void gbar(unsigned* bar, int s){
  __syncthreads();
  if (threadIdx.x == 0){
    __threadfence();
    unsigned* cnt = bar + s*32;
    unsigned* gen = bar + s*32 + 16;
    unsigned g0 = __hip_atomic_load(gen, __ATOMIC_RELAXED, __HIP_MEMORY_SCOPE_AGENT);
    unsigned a = __hip_atomic_fetch_add(cnt, 1u, __ATOMIC_ACQ_REL, __HIP_MEMORY_SCOPE_AGENT);
    if (a == NB-1u){
      __hip_atomic_store(cnt, 0u, __ATOMIC_RELAXED, __HIP_MEMORY_SCOPE_AGENT);
      __hip_atomic_fetch_add(gen, 1u, __ATOMIC_RELEASE, __HIP_MEMORY_SCOPE_AGENT);
    } else {
      while (__hip_atomic_load(gen, __ATOMIC_ACQUIRE, __HIP_MEMORY_SCOPE_AGENT) == g0){
        __builtin_amdgcn_s_sleep(4);
      }
    }
  }
  __syncthreads();
}

// Multi-block Householder tridiagonalization: 4 matrices x NB blocks.
// Row r of A owned by block g = r%NB (A rows are block-private!).
// Cross-block state: acc (matvec), col (next column), via ping-pong buffers.
// One per-matrix barrier per column. Arithmetic identical to verified r5/r6.
__global__ __launch_bounds__(256) void k_sytd2_mb(double* Ab, double* Vb,
                                                  double* smalls, unsigned* bar){
  int blk = blockIdx.x;
  int s = blk / NB, g = blk % NB;
  int t = threadIdx.x, wave = t >> 6, lane = t & 63;
  double* A = Ab + (size_t)s*MATSZ;
  double* V = Vb + (size_t)s*MATSZ;
  double* d  = smalls + (size_t)s*512;
  double* e  = smalls + 2048 + (size_t)s*512;
  double* tu = smalls + 4096 + (size_t)s*512;
  double* acc0 = smalls + 139264 + (size_t)s*512;
  double* acc1 = acc0 + 2048;
  double* col0 = smalls + 143360 + (size_t)s*512;
  double* col1 = col0 + 2048;

  __shared__ double vv[512], wv[512], v2[512], col2[512], acc[512];
  __shared__ double red[4];
  __shared__ double bc[4];

  // ---------- init: reflector 0 (replicated) ----------
  for (int r=t; r<512; r+=256) col2[r] = (r>=1) ? A[(size_t)r*512] : 0.0;
  __syncthreads();
  {
    double part = 0.0;
    for (int r=2+t; r<512; r+=256) part += col2[r]*col2[r];
    #pragma unroll
    for (int off=32; off; off>>=1) part += __shfl_down(part, off, 64);
    if (lane==0) red[wave]=part;
    __syncthreads();
    if (t==0){
      double xsq = red[0]+red[1]+red[2]+red[3];
      double alpha = col2[1];
      double beta,tv,scal;
      if (xsq == 0.0){ beta=alpha; tv=0.0; scal=0.0; }
      else {
        beta = -copysign(sqrt(alpha*alpha + xsq), alpha);   // LAPACK slarfg
        tv = (beta - alpha)/beta;
        scal = 1.0/(alpha - beta);
      }
      if (g==0){ e[0]=beta; tu[0]=tv; }
      bc[0]=tv; bc[1]=scal;
    }
  }
  __syncthreads();
  double tauv = bc[0];
  {
    double scal = bc[1];
    for (int r=t; r<512; r+=256){
      double v = 0.0;
      if (r==1) v = 1.0;
      else if (r>1) v = (tauv==0.0) ? 0.0 : col2[r]*scal;
      vv[r]=v;
    }
  }
  __syncthreads();
  if (g==0){
    for (int r=1+t; r<512; r+=256) V[r] = vv[r];
    for (int r=1+t; r<512; r+=256) col0[r] = A[(size_t)r*512 + 1];
  }
  // init matvec on owned rows (r>=1, r%NB==g) -> acc0
  {
    int r0 = 1 + ((g - 1) & (NB-1));
    for (int r = r0 + NB*wave; r < 512; r += 4*NB){
      const double* Ar = A + (size_t)r*512;
      double p = 0.0;
      for (int c=lane; c<512; c+=64) p += Ar[c]*vv[c];
      #pragma unroll
      for (int off=32; off; off>>=1) p += __shfl_down(p, off, 64);
      if (lane==0) acc0[r] = p;
    }
  }

  // ---------- main loop: iteration i applies reflector i, derives i+1 ----------
  for (int i=0; i<510; i++){
    gbar(bar, s);
    int lo=i+1, lo2=i+2;
    double* accR = (i&1) ? acc1 : acc0;
    double* colR = (i&1) ? col1 : col0;
    double* accW = (i&1) ? acc0 : acc1;
    double* colW = (i&1) ? col0 : col1;
    for (int r=lo+t; r<512; r+=256){ acc[r]=accR[r]; col2[r]=colR[r]; }
    __syncthreads();
    double part = 0.0;
    for (int r=lo+t; r<512; r+=256){ double wr = tauv*acc[r]; wv[r]=wr; part += wr*vv[r]; }
    #pragma unroll
    for (int off=32; off; off>>=1) part += __shfl_down(part, off, 64);
    if (lane==0) red[wave]=part;
    __syncthreads();
    if (t==0){ double dot=red[0]+red[1]+red[2]+red[3]; bc[2] = -0.5*tauv*dot; }
    __syncthreads();
    {
      double alpha2 = bc[2];
      for (int r=lo+t; r<512; r+=256) wv[r] += alpha2*vv[r];
    }
    __syncthreads();
    {
      double wlo = wv[lo], vlo = vv[lo];
      for (int r=lo+t; r<512; r+=256) col2[r] = col2[r] - vv[r]*wlo - wv[r]*vlo;
    }
    __syncthreads();
    part = 0.0;
    for (int r=lo2+1+t; r<512; r+=256) part += col2[r]*col2[r];
    #pragma unroll
    for (int off=32; off; off>>=1) part += __shfl_down(part, off, 64);
    if (lane==0) red[wave]=part;
    __syncthreads();
    if (t==0){
      double xsq = red[0]+red[1]+red[2]+red[3];
      double alpha = col2[lo2];
      double beta,tau2,scal2;
      if (xsq == 0.0){ beta=alpha; tau2=0.0; scal2=0.0; }
      else {
        beta = -copysign(sqrt(alpha*alpha + xsq), alpha);
        tau2 = (beta - alpha)/beta;
        scal2 = 1.0/(alpha - beta);
      }
      if (g==0){ e[lo]=beta; tu[lo]=tau2; }
      bc[0]=tau2; bc[1]=scal2;
    }
    __syncthreads();
    double tau2 = bc[0];
    {
      double scal2 = bc[1];
      for (int r=t; r<512; r+=256){
        double v = 0.0;
        if (r==lo2) v = 1.0;
        else if (r>lo2) v = (tau2==0.0) ? 0.0 : col2[r]*scal2;
        v2[r]=v;
      }
    }
    __syncthreads();
    if (g==0){
      for (int r=lo2+t; r<512; r+=256) V[(size_t)lo*512 + r] = v2[r];
    }
    // fused sweep over owned rows: A -= v w^T + w v^T ; acc = A_new * v2;
    // export column lo2 into colW.
    {
      double vvc[8], wvc[8], v2c[8];
      #pragma unroll
      for (int j=0;j<8;j++){
        int c = lo + lane + 64*j;
        bool ok = c < 512;
        vvc[j] = ok ? vv[c] : 0.0;
        wvc[j] = ok ? wv[c] : 0.0;
        v2c[j] = ok ? v2[c] : 0.0;
      }
      int r0 = lo + ((g - lo) & (NB-1));
      for (int r = r0 + NB*wave; r < 512; r += 4*NB){
        double* Ar = A + (size_t)r*512;
        double vr = vv[r], wr = wv[r];
        double p = 0.0;
        #pragma unroll
        for (int j=0;j<8;j++){
          int c = lo + lane + 64*j;
          if (c < 512){
            double an = Ar[c] - vr*wvc[j] - wr*vvc[j];
            Ar[c] = an;
            p += an * v2c[j];
            if (c == lo2) colW[r] = an;
          }
        }
        #pragma unroll
        for (int off=32; off; off>>=1) p += __shfl_down(p, off, 64);
        if (lane==0) accW[r] = p;
      }
    }
    __syncthreads();
    for (int r=t; r<512; r+=256) vv[r] = v2[r];
    tauv = tau2;
    __syncthreads();
  }
  // diag from owned rows (self-written, no barrier needed)
  if (lane == 0){
    for (int r = g + NB*wave; r < 512; r += 4*NB)
      d[r] = A[(size_t)r*512 + r];
  }
}

// sstedc-style pre-scale: org = max(|d|,|e|); d,e /= org
__global__ void k_scale(double* smalls){
  int s = blockIdx.x, t = threadIdx.x;
  double* d = smalls + (size_t)s*512;
  double* e = smalls + 2048 + (size_t)s*512;
  __shared__ double red[256];
  double m = 0.0;
  for (int i=t;i<512;i+=256) m = fmax(m, fabs(d[i]));
  for (int i=t;i<511;i+=256) m = fmax(m, fabs(e[i]));
  red[t]=m; __syncthreads();
  for (int off=128; off; off>>=1){ if (t<off) red[t]=fmax(red[t],red[t+off]); __syncthreads(); }
  double org = red[0]; if (org == 0.0) org = 1.0;
  if (t==0) smalls[6144+s] = org;
  double inv = 1.0/org;
  __syncthreads();
  for (int i=t;i<512;i+=256) d[i] *= inv;
  for (int i=t;i<511;i+=256) e[i] *= inv;
}

__global__ void k_tear(double* smalls){
  int t = threadIdx.x;           // 128 threads: s = t>>5, k = (t&31)+1
  int s = t >> 5, k = (t & 31) + 1;
  if (k <= 31){
    double* d = smalls + (size_t)s*512;
    double* e = smalls + 2048 + (size_t)s*512;
    double ae = fabs(e[16*k - 1]);
    d[16*k - 1] -= ae;
    d[16*k]     -= ae;
  }
}

// 32 leaves of 16 per matrix; 8 leaves per block, threads 0..7 active
__global__ __launch_bounds__(64) void k_leaves(double* smalls, double* Zb){
  __shared__ double LA[8][256];
  __shared__ double LQ[8][256];
  int t = threadIdx.x;
  if (t < 8){
    int bid = blockIdx.x;        // 0..15
    int s = bid >> 2;
    int leaf = (bid & 3)*8 + t;  // 0..31
    double* d = smalls + (size_t)s*512;
    double* e = smalls + 2048 + (size_t)s*512;
    double* Z = Zb + (size_t)s*MATSZ;
    int base = leaf*16;
    double* A = LA[t]; double* Q = LQ[t];
    for (int i=0;i<256;i++){ A[i]=0.0; Q[i]=0.0; }
    for (int i=0;i<16;i++){ A[i*17] = d[base+i]; Q[i*17] = 1.0; }
    for (int i=0;i<15;i++){ double ee = e[base+i]; A[i*16+i+1] = ee; A[(i+1)*16+i] = ee; }
    double nrm = 0.0;
    for (int i=0;i<256;i++) nrm += A[i]*A[i];
    double thr = nrm*1e-30 + 1e-300;
    for (int sweep=0; sweep<60; sweep++){
      double off = 0.0;
      for (int p=0;p<15;p++) for (int q=p+1;q<16;q++){
        double apq = A[p*16+q];
        off += 2.0*apq*apq;
        if (apq == 0.0) continue;
        double theta = 0.5*(A[q*17]-A[p*17])/apq;
        double tt;
        if (fabs(theta) > 1e18) tt = 0.5/theta;
        else tt = copysign(1.0, theta)/(fabs(theta)+sqrt(theta*theta+1.0));
        double cc = 1.0/sqrt(tt*tt+1.0), ss = tt*cc;
        for (int k=0;k<16;k++){
          double akp=A[k*16+p], akq=A[k*16+q];
          A[k*16+p] = cc*akp - ss*akq;
          A[k*16+q] = ss*akp + cc*akq;
        }
        for (int k=0;k<16;k++){
          double apk=A[p*16+k], aqk=A[q*16+k];
          A[p*16+k] = cc*apk - ss*aqk;
          A[q*16+k] = ss*apk + cc*aqk;
        }
        for (int k=0;k<16;k++){
          double qkp=Q[k*16+p], qkq=Q[k*16+q];
          Q[k*16+p] = cc*qkp - ss*qkq;
          Q[k*16+q] = ss*qkp + cc*qkq;
        }
      }
      if (off < thr) break;
    }
    for (int i=0;i<16;i++){
      int mi=i;
      for (int j=i+1;j<16;j++) if (A[j*17] < A[mi*17]) mi=j;
      if (mi!=i){
        double tmp=A[i*17]; A[i*17]=A[mi*17]; A[mi*17]=tmp;
        for (int k=0;k<16;k++){ double q1=Q[k*16+i]; Q[k*16+i]=Q[k*16+mi]; Q[k*16+mi]=q1; }
      }
    }
    for (int i=0;i<16;i++) d[base+i] = A[i*17];
    for (int r=0;r<16;r++)
      for (int c=0;c<16;c++)
        Z[(size_t)(base+r)*512 + base + c] = Q[r*16+c];
  }
}

// one block per merge: LAPACK slaed2 deflation + secular solve + Gu-Eisenstat
__global__ __launch_bounds__(256) void k_secular(double* smalls, const double* Zsrc_b,
                                                 double* Sm_b, int level){
  const double EPS32 = 5.9604644775390625e-8;   // SLAMCH('E') for f32
  const double ISQ2  = 0.70710678118654752440;
  int s = blockIdx.x;
  int hh = 16 << level, n = hh << 1;
  int merge = blockIdx.y, start = merge*n;
  double* d = smalls + (size_t)s*512;
  const double* e = smalls + 2048 + (size_t)s*512;
  const double* Z = Zsrc_b + (size_t)s*MATSZ;
  double* Sm = Sm_b + (size_t)s*MATSZ;
  double* rotg = smalls + 8192 + (size_t)(s*32+merge)*1024;
  __shared__ double ds[512], zl[512], dk[512], zk[512], tauk[512], zh[512], outlam[512];
  __shared__ double rc[256], rs[256];
  __shared__ double red[256];
  __shared__ double sv[2];
  __shared__ int perm[512], kidx[512], Ksk[512], didx[512], outid[512];
  __shared__ int rp[256], rq[256];
  __shared__ int counts[3];
  int t = threadIdx.x;
  if (t == 0){
    int i=0, j=hh, k=0;
    while (i < hh && j < n){
      if (d[start+i] <= d[start+j]) perm[k++]=i++; else perm[k++]=j++;
    }
    while (i < hh) perm[k++]=i++;
    while (j < n)  perm[k++]=j++;
  }
  __syncthreads();
  double eb = e[start+hh-1];
  double rho = 2.0*fabs(eb);
  double sgn = (eb < 0.0) ? -1.0 : 1.0;
  for (int i=t; i<n; i+=NT){
    int p = perm[i];
    ds[i] = d[start+p];
    double zr = (p < hh) ? Z[(size_t)(start+hh-1)*512 + start + p]
                         : sgn * Z[(size_t)(start+hh)*512 + start + p];
    zl[i] = zr * ISQ2;
  }
  __syncthreads();
  double m = 0.0;
  for (int i=t;i<n;i+=NT) m = fmax(m, fabs(zl[i]));
  red[t]=m; __syncthreads();
  for (int off=128; off; off>>=1){ if (t<off) red[t]=fmax(red[t],red[t+off]); __syncthreads(); }
  if (t==0) sv[0] = red[0];
  __syncthreads();
  m = 0.0;
  for (int i=t;i<n;i+=NT) m = fmax(m, fabs(ds[i]));
  red[t]=m; __syncthreads();
  for (int off=128; off; off>>=1){ if (t<off) red[t]=fmax(red[t],red[t+off]); __syncthreads(); }
  if (t==0) sv[1] = red[0];
  __syncthreads();
  double zmaxv = sv[0];
  double tol = 8.0*EPS32*fmax(sv[1], zmaxv);

  if (t == 0){
    int K=0, nd=0, nrot=0;
    if (rho*zmaxv <= tol){
      for (int j=0;j<n;j++) didx[nd++]=j;
    } else {
      int pj = -1;
      for (int j=0;j<n;j++){
        if (rho*fabs(zl[j]) <= tol){
          didx[nd++]=j;
        } else if (pj < 0){
          pj = j;
        } else {
          double s_ = zl[pj], c_ = zl[j];
          double tau2 = sqrt(c_*c_ + s_*s_);
          double tdf = ds[j] - ds[pj];
          double cc = c_/tau2, sr = -s_/tau2;
          if (fabs(tdf*cc*sr) <= tol){
            zl[j] = tau2; zl[pj] = 0.0;
            if (nrot < 256){
              rp[nrot]=perm[pj]; rq[nrot]=perm[j]; rc[nrot]=cc; rs[nrot]=sr; nrot++;
            }
            double tn = ds[pj]*cc*cc + ds[j]*sr*sr;
            ds[j]  = ds[pj]*sr*sr + ds[j]*cc*cc;
            ds[pj] = tn;
            didx[nd++] = pj;
            pj = j;
          } else {
            kidx[K++] = pj;
            pj = j;
          }
        }
      }
      if (pj >= 0) kidx[K++] = pj;
    }
    for (int a=1;a<nd;a++){
      int v = didx[a]; double dv = ds[v]; int b = a-1;
      while (b >= 0 && ds[didx[b]] > dv){ didx[b+1]=didx[b]; b--; }
      didx[b+1] = v;
    }
    counts[0]=K; counts[1]=nd; counts[2]=nrot;
    rotg[0] = (double)nrot;
    for (int i=0;i<nrot;i++){
      rotg[1+4*i]=(double)rp[i]; rotg[2+4*i]=(double)rq[i];
      rotg[3+4*i]=rc[i]; rotg[4+4*i]=rs[i];
    }
  }
  __syncthreads();
  int K = counts[0], nd = counts[1];

  for (int k=t; k<K; k+=NT){ dk[k]=ds[kidx[k]]; zk[k]=zl[kidx[k]]; }
  __syncthreads();

  for (int j2=t; j2<K; j2+=NT){
    int Kb; double lo, hi;
    if (j2 < K-1){
      double mid = 0.5*(dk[j2+1]-dk[j2]);
      double gg = 1.0;
      for (int i=0;i<K;i++){ double dif=(dk[i]-dk[j2])-mid; gg += rho*zk[i]*zk[i]/dif; }
      if (gg >= 0.0){ Kb=j2;   lo=0.0;  hi=mid; }
      else          { Kb=j2+1; lo=-mid; hi=0.0; }
    } else {
      double sz=0.0;
      for (int i=0;i<K;i++) sz += zk[i]*zk[i];
      Kb=K-1; lo=0.0; hi=rho*sz + 1e-300;
    }
    double dK = dk[Kb];
    for (int it=0; it<72; it++){
      double mid = 0.5*(lo+hi);
      if (mid==lo || mid==hi) break;
      double gg = 1.0;
      for (int i=0;i<K;i++){ double dif=(dk[i]-dK)-mid; gg += rho*zk[i]*zk[i]/dif; }
      if (gg < 0.0) lo=mid; else hi=mid;
    }
    Ksk[j2]=Kb; tauk[j2]=0.5*(lo+hi);
  }
  __syncthreads();
  for (int i=t; i<K; i+=NT){
    double P = (Ksk[i]==i) ? tauk[i] : (dk[Ksk[i]]-dk[i]) + tauk[i];
    for (int j=0;j<K;j++){
      if (j==i) continue;
      double num = (dk[Ksk[j]]-dk[i]) + tauk[j];
      double den = dk[j]-dk[i];
      P *= num/den;
    }
    zh[i] = copysign(sqrt(fabs(P/rho)), zk[i]);
  }
  __syncthreads();
  if (t == 0){
    int a=0, b=0;
    for (int j=0;j<n;j++){
      double la = (a<K)  ? (dk[Ksk[a]]+tauk[a]) : 1e300;
      double lb = (b<nd) ? ds[didx[b]]          : 1e300;
      if (la <= lb){ outid[j]=a;     outlam[j]=la; a++; }
      else         { outid[j]=512+b; outlam[j]=lb; b++; }
    }
  }
  __syncthreads();
  for (int j=t; j<n; j+=NT) d[start+j] = outlam[j];
  for (int j=t; j<n; j+=NT){
    double* col = Sm + (size_t)(start+j)*512;
    int id = outid[j];
    for (int i=0;i<n;i++) col[i]=0.0;
    if (id >= 512){
      col[perm[didx[id-512]]] = 1.0;
    } else {
      int k = id;
      double ss_ = 0.0;
      for (int i=0;i<K;i++){
        double dif = (dk[i]-dk[Ksk[k]]) - tauk[k];
        if (dif == 0.0) dif = 1e-300;
        double v = zh[i]/dif;
        col[perm[kidx[i]]] = v; ss_ += v*v;
      }
      double inv = 1.0/sqrt(ss_);
      for (int i=0;i<K;i++) col[perm[kidx[i]]] *= inv;
    }
  }
}

// apply recorded Givens rotations to S rows (reverse order)
__global__ __launch_bounds__(256) void k_rot(double* Sm_b, const double* smalls, int level){
  int s = blockIdx.x, merge = blockIdx.y;
  int hh = 16 << level, n = hh << 1, start = merge*n;
  const double* rotg = smalls + 8192 + (size_t)(s*32+merge)*1024;
  double* Sm = Sm_b + (size_t)s*MATSZ;
  int cnt = (int)rotg[0];
  for (int i=cnt-1; i>=0; i--){
    int p = (int)rotg[1+4*i], q = (int)rotg[2+4*i];
    double c = rotg[3+4*i], sr = rotg[4+4*i];
    for (int j=threadIdx.x; j<n; j+=256){
      double* col = Sm + (size_t)(start+j)*512;
      double a = col[p], b = col[q];
      col[p] = c*a - sr*b;
      col[q] = sr*a + c*b;
    }
    __syncthreads();
  }
}

// Zdst[merge square] = Zsrc[:,local-cols] * S
__global__ __launch_bounds__(256) void k_gemm64(const double* Zsrc_b, const double* Sm_b,
                                                double* Zdst_b, int level){
  int hh = 16 << level, n = hh << 1;
  int mpm = 512 / n;
  int bz = blockIdx.z;
  int s = bz / mpm, merge = bz % mpm;
  int start = merge*n;
  const double* Zs = Zsrc_b + (size_t)s*MATSZ;
  const double* Sm = Sm_b + (size_t)s*MATSZ;
  double* Zd = Zdst_b + (size_t)s*MATSZ;
  int row0 = start + blockIdx.y*32, col0 = start + blockIdx.x*32;
  int t = threadIdx.x;
  int tr = t >> 4, tc = t & 15;
  __shared__ double As[32][33];
  __shared__ double Bs[32][33];
  double a00=0,a01=0,a10=0,a11=0;
  for (int q0=0; q0<n; q0+=32){
    #pragma unroll
    for (int it=0; it<4; it++){
      int idx = t + it*256;
      int r = idx >> 5, q = idx & 31;
      As[r][q] = Zs[(size_t)(row0+r)*512 + start + q0 + q];
    }
    #pragma unroll
    for (int it=0; it<4; it++){
      int idx = t + it*256;
      int c = idx >> 5, q = idx & 31;
      Bs[q][c] = Sm[(size_t)(col0+c)*512 + q0 + q];
    }
    __syncthreads();
    #pragma unroll 8
    for (int q=0;q<32;q++){
      double ar0=As[tr][q], ar1=As[tr+16][q];
      double bc0=Bs[q][tc], bc1=Bs[q][tc+16];
      a00 = fma(ar0,bc0,a00); a01 = fma(ar0,bc1,a01);
      a10 = fma(ar1,bc0,a10); a11 = fma(ar1,bc1,a11);
    }
    __syncthreads();
  }
  Zd[(size_t)(row0+tr)*512 + col0+tc]       = a00;
  Zd[(size_t)(row0+tr)*512 + col0+tc+16]    = a01;
  Zd[(size_t)(row0+tr+16)*512 + col0+tc]    = a10;
  Zd[(size_t)(row0+tr+16)*512 + col0+tc+16] = a11;
}

// apply Q = H(1)...H(n-1) to Z from the left (reverse reflector order)
__global__ __launch_bounds__(256) void k_backq(double* Z2_b, const double* Vh_b,
                                               const double* smalls){
  int s = blockIdx.x, cb = blockIdx.y;
  double* Z = Z2_b + (size_t)s*MATSZ;
  const double* V = Vh_b + (size_t)s*MATSZ;
  const double* tu = smalls + 4096 + (size_t)s*512;
  int cg = threadIdx.x >> 5, lane = threadIdx.x & 31;
  int c = cb*8 + cg;
  __shared__ double zc[8][512];
  for (int r=lane; r<512; r+=32) zc[cg][r] = Z[(size_t)r*512 + c];
  for (int i=509; i>=0; i--){
    double tv = tu[i];
    if (tv == 0.0) continue;
    double wp = 0.0;
    for (int r=i+1+lane; r<512; r+=32) wp += V[(size_t)i*512 + r]*zc[cg][r];
    #pragma unroll
    for (int off=16; off; off>>=1) wp += __shfl_down(wp, off, 32);
    double w = __shfl(wp, 0, 32);
    double tw = tv*w;
    for (int r=i+1+lane; r<512; r+=32) zc[cg][r] -= tw*V[(size_t)i*512 + r];
  }
  for (int r=lane; r<512; r+=32) Z[(size_t)r*512 + c] = zc[cg][r];
}

__global__ void k_finalize(const double* Z2_b, const double* smalls,
                           float* Vt, float* eig, int pass){
  int s = blockIdx.x;
  const double* Z = Z2_b + (size_t)s*MATSZ;
  double org = smalls[6144+s];
  int idx = blockIdx.y*256 + threadIdx.x;   // < 262144
  int r = idx >> 9, c = idx & 511;
  Vt[(size_t)(pass*4+s)*MATSZ + (size_t)c*512 + r] = (float)Z[(size_t)r*512 + c];
  if (idx < 512)
    eig[(size_t)(pass*4+s)*512 + idx] = (float)(smalls[(size_t)s*512 + idx]*org);
}

// --------------------------- diffusion (f32) --------------------------------
struct KArgs {
  const float* Vt;
  float *xspec, *hbuf, *x, *E;
  const float *W1s, *W1t, *W2s, *W2t;
  const float *b2s, *b2t, *wts, *wtt, *b1s, *b1t, *wes, *wet;
  const float *cond, *Wcs, *Wct;
  const float *eig;
  const float *rec, *recW, *recb;
  float* out;
  float t, a, bc;
  unsigned nk0, nk1, nk2, nk3;   // threefry step keys (speaker, temporal)
  int mode;
};

__global__ __launch_bounds__(256) void k_gemm32(KArgs P){
  int t = threadIdx.x;
  int tr = t >> 4, tc = t & 15;
  int bz = blockIdx.z;
  int m0 = blockIdx.y << 6, n0 = blockIdx.x << 6;
  const float *A, *B; float *C;
  int lda, K, chain = 0;
  if (P.mode == 0){
    A = P.Vt + (size_t)bz*MATSZ; lda = 512; K = 512;
    B = P.x + (size_t)bz*SZF; C = P.xspec + (size_t)bz*SZF;
  } else if (P.mode == 1){
    chain = bz >> 2;
    A = P.xspec + (size_t)bz*SZF; lda = 256; K = 256;
    B = chain ? P.W1t : P.W1s; C = P.hbuf + (size_t)bz*SZF;
  } else if (P.mode == 2){
    chain = bz >> 2;
    A = P.hbuf + (size_t)bz*SZF; lda = 256; K = 256;
    B = chain ? P.W2t : P.W2s; C = P.x + (size_t)bz*SZF;
  } else if (P.mode == 3){
    chain = bz;
    A = P.cond; lda = 256; K = 256;
    B = chain ? P.Wct : P.Wcs; C = P.E + (size_t)chain*4*SZF;
  } else {
    A = P.rec; lda = 256; K = 256;
    B = P.recW; C = P.out;
  }
  __shared__ float As[16][65];
  __shared__ float Bs[16][65];
  float acc[4][4] = {{0}};
  for (int k0=0; k0<K; k0+=16){
    #pragma unroll
    for (int it=0; it<4; it++){
      int idx = t + it*256;
      int r = idx >> 4, kk = idx & 15;
      As[kk][r] = A[(size_t)(m0 + r)*lda + k0 + kk];
    }
    #pragma unroll
    for (int it=0; it<4; it++){
      int idx = t + it*256;
      int c = idx & 63, kk = idx >> 6;
      Bs[kk][c] = B[(size_t)(k0 + kk)*256 + n0 + c];
    }
    __syncthreads();
    #pragma unroll
    for (int kk=0; kk<16; kk++){
      float ar[4], bv[4];
      #pragma unroll
      for (int q=0;q<4;q++){ ar[q] = As[kk][tr + (q<<4)]; bv[q] = Bs[kk][tc + (q<<4)]; }
      #pragma unroll
      for (int q=0;q<4;q++)
        #pragma unroll
        for (int p=0;p<4;p++)
          acc[q][p] = fmaf(ar[q], bv[p], acc[q][p]);
    }
    __syncthreads();
  }
  #pragma unroll
  for (int q=0;q<4;q++){
    #pragma unroll
    for (int p=0;p<4;p++){
      int r = m0 + tr + (q<<4);
      int c = n0 + tc + (p<<4);
      size_t oi = (size_t)r*256 + c;
      float v = acc[q][p];
      if (P.mode == 1){
        v += P.E[(size_t)bz*SZF + oi] + P.t * ((chain ? P.wtt : P.wts)[c]);
        float sg = 1.0f/(1.0f + expf(-v));
        v = v * sg;
      } else if (P.mode == 2){
        float bias = (chain ? P.b2t : P.b2s)[c];
        unsigned j = ((unsigned)(bz & 3))*131072u + (unsigned)oi;
        unsigned kk0 = chain ? P.nk2 : P.nk0;
        unsigned kk1 = chain ? P.nk3 : P.nk1;
        unsigned y0, y1;
        tf2x32(kk0, kk1, 0u, j, &y0, &y1);
        float nz = bits_to_normal(y0 ^ y1);
        v = C[oi] + P.a*(v + bias) + P.bc*nz;
      } else if (P.mode == 3){
        int bb = r >> 9, s2 = r & 511;
        v += (chain ? P.b1t : P.b1s)[c]
           + P.eig[(size_t)(chain*4 + bb)*512 + s2] * ((chain ? P.wet : P.wes)[c]);
      } else if (P.mode == 4){
        v += P.recb[c];
      }
      C[oi] = v;
    }
  }
}

__global__ void k_cond(float* cond, const float* a, const float* v){
  size_t i = (size_t)blockIdx.x*256 + threadIdx.x;
  cond[i] = 0.5f*(a[i] + v[i]);
}

__global__ void k_xinit(float* x, const float* xT){
  size_t i = (size_t)blockIdx.x*256 + threadIdx.x;
  size_t b = i >> 17, off = i & 131071;
  x[i] = xT[((b & 3) << 17) + off];
}

__global__ void k_rec(float* rec, const float* x){
  size_t i = (size_t)blockIdx.x*256 + threadIdx.x;
  rec[i] = 0.5f*(x[i] + x[i + 524288]);
}

__global__ void k_copy(float* out, const float* a, const float* v){
  size_t i = (size_t)blockIdx.x*256 + threadIdx.x;
  out[524288 + i] = (i < 524288) ? a[i] : v[i - 524288];
}

// ------------------------------- host --------------------------------------
extern "C" void kernel_launch(void* const* d_in, const int* in_sizes, int n_in,
                              void* d_out, int out_size, void* d_ws, size_t ws_size,
                              hipStream_t stream){
  const float* f_audio   = (const float*)d_in[1];
  const float* f_visual  = (const float*)d_in[2];
  const float* g_speaker = (const float*)d_in[3];
  const float* g_temporal= (const float*)d_in[4];
  const float* x_T       = (const float*)d_in[6];
  const float* tsW1=(const float*)d_in[7],  *tswe=(const float*)d_in[8],
             * tswt=(const float*)d_in[9],  *tsb1=(const float*)d_in[10],
             * tsWc=(const float*)d_in[11], *tsW2=(const float*)d_in[12],
             * tsb2=(const float*)d_in[13];
  const float* ttW1=(const float*)d_in[14], *ttwe=(const float*)d_in[15],
             * ttwt=(const float*)d_in[16], *ttb1=(const float*)d_in[17],
             * ttWc=(const float*)d_in[18], *ttW2=(const float*)d_in[19],
             * ttb2=(const float*)d_in[20];
  const float* recW=(const float*)d_in[21], *recb=(const float*)d_in[22];
  float* out = (float*)d_out;

  const size_t MB = 1ull << 20;
  if (ws_size < 43*MB) return;

  char* ws = (char*)d_ws;
  double* A64  = (double*)(ws + 0);
  double* Vh   = (double*)(ws + 8*MB);
  double* Zb   = (double*)(ws + 16*MB);
  double* Sm   = (double*)(ws + 24*MB);
  double* smalls = (double*)(ws + 32*MB);
  unsigned* bar = (unsigned*)(smalls + 147456);
  float* cond  = (float*)(ws + 0);
  float* E     = (float*)(ws + 2*MB);
  float* xall  = (float*)(ws + 6*MB);
  float* xspec = (float*)(ws + 10*MB);
  float* hbuf  = (float*)(ws + 14*MB);
  float* Vt32  = (float*)(ws + 34*MB);
  float* eig32 = (float*)(ws + 42*MB);

  // ---- jax.random key schedule (host, exact threefry, PARTITIONABLE) ----
  unsigned f0, f1;
  tf2x32(0u, 42u, 0u, 0u, &f0, &f1);                 // fold_in(key(42), 0)
  unsigned s0,s1,t0,t1;
  tf2x32(f0, f1, 0u, 0u, &s0, &s1);                  // k_s = split[0]
  tf2x32(f0, f1, 0u, 1u, &t0, &t1);                  // k_t = split[1]
  unsigned skeys[100][2], tkeys[100][2];
  for (int k=0; k<100; k++){
    tf2x32(s0, s1, 0u, (unsigned)k, &skeys[k][0], &skeys[k][1]);
    tf2x32(t0, t1, 0u, (unsigned)k, &tkeys[k][0], &tkeys[k][1]);
  }

  hipMemsetAsync(bar, 0, 512, stream);

  // ---- eigh: 2 passes of 4 matrices ----
  for (int pass=0; pass<2; pass++){
    const float* G = pass ? g_temporal : g_speaker;
    k_prep<<<4096, 256, 0, stream>>>(A64, G);
    k_sytd2_mb<<<NSYB, 256, 0, stream>>>(A64, Vh, smalls, bar);
    k_scale<<<4, 256, 0, stream>>>(smalls);
    hipMemsetAsync(Zb, 0, 8*MB, stream);
    hipMemsetAsync(A64, 0, 8*MB, stream);
    k_tear<<<1, 128, 0, stream>>>(smalls);
    k_leaves<<<16, 64, 0, stream>>>(smalls, Zb);
    for (int level=0; level<5; level++){
      int n = 32 << level, mpm = 512/n;
      double* src = (level & 1) ? A64 : Zb;
      double* dst = (level & 1) ? Zb  : A64;
      k_secular<<<dim3(4, mpm), 256, 0, stream>>>(smalls, src, Sm, level);
      k_rot<<<dim3(4, mpm), 256, 0, stream>>>(Sm, smalls, level);
      k_gemm64<<<dim3(n/32, n/32, 4*mpm), 256, 0, stream>>>(src, Sm, dst, level);
    }
    k_backq<<<dim3(4, 64), 256, 0, stream>>>(A64, Vh, smalls);
    k_finalize<<<dim3(4, 1024), 256, 0, stream>>>(A64, smalls, Vt32, eig32, pass);
  }

  // ---- diffusion ----
  k_cond<<<2048, 256, 0, stream>>>(cond, f_audio, f_visual);
  k_xinit<<<4096, 256, 0, stream>>>(xall, x_T);

  KArgs P;
  P.Vt = Vt32; P.xspec = xspec; P.hbuf = hbuf; P.x = xall; P.E = E;
  P.W1s = tsW1; P.W1t = ttW1; P.W2s = tsW2; P.W2t = ttW2;
  P.b2s = tsb2; P.b2t = ttb2; P.wts = tswt; P.wtt = ttwt;
  P.b1s = tsb1; P.b1t = ttb1; P.wes = tswe; P.wet = ttwe;
  P.cond = cond; P.Wcs = tsWc; P.Wct = ttWc;
  P.eig = eig32; P.rec = xspec; P.recW = recW; P.recb = recb; P.out = out;
  P.t = 0.f; P.a = 0.f; P.bc = 0.f;
  P.nk0 = 0; P.nk1 = 0; P.nk2 = 0; P.nk3 = 0;

  P.mode = 3;
  k_gemm32<<<dim3(4, 32, 2), 256, 0, stream>>>(P);

  for (int k=0; k<100; k++){
    float tf = (float)(1.0 - (double)k/99.0);
    float av = (float)(pow(25.0, 2.0*(double)tf) * 0.01);
    float bcv = (float)(pow(25.0, (double)tf) * 0.1);
    P.nk0 = skeys[k][0]; P.nk1 = skeys[k][1];
    P.nk2 = tkeys[k][0]; P.nk3 = tkeys[k][1];
    P.mode = 0;
    k_gemm32<<<dim3(4, 8, 8), 256, 0, stream>>>(P);
    P.mode = 1; P.t = tf;
    k_gemm32<<<dim3(4, 8, 8), 256, 0, stream>>>(P);
    P.mode = 2; P.a = av; P.bc = bcv;
    k_gemm32<<<dim3(4, 8, 8), 256, 0, stream>>>(P);
  }

  k_rec<<<2048, 256, 0, stream>>>(xspec, xall);
  P.mode = 4; P.rec = xspec;
  k_gemm32<<<dim3(4, 32, 1), 256, 0, stream>>>(P);
  k_copy<<<4096, 256, 0, stream>>>(out, f_audio, f_visual);
}

// Round 8
// 50349.011 us; speedup vs baseline: 1.1141x; 1.1141x over previous
//
#include <hip/hip_runtime.h>
#include <math.h>
#include <stdint.h>

// ---------------------------------------------------------------------------
// DualSpectralDiffusion: faithful replication of the JAX reference.
//  - f64 LAPACK-style eigh (multi-block sytd2 with A resident in LDS +
//    D&C w/ slaed2 deflation mimicry), sign-faithful vs numpy ssyevd
//  - exact threefry2x32 / jax.random replication (PARTITIONABLE stream)
//  - f32 diffusion loop, noise threefry fused into the update-GEMM epilogue
// ---------------------------------------------------------------------------

#define NT 256
#define SZF 131072          // 512*256 floats per (b) tensor
#define MATSZ 262144        // 512*512
#define NB 32               // sytd2 blocks per matrix (16 rows each, in LDS)
#define NSYB (4*NB)         // total sytd2 blocks

// ----------------------------- threefry ------------------------------------
__host__ __device__ static inline unsigned rotl32(unsigned v, int r){ return (v<<r)|(v>>(32-r)); }

__host__ __device__ static inline void tf2x32(unsigned k0, unsigned k1,
                                              unsigned x0, unsigned x1,
                                              unsigned* o0, unsigned* o1){
  unsigned ks2 = k0 ^ k1 ^ 0x1BD11BDAu;
  x0 += k0; x1 += k1;
#define TF4(r0,r1,r2,r3) \
  x0 += x1; x1 = rotl32(x1,r0); x1 ^= x0; \
  x0 += x1; x1 = rotl32(x1,r1); x1 ^= x0; \
  x0 += x1; x1 = rotl32(x1,r2); x1 ^= x0; \
  x0 += x1; x1 = rotl32(x1,r3); x1 ^= x0;
  TF4(13,15,26,6)  x0 += k1;  x1 += ks2 + 1u;
  TF4(17,29,16,24) x0 += ks2; x1 += k0 + 2u;
  TF4(13,15,26,6)  x0 += k0;  x1 += k1 + 3u;
  TF4(17,29,16,24) x0 += k1;  x1 += ks2 + 4u;
  TF4(13,15,26,6)  x0 += ks2; x1 += k0 + 5u;
#undef TF4
  *o0 = x0; *o1 = x1;
}

// XLA ErfInv f32 polynomial; matches lax.erf_inv expansion.
__device__ static inline float erfinv_xla(float x){
  float w = -log1pf(-x*x);
  float p;
  if (w < 5.0f){
    w -= 2.5f;
    p = 2.81022636e-08f;
    p = fmaf(p, w, 3.43273939e-07f);
    p = fmaf(p, w, -3.5233877e-06f);
    p = fmaf(p, w, -4.39150654e-06f);
    p = fmaf(p, w, 0.00021858087f);
    p = fmaf(p, w, -0.00125372503f);
    p = fmaf(p, w, -0.00417768164f);
    p = fmaf(p, w, 0.246640727f);
    p = fmaf(p, w, 1.50140941f);
  } else {
    w = sqrtf(w) - 3.0f;
    p = -0.000200214257f;
    p = fmaf(p, w, 0.000100950558f);
    p = fmaf(p, w, 0.00134934322f);
    p = fmaf(p, w, -0.00367342844f);
    p = fmaf(p, w, 0.00573950773f);
    p = fmaf(p, w, -0.0076224613f);
    p = fmaf(p, w, 0.00943887047f);
    p = fmaf(p, w, 1.00167406f);
    p = fmaf(p, w, 2.83297682f);
  }
  return p*x;
}

__device__ static inline float bits_to_normal(unsigned bits){
  const float MINV = -0.99999994f;   // nextafter(-1,0) in f32
  float f = __uint_as_float((bits >> 9) | 0x3f800000u) - 1.0f;
  float u = fmaxf(MINV, fmaf(f, 2.0f, MINV));
  return 1.41421356237309515f * erfinv_xla(u);
}

// ------------------------------- eigh --------------------------------------
// smalls layout (doubles): d[s*512], e[2048+s*512], tau[4096+s*512],
// org[6144+s], rot at 8192+(s*32+merge)*1024 (up to 139264),
// acc ping/pong at 139264 (+2048), col ping/pong at 143360 (+2048),
// barrier counters (unsigned) at double-index 147456.

// per-matrix sense-reversing barrier: NB blocks of matrix s participate.
__device__ __forceinline__ void gbar(unsigned* bar, int s){
  __syncthreads();
  if (threadIdx.x == 0){
    __threadfence();
    unsigned* cnt = bar + s*32;
    unsigned* gen = bar + s*32 + 16;
    unsigned g0 = __hip_atomic_load(gen, __ATOMIC_RELAXED, __HIP_MEMORY_SCOPE_AGENT);
    unsigned a = __hip_atomic_fetch_add(cnt, 1u, __ATOMIC_ACQ_REL, __HIP_MEMORY_SCOPE_AGENT);
    if (a == NB-1u){
      __hip_atomic_store(cnt, 0u, __ATOMIC_RELAXED, __HIP_MEMORY_SCOPE_AGENT);
      __hip_atomic_fetch_add(gen, 1u, __ATOMIC_RELEASE, __HIP_MEMORY_SCOPE_AGENT);
    } else {
      while (__hip_atomic_load(gen, __ATOMIC_ACQUIRE, __HIP_MEMORY_SCOPE_AGENT) == g0){
        __builtin_amdgcn_s_sleep(4);
      }
    }
  }
  __syncthreads();
}

// Multi-block Householder tridiagonalization, A resident in LDS.
// 4 matrices x NB blocks; block g owns rows r%NB==g (16 rows, 64KB LDS).
// Cross-block state per iteration: acc/col ping-pong (global, ~KBs) only —
// the agent fences never touch LDS, so the sweep stays cache-local.
// Arithmetic identical to verified r5/r6/r7 kernels (bit-identical output).
__global__ __launch_bounds__(256) void k_sytd2_lds(const float* G4, double* Vb,
                                                   double* smalls, unsigned* bar){
  int blk = blockIdx.x;
  int s = blk / NB, g = blk % NB;
  int t = threadIdx.x, wave = t >> 6, lane = t & 63;
  const float* G = G4 + (size_t)s*MATSZ;
  double* V = Vb + (size_t)s*MATSZ;
  double* d  = smalls + (size_t)s*512;
  double* e  = smalls + 2048 + (size_t)s*512;
  double* tu = smalls + 4096 + (size_t)s*512;
  double* acc0 = smalls + 139264 + (size_t)s*512;
  double* acc1 = acc0 + 2048;
  double* col0 = smalls + 143360 + (size_t)s*512;
  double* col1 = col0 + 2048;

  __shared__ double Arows[16][512];   // owned rows r = 32*j + g
  __shared__ double vv[512], wv[512], v2[512], col2[512], acc[512];
  __shared__ double red[4];
  __shared__ double bc[4];

  // ---------- load owned rows into LDS (f32 -> f64) ----------
  for (int j=0; j<16; j++){
    int r = 32*j + g;
    for (int c=t; c<512; c+=256)
      Arows[j][c] = (double)G[(size_t)r*512 + c];
  }

  // ---------- init: reflector 0 (replicated) ----------
  for (int r=t; r<512; r+=256) col2[r] = (r>=1) ? (double)G[(size_t)r*512] : 0.0;
  __syncthreads();
  {
    double part = 0.0;
    for (int r=2+t; r<512; r+=256) part += col2[r]*col2[r];
    #pragma unroll
    for (int off=32; off; off>>=1) part += __shfl_down(part, off, 64);
    if (lane==0) red[wave]=part;
    __syncthreads();
    if (t==0){
      double xsq = red[0]+red[1]+red[2]+red[3];
      double alpha = col2[1];
      double beta,tv,scal;
      if (xsq == 0.0){ beta=alpha; tv=0.0; scal=0.0; }
      else {
        beta = -copysign(sqrt(alpha*alpha + xsq), alpha);   // LAPACK slarfg
        tv = (beta - alpha)/beta;
        scal = 1.0/(alpha - beta);
      }
      if (g==0){ e[0]=beta; tu[0]=tv; }
      bc[0]=tv; bc[1]=scal;
    }
  }
  __syncthreads();
  double tauv = bc[0];
  {
    double scal = bc[1];
    for (int r=t; r<512; r+=256){
      double v = 0.0;
      if (r==1) v = 1.0;
      else if (r>1) v = (tauv==0.0) ? 0.0 : col2[r]*scal;
      vv[r]=v;
    }
  }
  __syncthreads();
  if (g==0){
    for (int r=1+t; r<512; r+=256) V[r] = vv[r];
    for (int r=1+t; r<512; r+=256) col0[r] = (double)G[(size_t)r*512 + 1];
  }
  // init matvec on owned rows (r>=1, r%NB==g) -> acc0
  {
    int r0 = 1 + ((g - 1) & (NB-1));
    for (int r = r0 + NB*wave; r < 512; r += 4*NB){
      const double* Ar = Arows[r>>5];
      double p = 0.0;
      for (int c=lane; c<512; c+=64) p += Ar[c]*vv[c];
      #pragma unroll
      for (int off=32; off; off>>=1) p += __shfl_down(p, off, 64);
      if (lane==0) acc0[r] = p;
    }
  }

  // ---------- main loop: iteration i applies reflector i, derives i+1 ----------
  for (int i=0; i<510; i++){
    gbar(bar, s);
    int lo=i+1, lo2=i+2;
    double* accR = (i&1) ? acc1 : acc0;
    double* colR = (i&1) ? col1 : col0;
    double* accW = (i&1) ? acc0 : acc1;
    double* colW = (i&1) ? col0 : col1;
    for (int r=lo+t; r<512; r+=256){ acc[r]=accR[r]; col2[r]=colR[r]; }
    __syncthreads();
    double part = 0.0;
    for (int r=lo+t; r<512; r+=256){ double wr = tauv*acc[r]; wv[r]=wr; part += wr*vv[r]; }
    #pragma unroll
    for (int off=32; off; off>>=1) part += __shfl_down(part, off, 64);
    if (lane==0) red[wave]=part;
    __syncthreads();
    if (t==0){ double dot=red[0]+red[1]+red[2]+red[3]; bc[2] = -0.5*tauv*dot; }
    __syncthreads();
    {
      double alpha2 = bc[2];
      for (int r=lo+t; r<512; r+=256) wv[r] += alpha2*vv[r];
    }
    __syncthreads();
    {
      double wlo = wv[lo], vlo = vv[lo];
      for (int r=lo+t; r<512; r+=256) col2[r] = col2[r] - vv[r]*wlo - wv[r]*vlo;
    }
    __syncthreads();
    part = 0.0;
    for (int r=lo2+1+t; r<512; r+=256) part += col2[r]*col2[r];
    #pragma unroll
    for (int off=32; off; off>>=1) part += __shfl_down(part, off, 64);
    if (lane==0) red[wave]=part;
    __syncthreads();
    if (t==0){
      double xsq = red[0]+red[1]+red[2]+red[3];
      double alpha = col2[lo2];
      double beta,tau2,scal2;
      if (xsq == 0.0){ beta=alpha; tau2=0.0; scal2=0.0; }
      else {
        beta = -copysign(sqrt(alpha*alpha + xsq), alpha);
        tau2 = (beta - alpha)/beta;
        scal2 = 1.0/(alpha - beta);
      }
      if (g==0){ e[lo]=beta; tu[lo]=tau2; }
      bc[0]=tau2; bc[1]=scal2;
    }
    __syncthreads();
    double tau2 = bc[0];
    {
      double scal2 = bc[1];
      for (int r=t; r<512; r+=256){
        double v = 0.0;
        if (r==lo2) v = 1.0;
        else if (r>lo2) v = (tau2==0.0) ? 0.0 : col2[r]*scal2;
        v2[r]=v;
      }
    }
    __syncthreads();
    if (g==0){
      for (int r=lo2+t; r<512; r+=256) V[(size_t)lo*512 + r] = v2[r];
    }
    // fused sweep over owned rows (LDS): A -= v w^T + w v^T ; acc = A_new*v2;
    // export column lo2 into colW.
    {
      double vvc[8], wvc[8], v2c[8];
      #pragma unroll
      for (int j=0;j<8;j++){
        int c = lo + lane + 64*j;
        bool ok = c < 512;
        vvc[j] = ok ? vv[c] : 0.0;
        wvc[j] = ok ? wv[c] : 0.0;
        v2c[j] = ok ? v2[c] : 0.0;
      }
      int r0 = lo + ((g - lo) & (NB-1));
      for (int r = r0 + NB*wave; r < 512; r += 4*NB){
        double* Ar = Arows[r>>5];
        double vr = vv[r], wr = wv[r];
        double p = 0.0;
        #pragma unroll
        for (int j=0;j<8;j++){
          int c = lo + lane + 64*j;
          if (c < 512){
            double an = Ar[c] - vr*wvc[j] - wr*vvc[j];
            Ar[c] = an;
            p += an * v2c[j];
            if (c == lo2) colW[r] = an;
          }
        }
        #pragma unroll
        for (int off=32; off; off>>=1) p += __shfl_down(p, off, 64);
        if (lane==0) accW[r] = p;
      }
    }
    __syncthreads();
    for (int r=t; r<512; r+=256) vv[r] = v2[r];
    tauv = tau2;
    __syncthreads();
  }
  // diag from owned rows (LDS-resident)
  if (t < 16){
    int r = 32*t + g;
    d[r] = Arows[t][r];
  }
}

// sstedc-style pre-scale: org = max(|d|,|e|); d,e /= org
__global__ void k_scale(double* smalls){
  int s = blockIdx.x, t = threadIdx.x;
  double* d = smalls + (size_t)s*512;
  double* e = smalls + 2048 + (size_t)s*512;
  __shared__ double red[256];
  double m = 0.0;
  for (int i=t;i<512;i+=256) m = fmax(m, fabs(d[i]));
  for (int i=t;i<511;i+=256) m = fmax(m, fabs(e[i]));
  red[t]=m; __syncthreads();
  for (int off=128; off; off>>=1){ if (t<off) red[t]=fmax(red[t],red[t+off]); __syncthreads(); }
  double org = red[0]; if (org == 0.0) org = 1.0;
  if (t==0) smalls[6144+s] = org;
  double inv = 1.0/org;
  __syncthreads();
  for (int i=t;i<512;i+=256) d[i] *= inv;
  for (int i=t;i<511;i+=256) e[i] *= inv;
}

__global__ void k_tear(double* smalls){
  int t = threadIdx.x;           // 128 threads: s = t>>5, k = (t&31)+1
  int s = t >> 5, k = (t & 31) + 1;
  if (k <= 31){
    double* d = smalls + (size_t)s*512;
    double* e = smalls + 2048 + (size_t)s*512;
    double ae = fabs(e[16*k - 1]);
    d[16*k - 1] -= ae;
    d[16*k]     -= ae;
  }
}

// 32 leaves of 16 per matrix; 8 leaves per block, threads 0..7 active
__global__ __launch_bounds__(64) void k_leaves(double* smalls, double* Zb){
  __shared__ double LA[8][256];
  __shared__ double LQ[8][256];
  int t = threadIdx.x;
  if (t < 8){
    int bid = blockIdx.x;        // 0..15
    int s = bid >> 2;
    int leaf = (bid & 3)*8 + t;  // 0..31
    double* d = smalls + (size_t)s*512;
    double* e = smalls + 2048 + (size_t)s*512;
    double* Z = Zb + (size_t)s*MATSZ;
    int base = leaf*16;
    double* A = LA[t]; double* Q = LQ[t];
    for (int i=0;i<256;i++){ A[i]=0.0; Q[i]=0.0; }
    for (int i=0;i<16;i++){ A[i*17] = d[base+i]; Q[i*17] = 1.0; }
    for (int i=0;i<15;i++){ double ee = e[base+i]; A[i*16+i+1] = ee; A[(i+1)*16+i] = ee; }
    double nrm = 0.0;
    for (int i=0;i<256;i++) nrm += A[i]*A[i];
    double thr = nrm*1e-30 + 1e-300;
    for (int sweep=0; sweep<60; sweep++){
      double off = 0.0;
      for (int p=0;p<15;p++) for (int q=p+1;q<16;q++){
        double apq = A[p*16+q];
        off += 2.0*apq*apq;
        if (apq == 0.0) continue;
        double theta = 0.5*(A[q*17]-A[p*17])/apq;
        double tt;
        if (fabs(theta) > 1e18) tt = 0.5/theta;
        else tt = copysign(1.0, theta)/(fabs(theta)+sqrt(theta*theta+1.0));
        double cc = 1.0/sqrt(tt*tt+1.0), ss = tt*cc;
        for (int k=0;k<16;k++){
          double akp=A[k*16+p], akq=A[k*16+q];
          A[k*16+p] = cc*akp - ss*akq;
          A[k*16+q] = ss*akp + cc*akq;
        }
        for (int k=0;k<16;k++){
          double apk=A[p*16+k], aqk=A[q*16+k];
          A[p*16+k] = cc*apk - ss*aqk;
          A[q*16+k] = ss*apk + cc*aqk;
        }
        for (int k=0;k<16;k++){
          double qkp=Q[k*16+p], qkq=Q[k*16+q];
          Q[k*16+p] = cc*qkp - ss*qkq;
          Q[k*16+q] = ss*qkp + cc*qkq;
        }
      }
      if (off < thr) break;
    }
    for (int i=0;i<16;i++){
      int mi=i;
      for (int j=i+1;j<16;j++) if (A[j*17] < A[mi*17]) mi=j;
      if (mi!=i){
        double tmp=A[i*17]; A[i*17]=A[mi*17]; A[mi*17]=tmp;
        for (int k=0;k<16;k++){ double q1=Q[k*16+i]; Q[k*16+i]=Q[k*16+mi]; Q[k*16+mi]=q1; }
      }
    }
    for (int i=0;i<16;i++) d[base+i] = A[i*17];
    for (int r=0;r<16;r++)
      for (int c=0;c<16;c++)
        Z[(size_t)(base+r)*512 + base + c] = Q[r*16+c];
  }
}

// one block per merge: LAPACK slaed2 deflation + secular solve + Gu-Eisenstat
__global__ __launch_bounds__(256) void k_secular(double* smalls, const double* Zsrc_b,
                                                 double* Sm_b, int level){
  const double EPS32 = 5.9604644775390625e-8;   // SLAMCH('E') for f32
  const double ISQ2  = 0.70710678118654752440;
  int s = blockIdx.x;
  int hh = 16 << level, n = hh << 1;
  int merge = blockIdx.y, start = merge*n;
  double* d = smalls + (size_t)s*512;
  const double* e = smalls + 2048 + (size_t)s*512;
  const double* Z = Zsrc_b + (size_t)s*MATSZ;
  double* Sm = Sm_b + (size_t)s*MATSZ;
  double* rotg = smalls + 8192 + (size_t)(s*32+merge)*1024;
  __shared__ double ds[512], zl[512], dk[512], zk[512], tauk[512], zh[512], outlam[512];
  __shared__ double rc[256], rs[256];
  __shared__ double red[256];
  __shared__ double sv[2];
  __shared__ int perm[512], kidx[512], Ksk[512], didx[512], outid[512];
  __shared__ int rp[256], rq[256];
  __shared__ int counts[3];
  int t = threadIdx.x;
  if (t == 0){
    int i=0, j=hh, k=0;
    while (i < hh && j < n){
      if (d[start+i] <= d[start+j]) perm[k++]=i++; else perm[k++]=j++;
    }
    while (i < hh) perm[k++]=i++;
    while (j < n)  perm[k++]=j++;
  }
  __syncthreads();
  double eb = e[start+hh-1];
  double rho = 2.0*fabs(eb);
  double sgn = (eb < 0.0) ? -1.0 : 1.0;
  for (int i=t; i<n; i+=NT){
    int p = perm[i];
    ds[i] = d[start+p];
    double zr = (p < hh) ? Z[(size_t)(start+hh-1)*512 + start + p]
                         : sgn * Z[(size_t)(start+hh)*512 + start + p];
    zl[i] = zr * ISQ2;
  }
  __syncthreads();
  double m = 0.0;
  for (int i=t;i<n;i+=NT) m = fmax(m, fabs(zl[i]));
  red[t]=m; __syncthreads();
  for (int off=128; off; off>>=1){ if (t<off) red[t]=fmax(red[t],red[t+off]); __syncthreads(); }
  if (t==0) sv[0] = red[0];
  __syncthreads();
  m = 0.0;
  for (int i=t;i<n;i+=NT) m = fmax(m, fabs(ds[i]));
  red[t]=m; __syncthreads();
  for (int off=128; off; off>>=1){ if (t<off) red[t]=fmax(red[t],red[t+off]); __syncthreads(); }
  if (t==0) sv[1] = red[0];
  __syncthreads();
  double zmaxv = sv[0];
  double tol = 8.0*EPS32*fmax(sv[1], zmaxv);

  if (t == 0){
    int K=0, nd=0, nrot=0;
    if (rho*zmaxv <= tol){
      for (int j=0;j<n;j++) didx[nd++]=j;
    } else {
      int pj = -1;
      for (int j=0;j<n;j++){
        if (rho*fabs(zl[j]) <= tol){
          didx[nd++]=j;
        } else if (pj < 0){
          pj = j;
        } else {
          double s_ = zl[pj], c_ = zl[j];
          double tau2 = sqrt(c_*c_ + s_*s_);
          double tdf = ds[j] - ds[pj];
          double cc = c_/tau2, sr = -s_/tau2;
          if (fabs(tdf*cc*sr) <= tol){
            zl[j] = tau2; zl[pj] = 0.0;
            if (nrot < 256){
              rp[nrot]=perm[pj]; rq[nrot]=perm[j]; rc[nrot]=cc; rs[nrot]=sr; nrot++;
            }
            double tn = ds[pj]*cc*cc + ds[j]*sr*sr;
            ds[j]  = ds[pj]*sr*sr + ds[j]*cc*cc;
            ds[pj] = tn;
            didx[nd++] = pj;
            pj = j;
          } else {
            kidx[K++] = pj;
            pj = j;
          }
        }
      }
      if (pj >= 0) kidx[K++] = pj;
    }
    for (int a=1;a<nd;a++){
      int v = didx[a]; double dv = ds[v]; int b = a-1;
      while (b >= 0 && ds[didx[b]] > dv){ didx[b+1]=didx[b]; b--; }
      didx[b+1] = v;
    }
    counts[0]=K; counts[1]=nd; counts[2]=nrot;
    rotg[0] = (double)nrot;
    for (int i=0;i<nrot;i++){
      rotg[1+4*i]=(double)rp[i]; rotg[2+4*i]=(double)rq[i];
      rotg[3+4*i]=rc[i]; rotg[4+4*i]=rs[i];
    }
  }
  __syncthreads();
  int K = counts[0], nd = counts[1];

  for (int k=t; k<K; k+=NT){ dk[k]=ds[kidx[k]]; zk[k]=zl[kidx[k]]; }
  __syncthreads();

  for (int j2=t; j2<K; j2+=NT){
    int Kb; double lo, hi;
    if (j2 < K-1){
      double mid = 0.5*(dk[j2+1]-dk[j2]);
      double gg = 1.0;
      for (int i=0;i<K;i++){ double dif=(dk[i]-dk[j2])-mid; gg += rho*zk[i]*zk[i]/dif; }
      if (gg >= 0.0){ Kb=j2;   lo=0.0;  hi=mid; }
      else          { Kb=j2+1; lo=-mid; hi=0.0; }
    } else {
      double sz=0.0;
      for (int i=0;i<K;i++) sz += zk[i]*zk[i];
      Kb=K-1; lo=0.0; hi=rho*sz + 1e-300;
    }
    double dK = dk[Kb];
    for (int it=0; it<72; it++){
      double mid = 0.5*(lo+hi);
      if (mid==lo || mid==hi) break;
      double gg = 1.0;
      for (int i=0;i<K;i++){ double dif=(dk[i]-dK)-mid; gg += rho*zk[i]*zk[i]/dif; }
      if (gg < 0.0) lo=mid; else hi=mid;
    }
    Ksk[j2]=Kb; tauk[j2]=0.5*(lo+hi);
  }
  __syncthreads();
  for (int i=t; i<K; i+=NT){
    double P = (Ksk[i]==i) ? tauk[i] : (dk[Ksk[i]]-dk[i]) + tauk[i];
    for (int j=0;j<K;j++){
      if (j==i) continue;
      double num = (dk[Ksk[j]]-dk[i]) + tauk[j];
      double den = dk[j]-dk[i];
      P *= num/den;
    }
    zh[i] = copysign(sqrt(fabs(P/rho)), zk[i]);
  }
  __syncthreads();
  if (t == 0){
    int a=0, b=0;
    for (int j=0;j<n;j++){
      double la = (a<K)  ? (dk[Ksk[a]]+tauk[a]) : 1e300;
      double lb = (b<nd) ? ds[didx[b]]          : 1e300;
      if (la <= lb){ outid[j]=a;     outlam[j]=la; a++; }
      else         { outid[j]=512+b; outlam[j]=lb; b++; }
    }
  }
  __syncthreads();
  for (int j=t; j<n; j+=NT) d[start+j] = outlam[j];
  for (int j=t; j<n; j+=NT){
    double* col = Sm + (size_t)(start+j)*512;
    int id = outid[j];
    for (int i=0;i<n;i++) col[i]=0.0;
    if (id >= 512){
      col[perm[didx[id-512]]] = 1.0;
    } else {
      int k = id;
      double ss_ = 0.0;
      for (int i=0;i<K;i++){
        double dif = (dk[i]-dk[Ksk[k]]) - tauk[k];
        if (dif == 0.0) dif = 1e-300;
        double v = zh[i]/dif;
        col[perm[kidx[i]]] = v; ss_ += v*v;
      }
      double inv = 1.0/sqrt(ss_);
      for (int i=0;i<K;i++) col[perm[kidx[i]]] *= inv;
    }
  }
}

// apply recorded Givens rotations to S rows (reverse order)
__global__ __launch_bounds__(256) void k_rot(double* Sm_b, const double* smalls, int level){
  int s = blockIdx.x, merge = blockIdx.y;
  int hh = 16 << level, n = hh << 1, start = merge*n;
  const double* rotg = smalls + 8192 + (size_t)(s*32+merge)*1024;
  double* Sm = Sm_b + (size_t)s*MATSZ;
  int cnt = (int)rotg[0];
  for (int i=cnt-1; i>=0; i--){
    int p = (int)rotg[1+4*i], q = (int)rotg[2+4*i];
    double c = rotg[3+4*i], sr = rotg[4+4*i];
    for (int j=threadIdx.x; j<n; j+=256){
      double* col = Sm + (size_t)(start+j)*512;
      double a = col[p], b = col[q];
      col[p] = c*a - sr*b;
      col[q] = sr*a + c*b;
    }
    __syncthreads();
  }
}

// Zdst[merge square] = Zsrc[:,local-cols] * S
__global__ __launch_bounds__(256) void k_gemm64(const double* Zsrc_b, const double* Sm_b,
                                                double* Zdst_b, int level){
  int hh = 16 << level, n = hh << 1;
  int mpm = 512 / n;
  int bz = blockIdx.z;
  int s = bz / mpm, merge = bz % mpm;
  int start = merge*n;
  const double* Zs = Zsrc_b + (size_t)s*MATSZ;
  const double* Sm = Sm_b + (size_t)s*MATSZ;
  double* Zd = Zdst_b + (size_t)s*MATSZ;
  int row0 = start + blockIdx.y*32, col0 = start + blockIdx.x*32;
  int t = threadIdx.x;
  int tr = t >> 4, tc = t & 15;
  __shared__ double As[32][33];
  __shared__ double Bs[32][33];
  double a00=0,a01=0,a10=0,a11=0;
  for (int q0=0; q0<n; q0+=32){
    #pragma unroll
    for (int it=0; it<4; it++){
      int idx = t + it*256;
      int r = idx >> 5, q = idx & 31;
      As[r][q] = Zs[(size_t)(row0+r)*512 + start + q0 + q];
    }
    #pragma unroll
    for (int it=0; it<4; it++){
      int idx = t + it*256;
      int c = idx >> 5, q = idx & 31;
      Bs[q][c] = Sm[(size_t)(col0+c)*512 + q0 + q];
    }
    __syncthreads();
    #pragma unroll 8
    for (int q=0;q<32;q++){
      double ar0=As[tr][q], ar1=As[tr+16][q];
      double bc0=Bs[q][tc], bc1=Bs[q][tc+16];
      a00 = fma(ar0,bc0,a00); a01 = fma(ar0,bc1,a01);
      a10 = fma(ar1,bc0,a10); a11 = fma(ar1,bc1,a11);
    }
    __syncthreads();
  }
  Zd[(size_t)(row0+tr)*512 + col0+tc]       = a00;
  Zd[(size_t)(row0+tr)*512 + col0+tc+16]    = a01;
  Zd[(size_t)(row0+tr+16)*512 + col0+tc]    = a10;
  Zd[(size_t)(row0+tr+16)*512 + col0+tc+16] = a11;
}

// apply Q = H(1)...H(n-1) to Z from the left (reverse reflector order)
__global__ __launch_bounds__(256) void k_backq(double* Z2_b, const double* Vh_b,
                                               const double* smalls){
  int s = blockIdx.x, cb = blockIdx.y;
  double* Z = Z2_b + (size_t)s*MATSZ;
  const double* V = Vh_b + (size_t)s*MATSZ;
  const double* tu = smalls + 4096 + (size_t)s*512;
  int cg = threadIdx.x >> 5, lane = threadIdx.x & 31;
  int c = cb*8 + cg;
  __shared__ double zc[8][512];
  for (int r=lane; r<512; r+=32) zc[cg][r] = Z[(size_t)r*512 + c];
  for (int i=509; i>=0; i--){
    double tv = tu[i];
    if (tv == 0.0) continue;
    double wp = 0.0;
    for (int r=i+1+lane; r<512; r+=32) wp += V[(size_t)i*512 + r]*zc[cg][r];
    #pragma unroll
    for (int off=16; off; off>>=1) wp += __shfl_down(wp, off, 32);
    double w = __shfl(wp, 0, 32);
    double tw = tv*w;
    for (int r=i+1+lane; r<512; r+=32) zc[cg][r] -= tw*V[(size_t)i*512 + r];
  }
  for (int r=lane; r<512; r+=32) Z[(size_t)r*512 + c] = zc[cg][r];
}

__global__ void k_finalize(const double* Z2_b, const double* smalls,
                           float* Vt, float* eig, int pass){
  int s = blockIdx.x;
  const double* Z = Z2_b + (size_t)s*MATSZ;
  double org = smalls[6144+s];
  int idx = blockIdx.y*256 + threadIdx.x;   // < 262144
  int r = idx >> 9, c = idx & 511;
  Vt[(size_t)(pass*4+s)*MATSZ + (size_t)c*512 + r] = (float)Z[(size_t)r*512 + c];
  if (idx < 512)
    eig[(size_t)(pass*4+s)*512 + idx] = (float)(smalls[(size_t)s*512 + idx]*org);
}

// --------------------------- diffusion (f32) --------------------------------
struct KArgs {
  const float* Vt;
  float *xspec, *hbuf, *x, *E;
  const float *W1s, *W1t, *W2s, *W2t;
  const float *b2s, *b2t, *wts, *wtt, *b1s, *b1t, *wes, *wet;
  const float *cond, *Wcs, *Wct;
  const float *eig;
  const float *rec, *recW, *recb;
  float* out;
  float t, a, bc;
  unsigned nk0, nk1, nk2, nk3;   // threefry step keys (speaker, temporal)
  int mode;
};

__global__ __launch_bounds__(256) void k_gemm32(KArgs P){
  int t = threadIdx.x;
  int tr = t >> 4, tc = t & 15;
  int bz = blockIdx.z;
  int m0 = blockIdx.y << 6, n0 = blockIdx.x << 6;
  const float *A, *B; float *C;
  int lda, K, chain = 0;
  if (P.mode == 0){
    A = P.Vt + (size_t)bz*MATSZ; lda = 512; K = 512;
    B = P.x + (size_t)bz*SZF; C = P.xspec + (size_t)bz*SZF;
  } else if (P.mode == 1){
    chain = bz >> 2;
    A = P.xspec + (size_t)bz*SZF; lda = 256; K = 256;
    B = chain ? P.W1t : P.W1s; C = P.hbuf + (size_t)bz*SZF;
  } else if (P.mode == 2){
    chain = bz >> 2;
    A = P.hbuf + (size_t)bz*SZF; lda = 256; K = 256;
    B = chain ? P.W2t : P.W2s; C = P.x + (size_t)bz*SZF;
  } else if (P.mode == 3){
    chain = bz;
    A = P.cond; lda = 256; K = 256;
    B = chain ? P.Wct : P.Wcs; C = P.E + (size_t)chain*4*SZF;
  } else {
    A = P.rec; lda = 256; K = 256;
    B = P.recW; C = P.out;
  }
  __shared__ float As[16][65];
  __shared__ float Bs[16][65];
  float acc[4][4] = {{0}};
  for (int k0=0; k0<K; k0+=16){
    #pragma unroll
    for (int it=0; it<4; it++){
      int idx = t + it*256;
      int r = idx >> 4, kk = idx & 15;
      As[kk][r] = A[(size_t)(m0 + r)*lda + k0 + kk];
    }
    #pragma unroll
    for (int it=0; it<4; it++){
      int idx = t + it*256;
      int c = idx & 63, kk = idx >> 6;
      Bs[kk][c] = B[(size_t)(k0 + kk)*256 + n0 + c];
    }
    __syncthreads();
    #pragma unroll
    for (int kk=0; kk<16; kk++){
      float ar[4], bv[4];
      #pragma unroll
      for (int q=0;q<4;q++){ ar[q] = As[kk][tr + (q<<4)]; bv[q] = Bs[kk][tc + (q<<4)]; }
      #pragma unroll
      for (int q=0;q<4;q++)
        #pragma unroll
        for (int p=0;p<4;p++)
          acc[q][p] = fmaf(ar[q], bv[p], acc[q][p]);
    }
    __syncthreads();
  }
  #pragma unroll
  for (int q=0;q<4;q++){
    #pragma unroll
    for (int p=0;p<4;p++){
      int r = m0 + tr + (q<<4);
      int c = n0 + tc + (p<<4);
      size_t oi = (size_t)r*256 + c;
      float v = acc[q][p];
      if (P.mode == 1){
        v += P.E[(size_t)bz*SZF + oi] + P.t * ((chain ? P.wtt : P.wts)[c]);
        float sg = 1.0f/(1.0f + expf(-v));
        v = v * sg;
      } else if (P.mode == 2){
        float bias = (chain ? P.b2t : P.b2s)[c];
        unsigned j = ((unsigned)(bz & 3))*131072u + (unsigned)oi;
        unsigned kk0 = chain ? P.nk2 : P.nk0;
        unsigned kk1 = chain ? P.nk3 : P.nk1;
        unsigned y0, y1;
        tf2x32(kk0, kk1, 0u, j, &y0, &y1);
        float nz = bits_to_normal(y0 ^ y1);
        v = C[oi] + P.a*(v + bias) + P.bc*nz;
      } else if (P.mode == 3){
        int bb = r >> 9, s2 = r & 511;
        v += (chain ? P.b1t : P.b1s)[c]
           + P.eig[(size_t)(chain*4 + bb)*512 + s2] * ((chain ? P.wet : P.wes)[c]);
      } else if (P.mode == 4){
        v += P.recb[c];
      }
      C[oi] = v;
    }
  }
}

__global__ void k_cond(float* cond, const float* a, const float* v){
  size_t i = (size_t)blockIdx.x*256 + threadIdx.x;
  cond[i] = 0.5f*(a[i] + v[i]);
}

__global__ void k_xinit(float* x, const float* xT){
  size_t i = (size_t)blockIdx.x*256 + threadIdx.x;
  size_t b = i >> 17, off = i & 131071;
  x[i] = xT[((b & 3) << 17) + off];
}

__global__ void k_rec(float* rec, const float* x){
  size_t i = (size_t)blockIdx.x*256 + threadIdx.x;
  rec[i] = 0.5f*(x[i] + x[i + 524288]);
}

__global__ void k_copy(float* out, const float* a, const float* v){
  size_t i = (size_t)blockIdx.x*256 + threadIdx.x;
  out[524288 + i] = (i < 524288) ? a[i] : v[i - 524288];
}

// ------------------------------- host --------------------------------------
extern "C" void kernel_launch(void* const* d_in, const int* in_sizes, int n_in,
                              void* d_out, int out_size, void* d_ws, size_t ws_size,
                              hipStream_t stream){
  const float* f_audio   = (const float*)d_in[1];
  const float* f_visual  = (const float*)d_in[2];
  const float* g_speaker = (const float*)d_in[3];
  const float* g_temporal= (const float*)d_in[4];
  const float* x_T       = (const float*)d_in[6];
  const float* tsW1=(const float*)d_in[7],  *tswe=(const float*)d_in[8],
             * tswt=(const float*)d_in[9],  *tsb1=(const float*)d_in[10],
             * tsWc=(const float*)d_in[11], *tsW2=(const float*)d_in[12],
             * tsb2=(const float*)d_in[13];
  const float* ttW1=(const float*)d_in[14], *ttwe=(const float*)d_in[15],
             * ttwt=(const float*)d_in[16], *ttb1=(const float*)d_in[17],
             * ttWc=(const float*)d_in[18], *ttW2=(const float*)d_in[19],
             * ttb2=(const float*)d_in[20];
  const float* recW=(const float*)d_in[21], *recb=(const float*)d_in[22];
  float* out = (float*)d_out;

  const size_t MB = 1ull << 20;
  if (ws_size < 43*MB) return;

  char* ws = (char*)d_ws;
  double* A64  = (double*)(ws + 0);
  double* Vh   = (double*)(ws + 8*MB);
  double* Zb   = (double*)(ws + 16*MB);
  double* Sm   = (double*)(ws + 24*MB);
  double* smalls = (double*)(ws + 32*MB);
  unsigned* bar = (unsigned*)(smalls + 147456);
  float* cond  = (float*)(ws + 0);
  float* E     = (float*)(ws + 2*MB);
  float* xall  = (float*)(ws + 6*MB);
  float* xspec = (float*)(ws + 10*MB);
  float* hbuf  = (float*)(ws + 14*MB);
  float* Vt32  = (float*)(ws + 34*MB);
  float* eig32 = (float*)(ws + 42*MB);

  // ---- jax.random key schedule (host, exact threefry, PARTITIONABLE) ----
  unsigned f0, f1;
  tf2x32(0u, 42u, 0u, 0u, &f0, &f1);                 // fold_in(key(42), 0)
  unsigned s0,s1,t0,t1;
  tf2x32(f0, f1, 0u, 0u, &s0, &s1);                  // k_s = split[0]
  tf2x32(f0, f1, 0u, 1u, &t0, &t1);                  // k_t = split[1]
  unsigned skeys[100][2], tkeys[100][2];
  for (int k=0; k<100; k++){
    tf2x32(s0, s1, 0u, (unsigned)k, &skeys[k][0], &skeys[k][1]);
    tf2x32(t0, t1, 0u, (unsigned)k, &tkeys[k][0], &tkeys[k][1]);
  }

  hipMemsetAsync(bar, 0, 512, stream);

  // ---- eigh: 2 passes of 4 matrices ----
  for (int pass=0; pass<2; pass++){
    const float* G = pass ? g_temporal : g_speaker;
    k_sytd2_lds<<<NSYB, 256, 0, stream>>>(G, Vh, smalls, bar);
    k_scale<<<4, 256, 0, stream>>>(smalls);
    hipMemsetAsync(Zb, 0, 8*MB, stream);
    hipMemsetAsync(A64, 0, 8*MB, stream);
    k_tear<<<1, 128, 0, stream>>>(smalls);
    k_leaves<<<16, 64, 0, stream>>>(smalls, Zb);
    for (int level=0; level<5; level++){
      int n = 32 << level, mpm = 512/n;
      double* src = (level & 1) ? A64 : Zb;
      double* dst = (level & 1) ? Zb  : A64;
      k_secular<<<dim3(4, mpm), 256, 0, stream>>>(smalls, src, Sm, level);
      k_rot<<<dim3(4, mpm), 256, 0, stream>>>(Sm, smalls, level);
      k_gemm64<<<dim3(n/32, n/32, 4*mpm), 256, 0, stream>>>(src, Sm, dst, level);
    }
    k_backq<<<dim3(4, 64), 256, 0, stream>>>(A64, Vh, smalls);
    k_finalize<<<dim3(4, 1024), 256, 0, stream>>>(A64, smalls, Vt32, eig32, pass);
  }

  // ---- diffusion ----
  k_cond<<<2048, 256, 0, stream>>>(cond, f_audio, f_visual);
  k_xinit<<<4096, 256, 0, stream>>>(xall, x_T);

  KArgs P;
  P.Vt = Vt32; P.xspec = xspec; P.hbuf = hbuf; P.x = xall; P.E = E;
  P.W1s = tsW1; P.W1t = ttW1; P.W2s = tsW2; P.W2t = ttW2;
  P.b2s = tsb2; P.b2t = ttb2; P.wts = tswt; P.wtt = ttwt;
  P.b1s = tsb1; P.b1t = ttb1; P.wes = tswe; P.wet = ttwe;
  P.cond = cond; P.Wcs = tsWc; P.Wct = ttWc;
  P.eig = eig32; P.rec = xspec; P.recW = recW; P.recb = recb; P.out = out;
  P.t = 0.f; P.a = 0.f; P.bc = 0.f;
  P.nk0 = 0; P.nk1 = 0; P.nk2 = 0; P.nk3 = 0;

  P.mode = 3;
  k_gemm32<<<dim3(4, 32, 2), 256, 0, stream>>>(P);

  for (int k=0; k<100; k++){
    float tf = (float)(1.0 - (double)k/99.0);
    float av = (float)(pow(25.0, 2.0*(double)tf) * 0.01);
    float bcv = (float)(pow(25.0, (double)tf) * 0.1);
    P.nk0 = skeys[k][0]; P.nk1 = skeys[k][1];
    P.nk2 = tkeys[k][0]; P.nk3 = tkeys[k][1];
    P.mode = 0;
    k_gemm32<<<dim3(4, 8, 8), 256, 0, stream>>>(P);
    P.mode = 1; P.t = tf;
    k_gemm32<<<dim3(4, 8, 8), 256, 0, stream>>>(P);
    P.mode = 2; P.a = av; P.bc = bcv;
    k_gemm32<<<dim3(4, 8, 8), 256, 0, stream>>>(P);
  }

  k_rec<<<2048, 256, 0, stream>>>(xspec, xall);
  P.mode = 4; P.rec = xspec;
  k_gemm32<<<dim3(4, 32, 1), 256, 0, stream>>>(P);
  k_copy<<<4096, 256, 0, stream>>>(out, f_audio, f_visual);
}

// Round 9
// 43623.380 us; speedup vs baseline: 1.2858x; 1.1542x over previous
//
#include <hip/hip_runtime.h>
#include <math.h>
#include <stdint.h>

// ---------------------------------------------------------------------------
// DualSpectralDiffusion: faithful replication of the JAX reference.
//  - f64 LAPACK-style eigh (multi-block sytd2, A in LDS, FENCE-FREE epoch
//    barrier + relaxed agent atomics for cross-block data) + D&C w/ slaed2
//    deflation mimicry, sign-faithful vs numpy ssyevd
//  - exact threefry2x32 / jax.random replication (PARTITIONABLE stream)
//  - f32 diffusion loop, noise threefry fused into the update-GEMM epilogue
// ---------------------------------------------------------------------------

#define NT 256
#define SZF 131072          // 512*256 floats per (b) tensor
#define MATSZ 262144        // 512*512
#define NB 32               // sytd2 blocks per matrix (16 rows each, in LDS)
#define NSYB (4*NB)         // total sytd2 blocks

#define ALD(p)    __hip_atomic_load((p),  __ATOMIC_RELAXED, __HIP_MEMORY_SCOPE_AGENT)
#define AST(p,v)  __hip_atomic_store((p), (v), __ATOMIC_RELAXED, __HIP_MEMORY_SCOPE_AGENT)

// ----------------------------- threefry ------------------------------------
__host__ __device__ static inline unsigned rotl32(unsigned v, int r){ return (v<<r)|(v>>(32-r)); }

__host__ __device__ static inline void tf2x32(unsigned k0, unsigned k1,
                                              unsigned x0, unsigned x1,
                                              unsigned* o0, unsigned* o1){
  unsigned ks2 = k0 ^ k1 ^ 0x1BD11BDAu;
  x0 += k0; x1 += k1;
#define TF4(r0,r1,r2,r3) \
  x0 += x1; x1 = rotl32(x1,r0); x1 ^= x0; \
  x0 += x1; x1 = rotl32(x1,r1); x1 ^= x0; \
  x0 += x1; x1 = rotl32(x1,r2); x1 ^= x0; \
  x0 += x1; x1 = rotl32(x1,r3); x1 ^= x0;
  TF4(13,15,26,6)  x0 += k1;  x1 += ks2 + 1u;
  TF4(17,29,16,24) x0 += ks2; x1 += k0 + 2u;
  TF4(13,15,26,6)  x0 += k0;  x1 += k1 + 3u;
  TF4(17,29,16,24) x0 += k1;  x1 += ks2 + 4u;
  TF4(13,15,26,6)  x0 += ks2; x1 += k0 + 5u;
#undef TF4
  *o0 = x0; *o1 = x1;
}

// XLA ErfInv f32 polynomial; matches lax.erf_inv expansion.
__device__ static inline float erfinv_xla(float x){
  float w = -log1pf(-x*x);
  float p;
  if (w < 5.0f){
    w -= 2.5f;
    p = 2.81022636e-08f;
    p = fmaf(p, w, 3.43273939e-07f);
    p = fmaf(p, w, -3.5233877e-06f);
    p = fmaf(p, w, -4.39150654e-06f);
    p = fmaf(p, w, 0.00021858087f);
    p = fmaf(p, w, -0.00125372503f);
    p = fmaf(p, w, -0.00417768164f);
    p = fmaf(p, w, 0.246640727f);
    p = fmaf(p, w, 1.50140941f);
  } else {
    w = sqrtf(w) - 3.0f;
    p = -0.000200214257f;
    p = fmaf(p, w, 0.000100950558f);
    p = fmaf(p, w, 0.00134934322f);
    p = fmaf(p, w, -0.00367342844f);
    p = fmaf(p, w, 0.00573950773f);
    p = fmaf(p, w, -0.0076224613f);
    p = fmaf(p, w, 0.00943887047f);
    p = fmaf(p, w, 1.00167406f);
    p = fmaf(p, w, 2.83297682f);
  }
  return p*x;
}

__device__ static inline float bits_to_normal(unsigned bits){
  const float MINV = -0.99999994f;   // nextafter(-1,0) in f32
  float f = __uint_as_float((bits >> 9) | 0x3f800000u) - 1.0f;
  float u = fmaxf(MINV, fmaf(f, 2.0f, MINV));
  return 1.41421356237309515f * erfinv_xla(u);
}

// ------------------------------- eigh --------------------------------------
// smalls layout (doubles): d[s*512], e[2048+s*512], tau[4096+s*512],
// org[6144+s], rot at 8192+(s*32+merge)*1024 (up to 139264),
// acc ping/pong at 139264 (+2048), col ping/pong at 143360 (+2048),
// epoch slots (unsigned, 16-uint stride) at double-index 147456 (8 KB).

// FENCE-FREE per-matrix barrier: block (s,g) publishes epoch to its own
// slot (relaxed atomic store, no cache-maintenance); all NB slots polled
// with relaxed atomic loads. Data ordering: __threadfence_block (waitcnt
// only) + compiler-inserted vmcnt(0) before s_barrier drain each wave's
// sc-flagged (coherent-point) data stores before the epoch store.
__device__ __forceinline__ void gbar2(unsigned* slots, int s, int g, unsigned epoch){
  __threadfence_block();
  __syncthreads();
  int t = threadIdx.x;
  if (t == 0) AST(slots + (s*NB + g)*16, epoch);
  if (t < NB){
    unsigned* sl = slots + (s*NB + t)*16;
    while (ALD(sl) < epoch){ __builtin_amdgcn_s_sleep(1); }
  }
  __syncthreads();
}

// Multi-block Householder tridiagonalization, A resident in LDS.
// 4 matrices x NB blocks; block g owns rows r%NB==g (16 rows, 64KB LDS).
// Cross-block state per iteration: acc/col ping-pong via relaxed agent
// atomics (coherent, no fences). Arithmetic identical to verified r5-r8.
__global__ __launch_bounds__(256) void k_sytd2_lds(const float* G4, double* Vb,
                                                   double* smalls, unsigned* slots,
                                                   unsigned ebase){
  int blk = blockIdx.x;
  int s = blk / NB, g = blk % NB;
  int t = threadIdx.x, wave = t >> 6, lane = t & 63;
  const float* G = G4 + (size_t)s*MATSZ;
  double* V = Vb + (size_t)s*MATSZ;
  double* d  = smalls + (size_t)s*512;
  double* e  = smalls + 2048 + (size_t)s*512;
  double* tu = smalls + 4096 + (size_t)s*512;
  double* acc0 = smalls + 139264 + (size_t)s*512;
  double* acc1 = acc0 + 2048;
  double* col0 = smalls + 143360 + (size_t)s*512;
  double* col1 = col0 + 2048;

  __shared__ double Arows[16][512];   // owned rows r = 32*j + g
  __shared__ double vv[512], wv[512], v2[512], col2[512], acc[512];
  __shared__ double red[4];
  __shared__ double bc[4];

  // ---------- load owned rows into LDS (f32 -> f64) ----------
  for (int j=0; j<16; j++){
    int r = 32*j + g;
    for (int c=t; c<512; c+=256)
      Arows[j][c] = (double)G[(size_t)r*512 + c];
  }

  // ---------- init: reflector 0 (replicated) ----------
  for (int r=t; r<512; r+=256) col2[r] = (r>=1) ? (double)G[(size_t)r*512] : 0.0;
  __syncthreads();
  {
    double part = 0.0;
    for (int r=2+t; r<512; r+=256) part += col2[r]*col2[r];
    #pragma unroll
    for (int off=32; off; off>>=1) part += __shfl_down(part, off, 64);
    if (lane==0) red[wave]=part;
    __syncthreads();
    if (t==0){
      double xsq = red[0]+red[1]+red[2]+red[3];
      double alpha = col2[1];
      double beta,tv,scal;
      if (xsq == 0.0){ beta=alpha; tv=0.0; scal=0.0; }
      else {
        beta = -copysign(sqrt(alpha*alpha + xsq), alpha);   // LAPACK slarfg
        tv = (beta - alpha)/beta;
        scal = 1.0/(alpha - beta);
      }
      if (g==0){ e[0]=beta; tu[0]=tv; }
      bc[0]=tv; bc[1]=scal;
    }
  }
  __syncthreads();
  double tauv = bc[0];
  {
    double scal = bc[1];
    for (int r=t; r<512; r+=256){
      double v = 0.0;
      if (r==1) v = 1.0;
      else if (r>1) v = (tauv==0.0) ? 0.0 : col2[r]*scal;
      vv[r]=v;
    }
  }
  __syncthreads();
  if (g==0){
    for (int r=1+t; r<512; r+=256) V[r] = vv[r];
    for (int r=1+t; r<512; r+=256) AST(&col0[r], (double)G[(size_t)r*512 + 1]);
  }
  // init matvec on owned rows (r>=1, r%NB==g) -> acc0
  {
    int r0 = 1 + ((g - 1) & (NB-1));
    for (int r = r0 + NB*wave; r < 512; r += 4*NB){
      const double* Ar = Arows[r>>5];
      double p = 0.0;
      for (int c=lane; c<512; c+=64) p += Ar[c]*vv[c];
      #pragma unroll
      for (int off=32; off; off>>=1) p += __shfl_down(p, off, 64);
      if (lane==0) AST(&acc0[r], p);
    }
  }

  // ---------- main loop: iteration i applies reflector i, derives i+1 ----------
  for (int i=0; i<510; i++){
    gbar2(slots, s, g, ebase + (unsigned)i);
    int lo=i+1, lo2=i+2;
    double* accR = (i&1) ? acc1 : acc0;
    double* colR = (i&1) ? col1 : col0;
    double* accW = (i&1) ? acc0 : acc1;
    double* colW = (i&1) ? col0 : col1;
    for (int r=lo+t; r<512; r+=256){ acc[r]=ALD(&accR[r]); col2[r]=ALD(&colR[r]); }
    __syncthreads();
    double part = 0.0;
    for (int r=lo+t; r<512; r+=256){ double wr = tauv*acc[r]; wv[r]=wr; part += wr*vv[r]; }
    #pragma unroll
    for (int off=32; off; off>>=1) part += __shfl_down(part, off, 64);
    if (lane==0) red[wave]=part;
    __syncthreads();
    if (t==0){ double dot=red[0]+red[1]+red[2]+red[3]; bc[2] = -0.5*tauv*dot; }
    __syncthreads();
    {
      double alpha2 = bc[2];
      for (int r=lo+t; r<512; r+=256) wv[r] += alpha2*vv[r];
    }
    __syncthreads();
    {
      double wlo = wv[lo], vlo = vv[lo];
      for (int r=lo+t; r<512; r+=256) col2[r] = col2[r] - vv[r]*wlo - wv[r]*vlo;
    }
    __syncthreads();
    part = 0.0;
    for (int r=lo2+1+t; r<512; r+=256) part += col2[r]*col2[r];
    #pragma unroll
    for (int off=32; off; off>>=1) part += __shfl_down(part, off, 64);
    if (lane==0) red[wave]=part;
    __syncthreads();
    if (t==0){
      double xsq = red[0]+red[1]+red[2]+red[3];
      double alpha = col2[lo2];
      double beta,tau2,scal2;
      if (xsq == 0.0){ beta=alpha; tau2=0.0; scal2=0.0; }
      else {
        beta = -copysign(sqrt(alpha*alpha + xsq), alpha);
        tau2 = (beta - alpha)/beta;
        scal2 = 1.0/(alpha - beta);
      }
      if (g==0){ e[lo]=beta; tu[lo]=tau2; }
      bc[0]=tau2; bc[1]=scal2;
    }
    __syncthreads();
    double tau2 = bc[0];
    {
      double scal2 = bc[1];
      for (int r=t; r<512; r+=256){
        double v = 0.0;
        if (r==lo2) v = 1.0;
        else if (r>lo2) v = (tau2==0.0) ? 0.0 : col2[r]*scal2;
        v2[r]=v;
      }
    }
    __syncthreads();
    if (g==0){
      for (int r=lo2+t; r<512; r+=256) V[(size_t)lo*512 + r] = v2[r];
    }
    // fused sweep over owned rows (LDS): A -= v w^T + w v^T ; acc = A_new*v2;
    // export column lo2 into colW.
    {
      double vvc[8], wvc[8], v2c[8];
      #pragma unroll
      for (int j=0;j<8;j++){
        int c = lo + lane + 64*j;
        bool ok = c < 512;
        vvc[j] = ok ? vv[c] : 0.0;
        wvc[j] = ok ? wv[c] : 0.0;
        v2c[j] = ok ? v2[c] : 0.0;
      }
      int r0 = lo + ((g - lo) & (NB-1));
      for (int r = r0 + NB*wave; r < 512; r += 4*NB){
        double* Ar = Arows[r>>5];
        double vr = vv[r], wr = wv[r];
        double p = 0.0;
        #pragma unroll
        for (int j=0;j<8;j++){
          int c = lo + lane + 64*j;
          if (c < 512){
            double an = Ar[c] - vr*wvc[j] - wr*vvc[j];
            Ar[c] = an;
            p += an * v2c[j];
            if (c == lo2) AST(&colW[r], an);
          }
        }
        #pragma unroll
        for (int off=32; off; off>>=1) p += __shfl_down(p, off, 64);
        if (lane==0) AST(&accW[r], p);
      }
    }
    __syncthreads();
    for (int r=t; r<512; r+=256) vv[r] = v2[r];
    tauv = tau2;
    __syncthreads();
  }
  // diag from owned rows (LDS-resident)
  if (t < 16){
    int r = 32*t + g;
    d[r] = Arows[t][r];
  }
}

// sstedc-style pre-scale: org = max(|d|,|e|); d,e /= org
__global__ void k_scale(double* smalls){
  int s = blockIdx.x, t = threadIdx.x;
  double* d = smalls + (size_t)s*512;
  double* e = smalls + 2048 + (size_t)s*512;
  __shared__ double red[256];
  double m = 0.0;
  for (int i=t;i<512;i+=256) m = fmax(m, fabs(d[i]));
  for (int i=t;i<511;i+=256) m = fmax(m, fabs(e[i]));
  red[t]=m; __syncthreads();
  for (int off=128; off; off>>=1){ if (t<off) red[t]=fmax(red[t],red[t+off]); __syncthreads(); }
  double org = red[0]; if (org == 0.0) org = 1.0;
  if (t==0) smalls[6144+s] = org;
  double inv = 1.0/org;
  __syncthreads();
  for (int i=t;i<512;i+=256) d[i] *= inv;
  for (int i=t;i<511;i+=256) e[i] *= inv;
}

__global__ void k_tear(double* smalls){
  int t = threadIdx.x;           // 128 threads: s = t>>5, k = (t&31)+1
  int s = t >> 5, k = (t & 31) + 1;
  if (k <= 31){
    double* d = smalls + (size_t)s*512;
    double* e = smalls + 2048 + (size_t)s*512;
    double ae = fabs(e[16*k - 1]);
    d[16*k - 1] -= ae;
    d[16*k]     -= ae;
  }
}

// 32 leaves of 16 per matrix; 8 leaves per block, threads 0..7 active
__global__ __launch_bounds__(64) void k_leaves(double* smalls, double* Zb){
  __shared__ double LA[8][256];
  __shared__ double LQ[8][256];
  int t = threadIdx.x;
  if (t < 8){
    int bid = blockIdx.x;        // 0..15
    int s = bid >> 2;
    int leaf = (bid & 3)*8 + t;  // 0..31
    double* d = smalls + (size_t)s*512;
    double* e = smalls + 2048 + (size_t)s*512;
    double* Z = Zb + (size_t)s*MATSZ;
    int base = leaf*16;
    double* A = LA[t]; double* Q = LQ[t];
    for (int i=0;i<256;i++){ A[i]=0.0; Q[i]=0.0; }
    for (int i=0;i<16;i++){ A[i*17] = d[base+i]; Q[i*17] = 1.0; }
    for (int i=0;i<15;i++){ double ee = e[base+i]; A[i*16+i+1] = ee; A[(i+1)*16+i] = ee; }
    double nrm = 0.0;
    for (int i=0;i<256;i++) nrm += A[i]*A[i];
    double thr = nrm*1e-30 + 1e-300;
    for (int sweep=0; sweep<60; sweep++){
      double off = 0.0;
      for (int p=0;p<15;p++) for (int q=p+1;q<16;q++){
        double apq = A[p*16+q];
        off += 2.0*apq*apq;
        if (apq == 0.0) continue;
        double theta = 0.5*(A[q*17]-A[p*17])/apq;
        double tt;
        if (fabs(theta) > 1e18) tt = 0.5/theta;
        else tt = copysign(1.0, theta)/(fabs(theta)+sqrt(theta*theta+1.0));
        double cc = 1.0/sqrt(tt*tt+1.0), ss = tt*cc;
        for (int k=0;k<16;k++){
          double akp=A[k*16+p], akq=A[k*16+q];
          A[k*16+p] = cc*akp - ss*akq;
          A[k*16+q] = ss*akp + cc*akq;
        }
        for (int k=0;k<16;k++){
          double apk=A[p*16+k], aqk=A[q*16+k];
          A[p*16+k] = cc*apk - ss*aqk;
          A[q*16+k] = ss*apk + cc*aqk;
        }
        for (int k=0;k<16;k++){
          double qkp=Q[k*16+p], qkq=Q[k*16+q];
          Q[k*16+p] = cc*qkp - ss*qkq;
          Q[k*16+q] = ss*qkp + cc*qkq;
        }
      }
      if (off < thr) break;
    }
    for (int i=0;i<16;i++){
      int mi=i;
      for (int j=i+1;j<16;j++) if (A[j*17] < A[mi*17]) mi=j;
      if (mi!=i){
        double tmp=A[i*17]; A[i*17]=A[mi*17]; A[mi*17]=tmp;
        for (int k=0;k<16;k++){ double q1=Q[k*16+i]; Q[k*16+i]=Q[k*16+mi]; Q[k*16+mi]=q1; }
      }
    }
    for (int i=0;i<16;i++) d[base+i] = A[i*17];
    for (int r=0;r<16;r++)
      for (int c=0;c<16;c++)
        Z[(size_t)(base+r)*512 + base + c] = Q[r*16+c];
  }
}

// one block per merge: LAPACK slaed2 deflation + secular solve + Gu-Eisenstat
__global__ __launch_bounds__(256) void k_secular(double* smalls, const double* Zsrc_b,
                                                 double* Sm_b, int level){
  const double EPS32 = 5.9604644775390625e-8;   // SLAMCH('E') for f32
  const double ISQ2  = 0.70710678118654752440;
  int s = blockIdx.x;
  int hh = 16 << level, n = hh << 1;
  int merge = blockIdx.y, start = merge*n;
  double* d = smalls + (size_t)s*512;
  const double* e = smalls + 2048 + (size_t)s*512;
  const double* Z = Zsrc_b + (size_t)s*MATSZ;
  double* Sm = Sm_b + (size_t)s*MATSZ;
  double* rotg = smalls + 8192 + (size_t)(s*32+merge)*1024;
  __shared__ double ds[512], zl[512], dk[512], zk[512], tauk[512], zh[512], outlam[512];
  __shared__ double rc[256], rs[256];
  __shared__ double red[256];
  __shared__ double sv[2];
  __shared__ int perm[512], kidx[512], Ksk[512], didx[512], outid[512];
  __shared__ int rp[256], rq[256];
  __shared__ int counts[3];
  int t = threadIdx.x;
  if (t == 0){
    int i=0, j=hh, k=0;
    while (i < hh && j < n){
      if (d[start+i] <= d[start+j]) perm[k++]=i++; else perm[k++]=j++;
    }
    while (i < hh) perm[k++]=i++;
    while (j < n)  perm[k++]=j++;
  }
  __syncthreads();
  double eb = e[start+hh-1];
  double rho = 2.0*fabs(eb);
  double sgn = (eb < 0.0) ? -1.0 : 1.0;
  for (int i=t; i<n; i+=NT){
    int p = perm[i];
    ds[i] = d[start+p];
    double zr = (p < hh) ? Z[(size_t)(start+hh-1)*512 + start + p]
                         : sgn * Z[(size_t)(start+hh)*512 + start + p];
    zl[i] = zr * ISQ2;
  }
  __syncthreads();
  double m = 0.0;
  for (int i=t;i<n;i+=NT) m = fmax(m, fabs(zl[i]));
  red[t]=m; __syncthreads();
  for (int off=128; off; off>>=1){ if (t<off) red[t]=fmax(red[t],red[t+off]); __syncthreads(); }
  if (t==0) sv[0] = red[0];
  __syncthreads();
  m = 0.0;
  for (int i=t;i<n;i+=NT) m = fmax(m, fabs(ds[i]));
  red[t]=m; __syncthreads();
  for (int off=128; off; off>>=1){ if (t<off) red[t]=fmax(red[t],red[t+off]); __syncthreads(); }
  if (t==0) sv[1] = red[0];
  __syncthreads();
  double zmaxv = sv[0];
  double tol = 8.0*EPS32*fmax(sv[1], zmaxv);

  if (t == 0){
    int K=0, nd=0, nrot=0;
    if (rho*zmaxv <= tol){
      for (int j=0;j<n;j++) didx[nd++]=j;
    } else {
      int pj = -1;
      for (int j=0;j<n;j++){
        if (rho*fabs(zl[j]) <= tol){
          didx[nd++]=j;
        } else if (pj < 0){
          pj = j;
        } else {
          double s_ = zl[pj], c_ = zl[j];
          double tau2 = sqrt(c_*c_ + s_*s_);
          double tdf = ds[j] - ds[pj];
          double cc = c_/tau2, sr = -s_/tau2;
          if (fabs(tdf*cc*sr) <= tol){
            zl[j] = tau2; zl[pj] = 0.0;
            if (nrot < 256){
              rp[nrot]=perm[pj]; rq[nrot]=perm[j]; rc[nrot]=cc; rs[nrot]=sr; nrot++;
            }
            double tn = ds[pj]*cc*cc + ds[j]*sr*sr;
            ds[j]  = ds[pj]*sr*sr + ds[j]*cc*cc;
            ds[pj] = tn;
            didx[nd++] = pj;
            pj = j;
          } else {
            kidx[K++] = pj;
            pj = j;
          }
        }
      }
      if (pj >= 0) kidx[K++] = pj;
    }
    for (int a=1;a<nd;a++){
      int v = didx[a]; double dv = ds[v]; int b = a-1;
      while (b >= 0 && ds[didx[b]] > dv){ didx[b+1]=didx[b]; b--; }
      didx[b+1] = v;
    }
    counts[0]=K; counts[1]=nd; counts[2]=nrot;
    rotg[0] = (double)nrot;
    for (int i=0;i<nrot;i++){
      rotg[1+4*i]=(double)rp[i]; rotg[2+4*i]=(double)rq[i];
      rotg[3+4*i]=rc[i]; rotg[4+4*i]=rs[i];
    }
  }
  __syncthreads();
  int K = counts[0], nd = counts[1];

  for (int k=t; k<K; k+=NT){ dk[k]=ds[kidx[k]]; zk[k]=zl[kidx[k]]; }
  __syncthreads();

  for (int j2=t; j2<K; j2+=NT){
    int Kb; double lo, hi;
    if (j2 < K-1){
      double mid = 0.5*(dk[j2+1]-dk[j2]);
      double gg = 1.0;
      for (int i=0;i<K;i++){ double dif=(dk[i]-dk[j2])-mid; gg += rho*zk[i]*zk[i]/dif; }
      if (gg >= 0.0){ Kb=j2;   lo=0.0;  hi=mid; }
      else          { Kb=j2+1; lo=-mid; hi=0.0; }
    } else {
      double sz=0.0;
      for (int i=0;i<K;i++) sz += zk[i]*zk[i];
      Kb=K-1; lo=0.0; hi=rho*sz + 1e-300;
    }
    double dK = dk[Kb];
    for (int it=0; it<72; it++){
      double mid = 0.5*(lo+hi);
      if (mid==lo || mid==hi) break;
      double gg = 1.0;
      for (int i=0;i<K;i++){ double dif=(dk[i]-dK)-mid; gg += rho*zk[i]*zk[i]/dif; }
      if (gg < 0.0) lo=mid; else hi=mid;
    }
    Ksk[j2]=Kb; tauk[j2]=0.5*(lo+hi);
  }
  __syncthreads();
  for (int i=t; i<K; i+=NT){
    double P = (Ksk[i]==i) ? tauk[i] : (dk[Ksk[i]]-dk[i]) + tauk[i];
    for (int j=0;j<K;j++){
      if (j==i) continue;
      double num = (dk[Ksk[j]]-dk[i]) + tauk[j];
      double den = dk[j]-dk[i];
      P *= num/den;
    }
    zh[i] = copysign(sqrt(fabs(P/rho)), zk[i]);
  }
  __syncthreads();
  if (t == 0){
    int a=0, b=0;
    for (int j=0;j<n;j++){
      double la = (a<K)  ? (dk[Ksk[a]]+tauk[a]) : 1e300;
      double lb = (b<nd) ? ds[didx[b]]          : 1e300;
      if (la <= lb){ outid[j]=a;     outlam[j]=la; a++; }
      else         { outid[j]=512+b; outlam[j]=lb; b++; }
    }
  }
  __syncthreads();
  for (int j=t; j<n; j+=NT) d[start+j] = outlam[j];
  for (int j=t; j<n; j+=NT){
    double* col = Sm + (size_t)(start+j)*512;
    int id = outid[j];
    for (int i=0;i<n;i++) col[i]=0.0;
    if (id >= 512){
      col[perm[didx[id-512]]] = 1.0;
    } else {
      int k = id;
      double ss_ = 0.0;
      for (int i=0;i<K;i++){
        double dif = (dk[i]-dk[Ksk[k]]) - tauk[k];
        if (dif == 0.0) dif = 1e-300;
        double v = zh[i]/dif;
        col[perm[kidx[i]]] = v; ss_ += v*v;
      }
      double inv = 1.0/sqrt(ss_);
      for (int i=0;i<K;i++) col[perm[kidx[i]]] *= inv;
    }
  }
}

// apply recorded Givens rotations to S rows (reverse order)
__global__ __launch_bounds__(256) void k_rot(double* Sm_b, const double* smalls, int level){
  int s = blockIdx.x, merge = blockIdx.y;
  int hh = 16 << level, n = hh << 1, start = merge*n;
  const double* rotg = smalls + 8192 + (size_t)(s*32+merge)*1024;
  double* Sm = Sm_b + (size_t)s*MATSZ;
  int cnt = (int)rotg[0];
  for (int i=cnt-1; i>=0; i--){
    int p = (int)rotg[1+4*i], q = (int)rotg[2+4*i];
    double c = rotg[3+4*i], sr = rotg[4+4*i];
    for (int j=threadIdx.x; j<n; j+=256){
      double* col = Sm + (size_t)(start+j)*512;
      double a = col[p], b = col[q];
      col[p] = c*a - sr*b;
      col[q] = sr*a + c*b;
    }
    __syncthreads();
  }
}

// Zdst[merge square] = Zsrc[:,local-cols] * S
__global__ __launch_bounds__(256) void k_gemm64(const double* Zsrc_b, const double* Sm_b,
                                                double* Zdst_b, int level){
  int hh = 16 << level, n = hh << 1;
  int mpm = 512 / n;
  int bz = blockIdx.z;
  int s = bz / mpm, merge = bz % mpm;
  int start = merge*n;
  const double* Zs = Zsrc_b + (size_t)s*MATSZ;
  const double* Sm = Sm_b + (size_t)s*MATSZ;
  double* Zd = Zdst_b + (size_t)s*MATSZ;
  int row0 = start + blockIdx.y*32, col0 = start + blockIdx.x*32;
  int t = threadIdx.x;
  int tr = t >> 4, tc = t & 15;
  __shared__ double As[32][33];
  __shared__ double Bs[32][33];
  double a00=0,a01=0,a10=0,a11=0;
  for (int q0=0; q0<n; q0+=32){
    #pragma unroll
    for (int it=0; it<4; it++){
      int idx = t + it*256;
      int r = idx >> 5, q = idx & 31;
      As[r][q] = Zs[(size_t)(row0+r)*512 + start + q0 + q];
    }
    #pragma unroll
    for (int it=0; it<4; it++){
      int idx = t + it*256;
      int c = idx >> 5, q = idx & 31;
      Bs[q][c] = Sm[(size_t)(col0+c)*512 + q0 + q];
    }
    __syncthreads();
    #pragma unroll 8
    for (int q=0;q<32;q++){
      double ar0=As[tr][q], ar1=As[tr+16][q];
      double bc0=Bs[q][tc], bc1=Bs[q][tc+16];
      a00 = fma(ar0,bc0,a00); a01 = fma(ar0,bc1,a01);
      a10 = fma(ar1,bc0,a10); a11 = fma(ar1,bc1,a11);
    }
    __syncthreads();
  }
  Zd[(size_t)(row0+tr)*512 + col0+tc]       = a00;
  Zd[(size_t)(row0+tr)*512 + col0+tc+16]    = a01;
  Zd[(size_t)(row0+tr+16)*512 + col0+tc]    = a10;
  Zd[(size_t)(row0+tr+16)*512 + col0+tc+16] = a11;
}

// apply Q = H(1)...H(n-1) to Z from the left (reverse reflector order)
__global__ __launch_bounds__(256) void k_backq(double* Z2_b, const double* Vh_b,
                                               const double* smalls){
  int s = blockIdx.x, cb = blockIdx.y;
  double* Z = Z2_b + (size_t)s*MATSZ;
  const double* V = Vh_b + (size_t)s*MATSZ;
  const double* tu = smalls + 4096 + (size_t)s*512;
  int cg = threadIdx.x >> 5, lane = threadIdx.x & 31;
  int c = cb*8 + cg;
  __shared__ double zc[8][512];
  for (int r=lane; r<512; r+=32) zc[cg][r] = Z[(size_t)r*512 + c];
  for (int i=509; i>=0; i--){
    double tv = tu[i];
    if (tv == 0.0) continue;
    double wp = 0.0;
    for (int r=i+1+lane; r<512; r+=32) wp += V[(size_t)i*512 + r]*zc[cg][r];
    #pragma unroll
    for (int off=16; off; off>>=1) wp += __shfl_down(wp, off, 32);
    double w = __shfl(wp, 0, 32);
    double tw = tv*w;
    for (int r=i+1+lane; r<512; r+=32) zc[cg][r] -= tw*V[(size_t)i*512 + r];
  }
  for (int r=lane; r<512; r+=32) Z[(size_t)r*512 + c] = zc[cg][r];
}

__global__ void k_finalize(const double* Z2_b, const double* smalls,
                           float* Vt, float* eig, int pass){
  int s = blockIdx.x;
  const double* Z = Z2_b + (size_t)s*MATSZ;
  double org = smalls[6144+s];
  int idx = blockIdx.y*256 + threadIdx.x;   // < 262144
  int r = idx >> 9, c = idx & 511;
  Vt[(size_t)(pass*4+s)*MATSZ + (size_t)c*512 + r] = (float)Z[(size_t)r*512 + c];
  if (idx < 512)
    eig[(size_t)(pass*4+s)*512 + idx] = (float)(smalls[(size_t)s*512 + idx]*org);
}

// --------------------------- diffusion (f32) --------------------------------
struct KArgs {
  const float* Vt;
  float *xspec, *hbuf, *x, *E;
  const float *W1s, *W1t, *W2s, *W2t;
  const float *b2s, *b2t, *wts, *wtt, *b1s, *b1t, *wes, *wet;
  const float *cond, *Wcs, *Wct;
  const float *eig;
  const float *rec, *recW, *recb;
  float* out;
  float t, a, bc;
  unsigned nk0, nk1, nk2, nk3;   // threefry step keys (speaker, temporal)
  int mode;
};

__global__ __launch_bounds__(256) void k_gemm32(KArgs P){
  int t = threadIdx.x;
  int tr = t >> 4, tc = t & 15;
  int bz = blockIdx.z;
  int m0 = blockIdx.y << 6, n0 = blockIdx.x << 6;
  const float *A, *B; float *C;
  int lda, K, chain = 0;
  if (P.mode == 0){
    A = P.Vt + (size_t)bz*MATSZ; lda = 512; K = 512;
    B = P.x + (size_t)bz*SZF; C = P.xspec + (size_t)bz*SZF;
  } else if (P.mode == 1){
    chain = bz >> 2;
    A = P.xspec + (size_t)bz*SZF; lda = 256; K = 256;
    B = chain ? P.W1t : P.W1s; C = P.hbuf + (size_t)bz*SZF;
  } else if (P.mode == 2){
    chain = bz >> 2;
    A = P.hbuf + (size_t)bz*SZF; lda = 256; K = 256;
    B = chain ? P.W2t : P.W2s; C = P.x + (size_t)bz*SZF;
  } else if (P.mode == 3){
    chain = bz;
    A = P.cond; lda = 256; K = 256;
    B = chain ? P.Wct : P.Wcs; C = P.E + (size_t)chain*4*SZF;
  } else {
    A = P.rec; lda = 256; K = 256;
    B = P.recW; C = P.out;
  }
  __shared__ float As[16][65];
  __shared__ float Bs[16][65];
  float acc[4][4] = {{0}};
  for (int k0=0; k0<K; k0+=16){
    #pragma unroll
    for (int it=0; it<4; it++){
      int idx = t + it*256;
      int r = idx >> 4, kk = idx & 15;
      As[kk][r] = A[(size_t)(m0 + r)*lda + k0 + kk];
    }
    #pragma unroll
    for (int it=0; it<4; it++){
      int idx = t + it*256;
      int c = idx & 63, kk = idx >> 6;
      Bs[kk][c] = B[(size_t)(k0 + kk)*256 + n0 + c];
    }
    __syncthreads();
    #pragma unroll
    for (int kk=0; kk<16; kk++){
      float ar[4], bv[4];
      #pragma unroll
      for (int q=0;q<4;q++){ ar[q] = As[kk][tr + (q<<4)]; bv[q] = Bs[kk][tc + (q<<4)]; }
      #pragma unroll
      for (int q=0;q<4;q++)
        #pragma unroll
        for (int p=0;p<4;p++)
          acc[q][p] = fmaf(ar[q], bv[p], acc[q][p]);
    }
    __syncthreads();
  }
  #pragma unroll
  for (int q=0;q<4;q++){
    #pragma unroll
    for (int p=0;p<4;p++){
      int r = m0 + tr + (q<<4);
      int c = n0 + tc + (p<<4);
      size_t oi = (size_t)r*256 + c;
      float v = acc[q][p];
      if (P.mode == 1){
        v += P.E[(size_t)bz*SZF + oi] + P.t * ((chain ? P.wtt : P.wts)[c]);
        float sg = 1.0f/(1.0f + expf(-v));
        v = v * sg;
      } else if (P.mode == 2){
        float bias = (chain ? P.b2t : P.b2s)[c];
        unsigned j = ((unsigned)(bz & 3))*131072u + (unsigned)oi;
        unsigned kk0 = chain ? P.nk2 : P.nk0;
        unsigned kk1 = chain ? P.nk3 : P.nk1;
        unsigned y0, y1;
        tf2x32(kk0, kk1, 0u, j, &y0, &y1);
        float nz = bits_to_normal(y0 ^ y1);
        v = C[oi] + P.a*(v + bias) + P.bc*nz;
      } else if (P.mode == 3){
        int bb = r >> 9, s2 = r & 511;
        v += (chain ? P.b1t : P.b1s)[c]
           + P.eig[(size_t)(chain*4 + bb)*512 + s2] * ((chain ? P.wet : P.wes)[c]);
      } else if (P.mode == 4){
        v += P.recb[c];
      }
      C[oi] = v;
    }
  }
}

__global__ void k_cond(float* cond, const float* a, const float* v){
  size_t i = (size_t)blockIdx.x*256 + threadIdx.x;
  cond[i] = 0.5f*(a[i] + v[i]);
}

__global__ void k_xinit(float* x, const float* xT){
  size_t i = (size_t)blockIdx.x*256 + threadIdx.x;
  size_t b = i >> 17, off = i & 131071;
  x[i] = xT[((b & 3) << 17) + off];
}

__global__ void k_rec(float* rec, const float* x){
  size_t i = (size_t)blockIdx.x*256 + threadIdx.x;
  rec[i] = 0.5f*(x[i] + x[i + 524288]);
}

__global__ void k_copy(float* out, const float* a, const float* v){
  size_t i = (size_t)blockIdx.x*256 + threadIdx.x;
  out[524288 + i] = (i < 524288) ? a[i] : v[i - 524288];
}

// ------------------------------- host --------------------------------------
extern "C" void kernel_launch(void* const* d_in, const int* in_sizes, int n_in,
                              void* d_out, int out_size, void* d_ws, size_t ws_size,
                              hipStream_t stream){
  const float* f_audio   = (const float*)d_in[1];
  const float* f_visual  = (const float*)d_in[2];
  const float* g_speaker = (const float*)d_in[3];
  const float* g_temporal= (const float*)d_in[4];
  const float* x_T       = (const float*)d_in[6];
  const float* tsW1=(const float*)d_in[7],  *tswe=(const float*)d_in[8],
             * tswt=(const float*)d_in[9],  *tsb1=(const float*)d_in[10],
             * tsWc=(const float*)d_in[11], *tsW2=(const float*)d_in[12],
             * tsb2=(const float*)d_in[13];
  const float* ttW1=(const float*)d_in[14], *ttwe=(const float*)d_in[15],
             * ttwt=(const float*)d_in[16], *ttb1=(const float*)d_in[17],
             * ttWc=(const float*)d_in[18], *ttW2=(const float*)d_in[19],
             * ttb2=(const float*)d_in[20];
  const float* recW=(const float*)d_in[21], *recb=(const float*)d_in[22];
  float* out = (float*)d_out;

  const size_t MB = 1ull << 20;
  if (ws_size < 43*MB) return;

  char* ws = (char*)d_ws;
  double* A64  = (double*)(ws + 0);
  double* Vh   = (double*)(ws + 8*MB);
  double* Zb   = (double*)(ws + 16*MB);
  double* Sm   = (double*)(ws + 24*MB);
  double* smalls = (double*)(ws + 32*MB);
  unsigned* slots = (unsigned*)(smalls + 147456);   // 8 KB of epoch slots
  float* cond  = (float*)(ws + 0);
  float* E     = (float*)(ws + 2*MB);
  float* xall  = (float*)(ws + 6*MB);
  float* xspec = (float*)(ws + 10*MB);
  float* hbuf  = (float*)(ws + 14*MB);
  float* Vt32  = (float*)(ws + 34*MB);
  float* eig32 = (float*)(ws + 42*MB);

  // ---- jax.random key schedule (host, exact threefry, PARTITIONABLE) ----
  unsigned f0, f1;
  tf2x32(0u, 42u, 0u, 0u, &f0, &f1);                 // fold_in(key(42), 0)
  unsigned s0,s1,t0,t1;
  tf2x32(f0, f1, 0u, 0u, &s0, &s1);                  // k_s = split[0]
  tf2x32(f0, f1, 0u, 1u, &t0, &t1);                  // k_t = split[1]
  unsigned skeys[100][2], tkeys[100][2];
  for (int k=0; k<100; k++){
    tf2x32(s0, s1, 0u, (unsigned)k, &skeys[k][0], &skeys[k][1]);
    tf2x32(t0, t1, 0u, (unsigned)k, &tkeys[k][0], &tkeys[k][1]);
  }

  hipMemsetAsync(slots, 0, 8192, stream);

  // ---- eigh: 2 passes of 4 matrices ----
  for (int pass=0; pass<2; pass++){
    const float* G = pass ? g_temporal : g_speaker;
    k_sytd2_lds<<<NSYB, 256, 0, stream>>>(G, Vh, smalls, slots,
                                          (unsigned)(pass*512 + 1));
    k_scale<<<4, 256, 0, stream>>>(smalls);
    hipMemsetAsync(Zb, 0, 8*MB, stream);
    hipMemsetAsync(A64, 0, 8*MB, stream);
    k_tear<<<1, 128, 0, stream>>>(smalls);
    k_leaves<<<16, 64, 0, stream>>>(smalls, Zb);
    for (int level=0; level<5; level++){
      int n = 32 << level, mpm = 512/n;
      double* src = (level & 1) ? A64 : Zb;
      double* dst = (level & 1) ? Zb  : A64;
      k_secular<<<dim3(4, mpm), 256, 0, stream>>>(smalls, src, Sm, level);
      k_rot<<<dim3(4, mpm), 256, 0, stream>>>(Sm, smalls, level);
      k_gemm64<<<dim3(n/32, n/32, 4*mpm), 256, 0, stream>>>(src, Sm, dst, level);
    }
    k_backq<<<dim3(4, 64), 256, 0, stream>>>(A64, Vh, smalls);
    k_finalize<<<dim3(4, 1024), 256, 0, stream>>>(A64, smalls, Vt32, eig32, pass);
  }

  // ---- diffusion ----
  k_cond<<<2048, 256, 0, stream>>>(cond, f_audio, f_visual);
  k_xinit<<<4096, 256, 0, stream>>>(xall, x_T);

  KArgs P;
  P.Vt = Vt32; P.xspec = xspec; P.hbuf = hbuf; P.x = xall; P.E = E;
  P.W1s = tsW1; P.W1t = ttW1; P.W2s = tsW2; P.W2t = ttW2;
  P.b2s = tsb2; P.b2t = ttb2; P.wts = tswt; P.wtt = ttwt;
  P.b1s = tsb1; P.b1t = ttb1; P.wes = tswe; P.wet = ttwe;
  P.cond = cond; P.Wcs = tsWc; P.Wct = ttWc;
  P.eig = eig32; P.rec = xspec; P.recW = recW; P.recb = recb; P.out = out;
  P.t = 0.f; P.a = 0.f; P.bc = 0.f;
  P.nk0 = 0; P.nk1 = 0; P.nk2 = 0; P.nk3 = 0;

  P.mode = 3;
  k_gemm32<<<dim3(4, 32, 2), 256, 0, stream>>>(P);

  for (int k=0; k<100; k++){
    float tf = (float)(1.0 - (double)k/99.0);
    float av = (float)(pow(25.0, 2.0*(double)tf) * 0.01);
    float bcv = (float)(pow(25.0, (double)tf) * 0.1);
    P.nk0 = skeys[k][0]; P.nk1 = skeys[k][1];
    P.nk2 = tkeys[k][0]; P.nk3 = tkeys[k][1];
    P.mode = 0;
    k_gemm32<<<dim3(4, 8, 8), 256, 0, stream>>>(P);
    P.mode = 1; P.t = tf;
    k_gemm32<<<dim3(4, 8, 8), 256, 0, stream>>>(P);
    P.mode = 2; P.a = av; P.bc = bcv;
    k_gemm32<<<dim3(4, 8, 8), 256, 0, stream>>>(P);
  }

  k_rec<<<2048, 256, 0, stream>>>(xspec, xall);
  P.mode = 4; P.rec = xspec;
  k_gemm32<<<dim3(4, 32, 1), 256, 0, stream>>>(P);
  k_copy<<<4096, 256, 0, stream>>>(out, f_audio, f_visual);
}

// Round 10
// 40446.832 us; speedup vs baseline: 1.3868x; 1.0785x over previous
//
#include <hip/hip_runtime.h>
#include <math.h>
#include <stdint.h>

// ---------------------------------------------------------------------------
// DualSpectralDiffusion: faithful replication of the JAX reference.
//  - f64 LAPACK-style eigh (8-matrix-batched multi-block sytd2, A in LDS,
//    fence-free epoch barrier, fused phase chain) + D&C w/ slaed2 deflation
//    mimicry, sign-faithful vs numpy ssyevd
//  - exact threefry2x32 / jax.random replication (PARTITIONABLE stream)
//  - f32 diffusion loop, noise threefry fused into the update-GEMM epilogue
// ---------------------------------------------------------------------------

#define NT 256
#define SZF 131072          // 512*256 floats per (b) tensor
#define MATSZ 262144        // 512*512
#define NB 32               // sytd2 blocks per matrix (16 rows each, in LDS)

#define ALD(p)    __hip_atomic_load((p),  __ATOMIC_RELAXED, __HIP_MEMORY_SCOPE_AGENT)
#define AST(p,v)  __hip_atomic_store((p), (v), __ATOMIC_RELAXED, __HIP_MEMORY_SCOPE_AGENT)

// smalls layout (doubles), 8 slots:
//   d    : sg*512                [0,     4096)
//   e    : 4096  + sg*512        [4096,  8192)
//   tau  : 8192  + sg*512        [8192, 12288)
//   org  : 12288 + sg            [12288,12296)
//   rot  : 12544 + (sg*32+m)*1024             -> ends 274688
//   accpp: 274688 + sg*512 (pong +4096)       -> ends 282880
//   colpp: 282880 + sg*512 (pong +4096)       -> ends 291072
//   slots: (unsigned) at double-index 291072, (sg*32+g)*16 uints, 16 KB

// ----------------------------- threefry ------------------------------------
__host__ __device__ static inline unsigned rotl32(unsigned v, int r){ return (v<<r)|(v>>(32-r)); }

__host__ __device__ static inline void tf2x32(unsigned k0, unsigned k1,
                                              unsigned x0, unsigned x1,
                                              unsigned* o0, unsigned* o1){
  unsigned ks2 = k0 ^ k1 ^ 0x1BD11BDAu;
  x0 += k0; x1 += k1;
#define TF4(r0,r1,r2,r3) \
  x0 += x1; x1 = rotl32(x1,r0); x1 ^= x0; \
  x0 += x1; x1 = rotl32(x1,r1); x1 ^= x0; \
  x0 += x1; x1 = rotl32(x1,r2); x1 ^= x0; \
  x0 += x1; x1 = rotl32(x1,r3); x1 ^= x0;
  TF4(13,15,26,6)  x0 += k1;  x1 += ks2 + 1u;
  TF4(17,29,16,24) x0 += ks2; x1 += k0 + 2u;
  TF4(13,15,26,6)  x0 += k0;  x1 += k1 + 3u;
  TF4(17,29,16,24) x0 += k1;  x1 += ks2 + 4u;
  TF4(13,15,26,6)  x0 += ks2; x1 += k0 + 5u;
#undef TF4
  *o0 = x0; *o1 = x1;
}

// XLA ErfInv f32 polynomial; matches lax.erf_inv expansion.
__device__ static inline float erfinv_xla(float x){
  float w = -log1pf(-x*x);
  float p;
  if (w < 5.0f){
    w -= 2.5f;
    p = 2.81022636e-08f;
    p = fmaf(p, w, 3.43273939e-07f);
    p = fmaf(p, w, -3.5233877e-06f);
    p = fmaf(p, w, -4.39150654e-06f);
    p = fmaf(p, w, 0.00021858087f);
    p = fmaf(p, w, -0.00125372503f);
    p = fmaf(p, w, -0.00417768164f);
    p = fmaf(p, w, 0.246640727f);
    p = fmaf(p, w, 1.50140941f);
  } else {
    w = sqrtf(w) - 3.0f;
    p = -0.000200214257f;
    p = fmaf(p, w, 0.000100950558f);
    p = fmaf(p, w, 0.00134934322f);
    p = fmaf(p, w, -0.00367342844f);
    p = fmaf(p, w, 0.00573950773f);
    p = fmaf(p, w, -0.0076224613f);
    p = fmaf(p, w, 0.00943887047f);
    p = fmaf(p, w, 1.00167406f);
    p = fmaf(p, w, 2.83297682f);
  }
  return p*x;
}

__device__ static inline float bits_to_normal(unsigned bits){
  const float MINV = -0.99999994f;   // nextafter(-1,0) in f32
  float f = __uint_as_float((bits >> 9) | 0x3f800000u) - 1.0f;
  float u = fmaxf(MINV, fmaf(f, 2.0f, MINV));
  return 1.41421356237309515f * erfinv_xla(u);
}

// ------------------------------- eigh --------------------------------------
// FENCE-FREE per-matrix barrier: block (sg,g) publishes epoch to its own
// slot (relaxed agent store, no cache maintenance); NB slots polled with
// relaxed agent loads. Ordering: __threadfence_block (waitcnt only) drains
// the sc-flagged data stores before the epoch store.
__device__ __forceinline__ void gbar2(unsigned* slots, int sg, int g, unsigned epoch){
  __threadfence_block();
  __syncthreads();
  int t = threadIdx.x;
  if (t == 0) AST(slots + (sg*NB + g)*16, epoch);
  if (t < NB){
    unsigned* sl = slots + (sg*NB + t)*16;
    while (ALD(sl) < epoch){ __builtin_amdgcn_s_sleep(1); }
  }
  __syncthreads();
}

// Multi-block Householder tridiagonalization, A resident in LDS, fused
// phase chain. Up to 8 matrices x NB blocks; block g owns rows r%NB==g.
__global__ __launch_bounds__(256) void k_sytd2_lds(const float* Gs, const float* Gt,
                                                   double* Vb, double* smalls,
                                                   unsigned* slots, int sbase, int vlocal){
  int s_local = blockIdx.x / NB, g = blockIdx.x % NB;
  int sg = sbase + s_local;
  const float* G = (sg < 4) ? (Gs + (size_t)sg*MATSZ) : (Gt + (size_t)(sg-4)*MATSZ);
  int vslot = vlocal ? s_local : sg;
  double* V = Vb + (size_t)vslot*MATSZ;
  double* d  = smalls + (size_t)sg*512;
  double* e  = smalls + 4096 + (size_t)sg*512;
  double* tu = smalls + 8192 + (size_t)sg*512;
  double* acc0 = smalls + 274688 + (size_t)sg*512;
  double* acc1 = acc0 + 4096;
  double* col0 = smalls + 282880 + (size_t)sg*512;
  double* col1 = col0 + 4096;
  int t = threadIdx.x, wave = t >> 6, lane = t & 63;

  __shared__ double Arows[16][512];   // owned rows r = 32*j + g
  __shared__ double vv[512], wv[512], col2[512], acc[512];
  __shared__ double red[4];
  __shared__ double bc[4];

  // ---------- load owned rows into LDS (f32 -> f64) ----------
  for (int j=0; j<16; j++){
    int r = 32*j + g;
    for (int c=t; c<512; c+=256)
      Arows[j][c] = (double)G[(size_t)r*512 + c];
  }

  // ---------- init: reflector 0 (replicated) ----------
  for (int r=t; r<512; r+=256) col2[r] = (r>=1) ? (double)G[(size_t)r*512] : 0.0;
  __syncthreads();
  {
    double part = 0.0;
    for (int r=2+t; r<512; r+=256) part += col2[r]*col2[r];
    #pragma unroll
    for (int off=32; off; off>>=1) part += __shfl_down(part, off, 64);
    if (lane==0) red[wave]=part;
    __syncthreads();
    if (t==0){
      double xsq = red[0]+red[1]+red[2]+red[3];
      double alpha = col2[1];
      double beta,tv,scal;
      if (xsq == 0.0){ beta=alpha; tv=0.0; scal=0.0; }
      else {
        beta = -copysign(sqrt(alpha*alpha + xsq), alpha);   // LAPACK slarfg
        tv = (beta - alpha)/beta;
        scal = 1.0/(alpha - beta);
      }
      if (g==0){ e[0]=beta; tu[0]=tv; }
      bc[0]=tv; bc[1]=scal;
    }
  }
  __syncthreads();
  double tauv = bc[0];
  {
    double scal = bc[1];
    for (int r=t; r<512; r+=256){
      double v = 0.0;
      if (r==1) v = 1.0;
      else if (r>1) v = (tauv==0.0) ? 0.0 : col2[r]*scal;
      vv[r]=v;
    }
  }
  __syncthreads();
  if (g==0){
    for (int r=1+t; r<512; r+=256) V[r] = vv[r];
    for (int r=1+t; r<512; r+=256) AST(&col0[r], (double)G[(size_t)r*512 + 1]);
  }
  // init matvec on owned rows (r>=1, r%NB==g) -> acc0
  {
    int r0 = 1 + ((g - 1) & (NB-1));
    for (int r = r0 + NB*wave; r < 512; r += 4*NB){
      const double* Ar = Arows[r>>5];
      double p = 0.0;
      for (int c=lane; c<512; c+=64) p += Ar[c]*vv[c];
      #pragma unroll
      for (int off=32; off; off>>=1) p += __shfl_down(p, off, 64);
      if (lane==0) AST(&acc0[r], p);
    }
  }

  // ---------- main loop (fused phases) ----------
  for (int i=0; i<510; i++){
    gbar2(slots, sg, g, (unsigned)(i+1));
    int lo=i+1, lo2=i+2;
    double* accR = (i&1) ? acc1 : acc0;
    double* colR = (i&1) ? col1 : col0;
    double* accW = (i&1) ? acc0 : acc1;
    double* colW = (i&1) ? col0 : col1;
    // pass1: read acc/col + dot partial (same per-thread subset as before)
    double part = 0.0;
    for (int r=lo+t; r<512; r+=256){
      double a_ = ALD(&accR[r]);
      double c_ = ALD(&colR[r]);
      acc[r]=a_; col2[r]=c_;
      part += (tauv*a_)*vv[r];
    }
    #pragma unroll
    for (int off=32; off; off>>=1) part += __shfl_down(part, off, 64);
    if (lane==0) red[wave]=part;
    __syncthreads();
    if (t==0){ double dot=red[0]+red[1]+red[2]+red[3]; bc[2] = -0.5*tauv*dot; }
    __syncthreads();
    // pass2: w = tau*acc + alpha2*v ; col2 -= v*wlo + w*vlo   (wlo replicated)
    {
      double alpha2 = bc[2];
      double vlo = vv[lo];
      double wlo = fma(alpha2, vlo, tauv*acc[lo]);
      for (int r=lo+t; r<512; r+=256){
        double wr = fma(alpha2, vv[r], tauv*acc[r]);
        wv[r]=wr;
        col2[r] = col2[r] - vv[r]*wlo - wr*vlo;
      }
    }
    __syncthreads();
    // pass2b: xsq over r>=lo2+1 (original mapping)
    part = 0.0;
    for (int r=lo2+1+t; r<512; r+=256) part += col2[r]*col2[r];
    #pragma unroll
    for (int off=32; off; off>>=1) part += __shfl_down(part, off, 64);
    if (lane==0) red[wave]=part;
    __syncthreads();
    if (t==0){
      double xsq = red[0]+red[1]+red[2]+red[3];
      double alpha = col2[lo2];
      double beta,tau2,scal2;
      if (xsq == 0.0){ beta=alpha; tau2=0.0; scal2=0.0; }
      else {
        beta = -copysign(sqrt(alpha*alpha + xsq), alpha);
        tau2 = (beta - alpha)/beta;
        scal2 = 1.0/(alpha - beta);
      }
      if (g==0){ e[lo]=beta; tu[lo]=tau2; }
      bc[0]=tau2; bc[1]=scal2;
    }
    __syncthreads();
    double tau2 = bc[0], scal2 = bc[1];
    // sweep over owned rows (LDS): A -= v w^T + w v^T ; acc = A_new*v2
    // (v2 derived on the fly from col2); export column lo2 into colW.
    {
      double vvc[8], wvc[8], v2c[8];
      #pragma unroll
      for (int j=0;j<8;j++){
        int c = lo + lane + 64*j;
        bool ok = c < 512;
        vvc[j] = ok ? vv[c] : 0.0;
        wvc[j] = ok ? wv[c] : 0.0;
        double v2v = 0.0;
        if (ok){
          if (c==lo2) v2v = 1.0;
          else if (c>lo2) v2v = (tau2==0.0) ? 0.0 : col2[c]*scal2;
        }
        v2c[j] = v2v;
      }
      int r0 = lo + ((g - lo) & (NB-1));
      for (int r = r0 + NB*wave; r < 512; r += 4*NB){
        double* Ar = Arows[r>>5];
        double vr = vv[r], wr = wv[r];
        double p = 0.0;
        #pragma unroll
        for (int j=0;j<8;j++){
          int c = lo + lane + 64*j;
          if (c < 512){
            double an = Ar[c] - vr*wvc[j] - wr*vvc[j];
            Ar[c] = an;
            p += an * v2c[j];
            if (c == lo2) AST(&colW[r], an);
          }
        }
        #pragma unroll
        for (int off=32; off; off>>=1) p += __shfl_down(p, off, 64);
        if (lane==0) AST(&accW[r], p);
      }
    }
    __syncthreads();
    // vv <- v2 (in place) ; V write by g==0
    for (int r=t; r<512; r+=256){
      double v = 0.0;
      if (r==lo2) v = 1.0;
      else if (r>lo2) v = (tau2==0.0) ? 0.0 : col2[r]*scal2;
      vv[r]=v;
      if (g==0 && r>=lo2) V[(size_t)lo*512 + r] = v;
    }
    tauv = tau2;
    // no trailing sync: gbar2 entry syncs
  }
  // diag from owned rows (LDS-resident)
  if (t < 16){
    int r = 32*t + g;
    d[r] = Arows[t][r];
  }
}

// sstedc-style pre-scale: org = max(|d|,|e|); d,e /= org
__global__ void k_scale(double* smalls, int sbase){
  int sg = sbase + blockIdx.x, t = threadIdx.x;
  double* d = smalls + (size_t)sg*512;
  double* e = smalls + 4096 + (size_t)sg*512;
  __shared__ double red[256];
  double m = 0.0;
  for (int i=t;i<512;i+=256) m = fmax(m, fabs(d[i]));
  for (int i=t;i<511;i+=256) m = fmax(m, fabs(e[i]));
  red[t]=m; __syncthreads();
  for (int off=128; off; off>>=1){ if (t<off) red[t]=fmax(red[t],red[t+off]); __syncthreads(); }
  double org = red[0]; if (org == 0.0) org = 1.0;
  if (t==0) smalls[12288+sg] = org;
  double inv = 1.0/org;
  __syncthreads();
  for (int i=t;i<512;i+=256) d[i] *= inv;
  for (int i=t;i<511;i+=256) e[i] *= inv;
}

__global__ void k_tear(double* smalls, int sbase){
  int t = threadIdx.x;           // 128 threads: s = t>>5, k = (t&31)+1
  int sg = sbase + (t >> 5), k = (t & 31) + 1;
  if (k <= 31){
    double* d = smalls + (size_t)sg*512;
    double* e = smalls + 4096 + (size_t)sg*512;
    double ae = fabs(e[16*k - 1]);
    d[16*k - 1] -= ae;
    d[16*k]     -= ae;
  }
}

// 32 leaves of 16 per matrix; 8 leaves per block, threads 0..7 active
__global__ __launch_bounds__(64) void k_leaves(double* smalls, double* Zb, int sbase){
  __shared__ double LA[8][256];
  __shared__ double LQ[8][256];
  int t = threadIdx.x;
  if (t < 8){
    int bid = blockIdx.x;        // 0..15
    int s_local = bid >> 2;
    int sg = sbase + s_local;
    int leaf = (bid & 3)*8 + t;  // 0..31
    double* d = smalls + (size_t)sg*512;
    double* e = smalls + 4096 + (size_t)sg*512;
    double* Z = Zb + (size_t)s_local*MATSZ;
    int base = leaf*16;
    double* A = LA[t]; double* Q = LQ[t];
    for (int i=0;i<256;i++){ A[i]=0.0; Q[i]=0.0; }
    for (int i=0;i<16;i++){ A[i*17] = d[base+i]; Q[i*17] = 1.0; }
    for (int i=0;i<15;i++){ double ee = e[base+i]; A[i*16+i+1] = ee; A[(i+1)*16+i] = ee; }
    double nrm = 0.0;
    for (int i=0;i<256;i++) nrm += A[i]*A[i];
    double thr = nrm*1e-30 + 1e-300;
    for (int sweep=0; sweep<60; sweep++){
      double off = 0.0;
      for (int p=0;p<15;p++) for (int q=p+1;q<16;q++){
        double apq = A[p*16+q];
        off += 2.0*apq*apq;
        if (apq == 0.0) continue;
        double theta = 0.5*(A[q*17]-A[p*17])/apq;
        double tt;
        if (fabs(theta) > 1e18) tt = 0.5/theta;
        else tt = copysign(1.0, theta)/(fabs(theta)+sqrt(theta*theta+1.0));
        double cc = 1.0/sqrt(tt*tt+1.0), ss = tt*cc;
        for (int k=0;k<16;k++){
          double akp=A[k*16+p], akq=A[k*16+q];
          A[k*16+p] = cc*akp - ss*akq;
          A[k*16+q] = ss*akp + cc*akq;
        }
        for (int k=0;k<16;k++){
          double apk=A[p*16+k], aqk=A[q*16+k];
          A[p*16+k] = cc*apk - ss*aqk;
          A[q*16+k] = ss*apk + cc*aqk;
        }
        for (int k=0;k<16;k++){
          double qkp=Q[k*16+p], qkq=Q[k*16+q];
          Q[k*16+p] = cc*qkp - ss*qkq;
          Q[k*16+q] = ss*qkp + cc*qkq;
        }
      }
      if (off < thr) break;
    }
    for (int i=0;i<16;i++){
      int mi=i;
      for (int j=i+1;j<16;j++) if (A[j*17] < A[mi*17]) mi=j;
      if (mi!=i){
        double tmp=A[i*17]; A[i*17]=A[mi*17]; A[mi*17]=tmp;
        for (int k=0;k<16;k++){ double q1=Q[k*16+i]; Q[k*16+i]=Q[k*16+mi]; Q[k*16+mi]=q1; }
      }
    }
    for (int i=0;i<16;i++) d[base+i] = A[i*17];
    for (int r=0;r<16;r++)
      for (int c=0;c<16;c++)
        Z[(size_t)(base+r)*512 + base + c] = Q[r*16+c];
  }
}

// one block per merge: LAPACK slaed2 deflation + secular solve + Gu-Eisenstat
__global__ __launch_bounds__(256) void k_secular(double* smalls, const double* Zsrc_b,
                                                 double* Sm_b, int level, int sbase){
  const double EPS32 = 5.9604644775390625e-8;   // SLAMCH('E') for f32
  const double ISQ2  = 0.70710678118654752440;
  int s_local = blockIdx.x;
  int sg = sbase + s_local;
  int hh = 16 << level, n = hh << 1;
  int merge = blockIdx.y, start = merge*n;
  double* d = smalls + (size_t)sg*512;
  const double* e = smalls + 4096 + (size_t)sg*512;
  const double* Z = Zsrc_b + (size_t)s_local*MATSZ;
  double* Sm = Sm_b + (size_t)s_local*MATSZ;
  double* rotg = smalls + 12544 + (size_t)(sg*32+merge)*1024;
  __shared__ double ds[512], zl[512], dk[512], zk[512], tauk[512], zh[512], outlam[512];
  __shared__ double rc[256], rs[256];
  __shared__ double red[256];
  __shared__ double sv[2];
  __shared__ int perm[512], kidx[512], Ksk[512], didx[512], outid[512];
  __shared__ int rp[256], rq[256];
  __shared__ int counts[3];
  int t = threadIdx.x;
  if (t == 0){
    int i=0, j=hh, k=0;
    while (i < hh && j < n){
      if (d[start+i] <= d[start+j]) perm[k++]=i++; else perm[k++]=j++;
    }
    while (i < hh) perm[k++]=i++;
    while (j < n)  perm[k++]=j++;
  }
  __syncthreads();
  double eb = e[start+hh-1];
  double rho = 2.0*fabs(eb);
  double sgn = (eb < 0.0) ? -1.0 : 1.0;
  for (int i=t; i<n; i+=NT){
    int p = perm[i];
    ds[i] = d[start+p];
    double zr = (p < hh) ? Z[(size_t)(start+hh-1)*512 + start + p]
                         : sgn * Z[(size_t)(start+hh)*512 + start + p];
    zl[i] = zr * ISQ2;
  }
  __syncthreads();
  double m = 0.0;
  for (int i=t;i<n;i+=NT) m = fmax(m, fabs(zl[i]));
  red[t]=m; __syncthreads();
  for (int off=128; off; off>>=1){ if (t<off) red[t]=fmax(red[t],red[t+off]); __syncthreads(); }
  if (t==0) sv[0] = red[0];
  __syncthreads();
  m = 0.0;
  for (int i=t;i<n;i+=NT) m = fmax(m, fabs(ds[i]));
  red[t]=m; __syncthreads();
  for (int off=128; off; off>>=1){ if (t<off) red[t]=fmax(red[t],red[t+off]); __syncthreads(); }
  if (t==0) sv[1] = red[0];
  __syncthreads();
  double zmaxv = sv[0];
  double tol = 8.0*EPS32*fmax(sv[1], zmaxv);

  if (t == 0){
    int K=0, nd=0, nrot=0;
    if (rho*zmaxv <= tol){
      for (int j=0;j<n;j++) didx[nd++]=j;
    } else {
      int pj = -1;
      for (int j=0;j<n;j++){
        if (rho*fabs(zl[j]) <= tol){
          didx[nd++]=j;
        } else if (pj < 0){
          pj = j;
        } else {
          double s_ = zl[pj], c_ = zl[j];
          double tau2 = sqrt(c_*c_ + s_*s_);
          double tdf = ds[j] - ds[pj];
          double cc = c_/tau2, sr = -s_/tau2;
          if (fabs(tdf*cc*sr) <= tol){
            zl[j] = tau2; zl[pj] = 0.0;
            if (nrot < 256){
              rp[nrot]=perm[pj]; rq[nrot]=perm[j]; rc[nrot]=cc; rs[nrot]=sr; nrot++;
            }
            double tn = ds[pj]*cc*cc + ds[j]*sr*sr;
            ds[j]  = ds[pj]*sr*sr + ds[j]*cc*cc;
            ds[pj] = tn;
            didx[nd++] = pj;
            pj = j;
          } else {
            kidx[K++] = pj;
            pj = j;
          }
        }
      }
      if (pj >= 0) kidx[K++] = pj;
    }
    for (int a=1;a<nd;a++){
      int v = didx[a]; double dv = ds[v]; int b = a-1;
      while (b >= 0 && ds[didx[b]] > dv){ didx[b+1]=didx[b]; b--; }
      didx[b+1] = v;
    }
    counts[0]=K; counts[1]=nd; counts[2]=nrot;
    rotg[0] = (double)nrot;
    for (int i=0;i<nrot;i++){
      rotg[1+4*i]=(double)rp[i]; rotg[2+4*i]=(double)rq[i];
      rotg[3+4*i]=rc[i]; rotg[4+4*i]=rs[i];
    }
  }
  __syncthreads();
  int K = counts[0], nd = counts[1];

  for (int k=t; k<K; k+=NT){ dk[k]=ds[kidx[k]]; zk[k]=zl[kidx[k]]; }
  __syncthreads();

  for (int j2=t; j2<K; j2+=NT){
    int Kb; double lo, hi;
    if (j2 < K-1){
      double mid = 0.5*(dk[j2+1]-dk[j2]);
      double gg = 1.0;
      for (int i=0;i<K;i++){ double dif=(dk[i]-dk[j2])-mid; gg += rho*zk[i]*zk[i]/dif; }
      if (gg >= 0.0){ Kb=j2;   lo=0.0;  hi=mid; }
      else          { Kb=j2+1; lo=-mid; hi=0.0; }
    } else {
      double sz=0.0;
      for (int i=0;i<K;i++) sz += zk[i]*zk[i];
      Kb=K-1; lo=0.0; hi=rho*sz + 1e-300;
    }
    double dK = dk[Kb];
    for (int it=0; it<72; it++){
      double mid = 0.5*(lo+hi);
      if (mid==lo || mid==hi) break;
      double gg = 1.0;
      for (int i=0;i<K;i++){ double dif=(dk[i]-dK)-mid; gg += rho*zk[i]*zk[i]/dif; }
      if (gg < 0.0) lo=mid; else hi=mid;
    }
    Ksk[j2]=Kb; tauk[j2]=0.5*(lo+hi);
  }
  __syncthreads();
  for (int i=t; i<K; i+=NT){
    double P = (Ksk[i]==i) ? tauk[i] : (dk[Ksk[i]]-dk[i]) + tauk[i];
    for (int j=0;j<K;j++){
      if (j==i) continue;
      double num = (dk[Ksk[j]]-dk[i]) + tauk[j];
      double den = dk[j]-dk[i];
      P *= num/den;
    }
    zh[i] = copysign(sqrt(fabs(P/rho)), zk[i]);
  }
  __syncthreads();
  if (t == 0){
    int a=0, b=0;
    for (int j=0;j<n;j++){
      double la = (a<K)  ? (dk[Ksk[a]]+tauk[a]) : 1e300;
      double lb = (b<nd) ? ds[didx[b]]          : 1e300;
      if (la <= lb){ outid[j]=a;     outlam[j]=la; a++; }
      else         { outid[j]=512+b; outlam[j]=lb; b++; }
    }
  }
  __syncthreads();
  for (int j=t; j<n; j+=NT) d[start+j] = outlam[j];
  for (int j=t; j<n; j+=NT){
    double* col = Sm + (size_t)(start+j)*512;
    int id = outid[j];
    for (int i=0;i<n;i++) col[i]=0.0;
    if (id >= 512){
      col[perm[didx[id-512]]] = 1.0;
    } else {
      int k = id;
      double ss_ = 0.0;
      for (int i=0;i<K;i++){
        double dif = (dk[i]-dk[Ksk[k]]) - tauk[k];
        if (dif == 0.0) dif = 1e-300;
        double v = zh[i]/dif;
        col[perm[kidx[i]]] = v; ss_ += v*v;
      }
      double inv = 1.0/sqrt(ss_);
      for (int i=0;i<K;i++) col[perm[kidx[i]]] *= inv;
    }
  }
}

// apply recorded Givens rotations to S rows (reverse order)
__global__ __launch_bounds__(256) void k_rot(double* Sm_b, const double* smalls,
                                             int level, int sbase){
  int s_local = blockIdx.x, merge = blockIdx.y;
  int sg = sbase + s_local;
  int hh = 16 << level, n = hh << 1, start = merge*n;
  const double* rotg = smalls + 12544 + (size_t)(sg*32+merge)*1024;
  double* Sm = Sm_b + (size_t)s_local*MATSZ;
  int cnt = (int)rotg[0];
  for (int i=cnt-1; i>=0; i--){
    int p = (int)rotg[1+4*i], q = (int)rotg[2+4*i];
    double c = rotg[3+4*i], sr = rotg[4+4*i];
    for (int j=threadIdx.x; j<n; j+=256){
      double* col = Sm + (size_t)(start+j)*512;
      double a = col[p], b = col[q];
      col[p] = c*a - sr*b;
      col[q] = sr*a + c*b;
    }
    __syncthreads();
  }
}

// Zdst[merge square] = Zsrc[:,local-cols] * S
__global__ __launch_bounds__(256) void k_gemm64(const double* Zsrc_b, const double* Sm_b,
                                                double* Zdst_b, int level){
  int hh = 16 << level, n = hh << 1;
  int mpm = 512 / n;
  int bz = blockIdx.z;
  int s = bz / mpm, merge = bz % mpm;
  int start = merge*n;
  const double* Zs = Zsrc_b + (size_t)s*MATSZ;
  const double* Sm = Sm_b + (size_t)s*MATSZ;
  double* Zd = Zdst_b + (size_t)s*MATSZ;
  int row0 = start + blockIdx.y*32, col0 = start + blockIdx.x*32;
  int t = threadIdx.x;
  int tr = t >> 4, tc = t & 15;
  __shared__ double As[32][33];
  __shared__ double Bs[32][33];
  double a00=0,a01=0,a10=0,a11=0;
  for (int q0=0; q0<n; q0+=32){
    #pragma unroll
    for (int it=0; it<4; it++){
      int idx = t + it*256;
      int r = idx >> 5, q = idx & 31;
      As[r][q] = Zs[(size_t)(row0+r)*512 + start + q0 + q];
    }
    #pragma unroll
    for (int it=0; it<4; it++){
      int idx = t + it*256;
      int c = idx >> 5, q = idx & 31;
      Bs[q][c] = Sm[(size_t)(col0+c)*512 + q0 + q];
    }
    __syncthreads();
    #pragma unroll 8
    for (int q=0;q<32;q++){
      double ar0=As[tr][q], ar1=As[tr+16][q];
      double bc0=Bs[q][tc], bc1=Bs[q][tc+16];
      a00 = fma(ar0,bc0,a00); a01 = fma(ar0,bc1,a01);
      a10 = fma(ar1,bc0,a10); a11 = fma(ar1,bc1,a11);
    }
    __syncthreads();
  }
  Zd[(size_t)(row0+tr)*512 + col0+tc]       = a00;
  Zd[(size_t)(row0+tr)*512 + col0+tc+16]    = a01;
  Zd[(size_t)(row0+tr+16)*512 + col0+tc]    = a10;
  Zd[(size_t)(row0+tr+16)*512 + col0+tc+16] = a11;
}

// apply Q = H(1)...H(n-1) to Z from the left (reverse reflector order)
__global__ __launch_bounds__(256) void k_backq(double* Z2_b, const double* Vh_b,
                                               const double* smalls, int sbase, int vlocal){
  int s_local = blockIdx.x, cb = blockIdx.y;
  int sg = sbase + s_local;
  double* Z = Z2_b + (size_t)s_local*MATSZ;
  const double* V = Vh_b + (size_t)(vlocal ? s_local : sg)*MATSZ;
  const double* tu = smalls + 8192 + (size_t)sg*512;
  int cg = threadIdx.x >> 5, lane = threadIdx.x & 31;
  int c = cb*8 + cg;
  __shared__ double zc[8][512];
  for (int r=lane; r<512; r+=32) zc[cg][r] = Z[(size_t)r*512 + c];
  for (int i=509; i>=0; i--){
    double tv = tu[i];
    if (tv == 0.0) continue;
    double wp = 0.0;
    for (int r=i+1+lane; r<512; r+=32) wp += V[(size_t)i*512 + r]*zc[cg][r];
    #pragma unroll
    for (int off=16; off; off>>=1) wp += __shfl_down(wp, off, 32);
    double w = __shfl(wp, 0, 32);
    double tw = tv*w;
    for (int r=i+1+lane; r<512; r+=32) zc[cg][r] -= tw*V[(size_t)i*512 + r];
  }
  for (int r=lane; r<512; r+=32) Z[(size_t)r*512 + c] = zc[cg][r];
}

__global__ void k_finalize(const double* Z2_b, const double* smalls,
                           float* Vt, float* eig, int pass, int sbase){
  int s_local = blockIdx.x;
  int sg = sbase + s_local;
  const double* Z = Z2_b + (size_t)s_local*MATSZ;
  double org = smalls[12288+sg];
  int idx = blockIdx.y*256 + threadIdx.x;   // < 262144
  int r = idx >> 9, c = idx & 511;
  Vt[(size_t)(pass*4+s_local)*MATSZ + (size_t)c*512 + r] = (float)Z[(size_t)r*512 + c];
  if (idx < 512)
    eig[(size_t)(pass*4+s_local)*512 + idx] = (float)(smalls[(size_t)sg*512 + idx]*org);
}

// --------------------------- diffusion (f32) --------------------------------
struct KArgs {
  const float* Vt;
  float *xspec, *hbuf, *x, *E;
  const float *W1s, *W1t, *W2s, *W2t;
  const float *b2s, *b2t, *wts, *wtt, *b1s, *b1t, *wes, *wet;
  const float *cond, *Wcs, *Wct;
  const float *eig;
  const float *rec, *recW, *recb;
  float* out;
  float t, a, bc;
  unsigned nk0, nk1, nk2, nk3;   // threefry step keys (speaker, temporal)
  int mode;
};

__global__ __launch_bounds__(256) void k_gemm32(KArgs P){
  int t = threadIdx.x;
  int tr = t >> 4, tc = t & 15;
  int bz = blockIdx.z;
  int m0 = blockIdx.y << 6, n0 = blockIdx.x << 6;
  const float *A, *B; float *C;
  int lda, K, chain = 0;
  if (P.mode == 0){
    A = P.Vt + (size_t)bz*MATSZ; lda = 512; K = 512;
    B = P.x + (size_t)bz*SZF; C = P.xspec + (size_t)bz*SZF;
  } else if (P.mode == 1){
    chain = bz >> 2;
    A = P.xspec + (size_t)bz*SZF; lda = 256; K = 256;
    B = chain ? P.W1t : P.W1s; C = P.hbuf + (size_t)bz*SZF;
  } else if (P.mode == 2){
    chain = bz >> 2;
    A = P.hbuf + (size_t)bz*SZF; lda = 256; K = 256;
    B = chain ? P.W2t : P.W2s; C = P.x + (size_t)bz*SZF;
  } else if (P.mode == 3){
    chain = bz;
    A = P.cond; lda = 256; K = 256;
    B = chain ? P.Wct : P.Wcs; C = P.E + (size_t)chain*4*SZF;
  } else {
    A = P.rec; lda = 256; K = 256;
    B = P.recW; C = P.out;
  }
  __shared__ float As[16][65];
  __shared__ float Bs[16][65];
  float acc[4][4] = {{0}};
  for (int k0=0; k0<K; k0+=16){
    #pragma unroll
    for (int it=0; it<4; it++){
      int idx = t + it*256;
      int r = idx >> 4, kk = idx & 15;
      As[kk][r] = A[(size_t)(m0 + r)*lda + k0 + kk];
    }
    #pragma unroll
    for (int it=0; it<4; it++){
      int idx = t + it*256;
      int c = idx & 63, kk = idx >> 6;
      Bs[kk][c] = B[(size_t)(k0 + kk)*256 + n0 + c];
    }
    __syncthreads();
    #pragma unroll
    for (int kk=0; kk<16; kk++){
      float ar[4], bv[4];
      #pragma unroll
      for (int q=0;q<4;q++){ ar[q] = As[kk][tr + (q<<4)]; bv[q] = Bs[kk][tc + (q<<4)]; }
      #pragma unroll
      for (int q=0;q<4;q++)
        #pragma unroll
        for (int p=0;p<4;p++)
          acc[q][p] = fmaf(ar[q], bv[p], acc[q][p]);
    }
    __syncthreads();
  }
  #pragma unroll
  for (int q=0;q<4;q++){
    #pragma unroll
    for (int p=0;p<4;p++){
      int r = m0 + tr + (q<<4);
      int c = n0 + tc + (p<<4);
      size_t oi = (size_t)r*256 + c;
      float v = acc[q][p];
      if (P.mode == 1){
        v += P.E[(size_t)bz*SZF + oi] + P.t * ((chain ? P.wtt : P.wts)[c]);
        float sg = 1.0f/(1.0f + expf(-v));
        v = v * sg;
      } else if (P.mode == 2){
        float bias = (chain ? P.b2t : P.b2s)[c];
        unsigned j = ((unsigned)(bz & 3))*131072u + (unsigned)oi;
        unsigned kk0 = chain ? P.nk2 : P.nk0;
        unsigned kk1 = chain ? P.nk3 : P.nk1;
        unsigned y0, y1;
        tf2x32(kk0, kk1, 0u, j, &y0, &y1);
        float nz = bits_to_normal(y0 ^ y1);
        v = C[oi] + P.a*(v + bias) + P.bc*nz;
      } else if (P.mode == 3){
        int bb = r >> 9, s2 = r & 511;
        v += (chain ? P.b1t : P.b1s)[c]
           + P.eig[(size_t)(chain*4 + bb)*512 + s2] * ((chain ? P.wet : P.wes)[c]);
      } else if (P.mode == 4){
        v += P.recb[c];
      }
      C[oi] = v;
    }
  }
}

__global__ void k_cond(float* cond, const float* a, const float* v){
  size_t i = (size_t)blockIdx.x*256 + threadIdx.x;
  cond[i] = 0.5f*(a[i] + v[i]);
}

__global__ void k_xinit(float* x, const float* xT){
  size_t i = (size_t)blockIdx.x*256 + threadIdx.x;
  size_t b = i >> 17, off = i & 131071;
  x[i] = xT[((b & 3) << 17) + off];
}

__global__ void k_rec(float* rec, const float* x){
  size_t i = (size_t)blockIdx.x*256 + threadIdx.x;
  rec[i] = 0.5f*(x[i] + x[i + 524288]);
}

__global__ void k_copy(float* out, const float* a, const float* v){
  size_t i = (size_t)blockIdx.x*256 + threadIdx.x;
  out[524288 + i] = (i < 524288) ? a[i] : v[i - 524288];
}

// ------------------------------- host --------------------------------------
extern "C" void kernel_launch(void* const* d_in, const int* in_sizes, int n_in,
                              void* d_out, int out_size, void* d_ws, size_t ws_size,
                              hipStream_t stream){
  const float* f_audio   = (const float*)d_in[1];
  const float* f_visual  = (const float*)d_in[2];
  const float* g_speaker = (const float*)d_in[3];
  const float* g_temporal= (const float*)d_in[4];
  const float* x_T       = (const float*)d_in[6];
  const float* tsW1=(const float*)d_in[7],  *tswe=(const float*)d_in[8],
             * tswt=(const float*)d_in[9],  *tsb1=(const float*)d_in[10],
             * tsWc=(const float*)d_in[11], *tsW2=(const float*)d_in[12],
             * tsb2=(const float*)d_in[13];
  const float* ttW1=(const float*)d_in[14], *ttwe=(const float*)d_in[15],
             * ttwt=(const float*)d_in[16], *ttb1=(const float*)d_in[17],
             * ttWc=(const float*)d_in[18], *ttW2=(const float*)d_in[19],
             * ttb2=(const float*)d_in[20];
  const float* recW=(const float*)d_in[21], *recb=(const float*)d_in[22];
  float* out = (float*)d_out;

  const size_t MB = 1ull << 20;
  if (ws_size < 43*MB) return;
  bool big = (ws_size >= 52*MB);

  char* ws = (char*)d_ws;
  double *Vh, *A64, *Zb, *Sm, *smalls;
  float *Vt32, *eig32;
  if (big){
    Vh   = (double*)(ws + 0);        // 8 slots, 16 MB
    A64  = (double*)(ws + 16*MB);    // 4 slots
    Zb   = (double*)(ws + 24*MB);
    Sm   = (double*)(ws + 32*MB);
    smalls = (double*)(ws + 40*MB);  // ~2.3 MB
    Vt32 = (float*)(ws + 43*MB);     // 8 MB
    eig32= (float*)(ws + 51*MB);
  } else {
    A64  = (double*)(ws + 0);
    Vh   = (double*)(ws + 8*MB);     // 4 slots
    Zb   = (double*)(ws + 16*MB);
    Sm   = (double*)(ws + 24*MB);
    smalls = (double*)(ws + 32*MB);
    Vt32 = (float*)(ws + 34*MB + MB/2);
    eig32= (float*)(ws + 42*MB + MB/2);
  }
  unsigned* slots = (unsigned*)(smalls + 291072);
  // diffusion overlay (both layouts; regions dead after eigh)
  float* cond  = (float*)(ws + 0);
  float* E     = (float*)(ws + 2*MB);
  float* xall  = (float*)(ws + 6*MB);
  float* xspec = (float*)(ws + 10*MB);
  float* hbuf  = (float*)(ws + 14*MB);

  // ---- jax.random key schedule (host, exact threefry, PARTITIONABLE) ----
  unsigned f0, f1;
  tf2x32(0u, 42u, 0u, 0u, &f0, &f1);                 // fold_in(key(42), 0)
  unsigned s0,s1,t0,t1;
  tf2x32(f0, f1, 0u, 0u, &s0, &s1);                  // k_s = split[0]
  tf2x32(f0, f1, 0u, 1u, &t0, &t1);                  // k_t = split[1]
  unsigned skeys[100][2], tkeys[100][2];
  for (int k=0; k<100; k++){
    tf2x32(s0, s1, 0u, (unsigned)k, &skeys[k][0], &skeys[k][1]);
    tf2x32(t0, t1, 0u, (unsigned)k, &tkeys[k][0], &tkeys[k][1]);
  }

  hipMemsetAsync(slots, 0, 16384, stream);

  // ---- eigh ----
  if (big){
    // all 8 matrices tridiagonalized concurrently (256 blocks, 1/CU)
    k_sytd2_lds<<<8*NB, 256, 0, stream>>>(g_speaker, g_temporal, Vh, smalls, slots,
                                          0, /*vlocal=*/0);
  }
  for (int pass=0; pass<2; pass++){
    int sbase = 4*pass;
    if (!big){
      k_sytd2_lds<<<4*NB, 256, 0, stream>>>(g_speaker, g_temporal, Vh, smalls, slots,
                                            sbase, /*vlocal=*/1);
    }
    k_scale<<<4, 256, 0, stream>>>(smalls, sbase);
    hipMemsetAsync(Zb, 0, 8*MB, stream);
    hipMemsetAsync(A64, 0, 8*MB, stream);
    k_tear<<<1, 128, 0, stream>>>(smalls, sbase);
    k_leaves<<<16, 64, 0, stream>>>(smalls, Zb, sbase);
    for (int level=0; level<5; level++){
      int n = 32 << level, mpm = 512/n;
      double* src = (level & 1) ? A64 : Zb;
      double* dst = (level & 1) ? Zb  : A64;
      k_secular<<<dim3(4, mpm), 256, 0, stream>>>(smalls, src, Sm, level, sbase);
      k_rot<<<dim3(4, mpm), 256, 0, stream>>>(Sm, smalls, level, sbase);
      k_gemm64<<<dim3(n/32, n/32, 4*mpm), 256, 0, stream>>>(src, Sm, dst, level);
    }
    k_backq<<<dim3(4, 64), 256, 0, stream>>>(A64, Vh, smalls, sbase, big ? 0 : 1);
    k_finalize<<<dim3(4, 1024), 256, 0, stream>>>(A64, smalls, Vt32, eig32, pass, sbase);
  }

  // ---- diffusion ----
  k_cond<<<2048, 256, 0, stream>>>(cond, f_audio, f_visual);
  k_xinit<<<4096, 256, 0, stream>>>(xall, x_T);

  KArgs P;
  P.Vt = Vt32; P.xspec = xspec; P.hbuf = hbuf; P.x = xall; P.E = E;
  P.W1s = tsW1; P.W1t = ttW1; P.W2s = tsW2; P.W2t = ttW2;
  P.b2s = tsb2; P.b2t = ttb2; P.wts = tswt; P.wtt = ttwt;
  P.b1s = tsb1; P.b1t = ttb1; P.wes = tswe; P.wet = ttwe;
  P.cond = cond; P.Wcs = tsWc; P.Wct = ttWc;
  P.eig = eig32; P.rec = xspec; P.recW = recW; P.recb = recb; P.out = out;
  P.t = 0.f; P.a = 0.f; P.bc = 0.f;
  P.nk0 = 0; P.nk1 = 0; P.nk2 = 0; P.nk3 = 0;

  P.mode = 3;
  k_gemm32<<<dim3(4, 32, 2), 256, 0, stream>>>(P);

  for (int k=0; k<100; k++){
    float tf = (float)(1.0 - (double)k/99.0);
    float av = (float)(pow(25.0, 2.0*(double)tf) * 0.01);
    float bcv = (float)(pow(25.0, (double)tf) * 0.1);
    P.nk0 = skeys[k][0]; P.nk1 = skeys[k][1];
    P.nk2 = tkeys[k][0]; P.nk3 = tkeys[k][1];
    P.mode = 0;
    k_gemm32<<<dim3(4, 8, 8), 256, 0, stream>>>(P);
    P.mode = 1; P.t = tf;
    k_gemm32<<<dim3(4, 8, 8), 256, 0, stream>>>(P);
    P.mode = 2; P.a = av; P.bc = bcv;
    k_gemm32<<<dim3(4, 8, 8), 256, 0, stream>>>(P);
  }

  k_rec<<<2048, 256, 0, stream>>>(xspec, xall);
  P.mode = 4; P.rec = xspec;
  k_gemm32<<<dim3(4, 32, 1), 256, 0, stream>>>(P);
  k_copy<<<4096, 256, 0, stream>>>(out, f_audio, f_visual);
}

// Round 11
// 40225.238 us; speedup vs baseline: 1.3944x; 1.0055x over previous
//
#include <hip/hip_runtime.h>
#include <math.h>
#include <stdint.h>

// ---------------------------------------------------------------------------
// DualSpectralDiffusion: faithful replication of the JAX reference.
//  - f64 LAPACK-style eigh (8-matrix-batched multi-block sytd2 in 43MB, A in
//    LDS, fence-free epoch barrier) + D&C w/ slaed2 deflation mimicry,
//    sign-faithful vs numpy ssyevd
//  - exact threefry2x32 / jax.random replication (PARTITIONABLE stream)
//  - f32 diffusion loop, noise threefry fused into the update-GEMM epilogue
// ---------------------------------------------------------------------------

#define NT 256
#define SZF 131072          // 512*256 floats per (b) tensor
#define MATSZ 262144        // 512*512
#define NB 32               // sytd2 blocks per matrix (16 rows each, in LDS)

#define ALD(p)    __hip_atomic_load((p),  __ATOMIC_RELAXED, __HIP_MEMORY_SCOPE_AGENT)
#define AST(p,v)  __hip_atomic_store((p), (v), __ATOMIC_RELAXED, __HIP_MEMORY_SCOPE_AGENT)

// ws layout (bytes):
//   V (f64, 8 slots)      [0, 16MB)   -- Vt32 overlays: pass0 [0,4MB), pass1 [8,12MB)
//   A64 (4 slots)         [16,24MB)   -- diffusion overlay: cond@16, E@18
//   Zb  (4 slots)         [24,32MB)   --                    xall@22, xspec@26, hbuf@30
//   Sm  (4 slots)         [32,40MB)
//   smalls (f64)          [40MB, ~42.3MB)
//   eig32                 [42.5MB, +16KB)
// smalls (double idx): d[sg*512], e@4096, tau@8192, org@12288,
//   rot@12544+(sg*32+m)*1024 (ends 274688), accpp@274688(+4096 pong),
//   colpp@282880(+4096 pong), slots(unsigned)@291072 (16KB)

// ----------------------------- threefry ------------------------------------
__host__ __device__ static inline unsigned rotl32(unsigned v, int r){ return (v<<r)|(v>>(32-r)); }

__host__ __device__ static inline void tf2x32(unsigned k0, unsigned k1,
                                              unsigned x0, unsigned x1,
                                              unsigned* o0, unsigned* o1){
  unsigned ks2 = k0 ^ k1 ^ 0x1BD11BDAu;
  x0 += k0; x1 += k1;
#define TF4(r0,r1,r2,r3) \
  x0 += x1; x1 = rotl32(x1,r0); x1 ^= x0; \
  x0 += x1; x1 = rotl32(x1,r1); x1 ^= x0; \
  x0 += x1; x1 = rotl32(x1,r2); x1 ^= x0; \
  x0 += x1; x1 = rotl32(x1,r3); x1 ^= x0;
  TF4(13,15,26,6)  x0 += k1;  x1 += ks2 + 1u;
  TF4(17,29,16,24) x0 += ks2; x1 += k0 + 2u;
  TF4(13,15,26,6)  x0 += k0;  x1 += k1 + 3u;
  TF4(17,29,16,24) x0 += k1;  x1 += ks2 + 4u;
  TF4(13,15,26,6)  x0 += ks2; x1 += k0 + 5u;
#undef TF4
  *o0 = x0; *o1 = x1;
}

// XLA ErfInv f32 polynomial; matches lax.erf_inv expansion.
__device__ static inline float erfinv_xla(float x){
  float w = -log1pf(-x*x);
  float p;
  if (w < 5.0f){
    w -= 2.5f;
    p = 2.81022636e-08f;
    p = fmaf(p, w, 3.43273939e-07f);
    p = fmaf(p, w, -3.5233877e-06f);
    p = fmaf(p, w, -4.39150654e-06f);
    p = fmaf(p, w, 0.00021858087f);
    p = fmaf(p, w, -0.00125372503f);
    p = fmaf(p, w, -0.00417768164f);
    p = fmaf(p, w, 0.246640727f);
    p = fmaf(p, w, 1.50140941f);
  } else {
    w = sqrtf(w) - 3.0f;
    p = -0.000200214257f;
    p = fmaf(p, w, 0.000100950558f);
    p = fmaf(p, w, 0.00134934322f);
    p = fmaf(p, w, -0.00367342844f);
    p = fmaf(p, w, 0.00573950773f);
    p = fmaf(p, w, -0.0076224613f);
    p = fmaf(p, w, 0.00943887047f);
    p = fmaf(p, w, 1.00167406f);
    p = fmaf(p, w, 2.83297682f);
  }
  return p*x;
}

__device__ static inline float bits_to_normal(unsigned bits){
  const float MINV = -0.99999994f;   // nextafter(-1,0) in f32
  float f = __uint_as_float((bits >> 9) | 0x3f800000u) - 1.0f;
  float u = fmaxf(MINV, fmaf(f, 2.0f, MINV));
  return 1.41421356237309515f * erfinv_xla(u);
}

// ------------------------------- eigh --------------------------------------
// FENCE-FREE per-matrix barrier: block (sg,g) publishes epoch to its own
// slot; NB slots polled with relaxed agent loads.
__device__ __forceinline__ void gbar2(unsigned* slots, int sg, int g, unsigned epoch){
  __threadfence_block();
  __syncthreads();
  int t = threadIdx.x;
  if (t == 0) AST(slots + (sg*NB + g)*16, epoch);
  if (t < NB){
    unsigned* sl = slots + (sg*NB + t)*16;
    while (ALD(sl) < epoch){ __builtin_amdgcn_s_sleep(1); }
  }
  __syncthreads();
}

// Multi-block Householder tridiagonalization, A resident in LDS, fused
// phase chain. 8 matrices x NB blocks (256 blocks = 1/CU); block g owns
// rows r%NB==g. Arithmetic identical to verified r9/r10 kernels.
__global__ __launch_bounds__(256) void k_sytd2_lds(const float* Gs, const float* Gt,
                                                   double* Vb, double* smalls,
                                                   unsigned* slots){
  int sg = blockIdx.x / NB, g = blockIdx.x % NB;
  const float* G = (sg < 4) ? (Gs + (size_t)sg*MATSZ) : (Gt + (size_t)(sg-4)*MATSZ);
  double* V = Vb + (size_t)sg*MATSZ;
  double* d  = smalls + (size_t)sg*512;
  double* e  = smalls + 4096 + (size_t)sg*512;
  double* tu = smalls + 8192 + (size_t)sg*512;
  double* acc0 = smalls + 274688 + (size_t)sg*512;
  double* acc1 = acc0 + 4096;
  double* col0 = smalls + 282880 + (size_t)sg*512;
  double* col1 = col0 + 4096;
  int t = threadIdx.x, wave = t >> 6, lane = t & 63;

  __shared__ double Arows[16][512];   // owned rows r = 32*j + g
  __shared__ double vv[512], wv[512], col2[512], acc[512];
  __shared__ double red[4];
  __shared__ double bc[4];

  // ---------- load owned rows into LDS (f32 -> f64) ----------
  for (int j=0; j<16; j++){
    int r = 32*j + g;
    for (int c=t; c<512; c+=256)
      Arows[j][c] = (double)G[(size_t)r*512 + c];
  }

  // ---------- init: reflector 0 (replicated) ----------
  for (int r=t; r<512; r+=256) col2[r] = (r>=1) ? (double)G[(size_t)r*512] : 0.0;
  __syncthreads();
  {
    double part = 0.0;
    for (int r=2+t; r<512; r+=256) part += col2[r]*col2[r];
    #pragma unroll
    for (int off=32; off; off>>=1) part += __shfl_down(part, off, 64);
    if (lane==0) red[wave]=part;
    __syncthreads();
    if (t==0){
      double xsq = red[0]+red[1]+red[2]+red[3];
      double alpha = col2[1];
      double beta,tv,scal;
      if (xsq == 0.0){ beta=alpha; tv=0.0; scal=0.0; }
      else {
        beta = -copysign(sqrt(alpha*alpha + xsq), alpha);   // LAPACK slarfg
        tv = (beta - alpha)/beta;
        scal = 1.0/(alpha - beta);
      }
      if (g==0){ e[0]=beta; tu[0]=tv; }
      bc[0]=tv; bc[1]=scal;
    }
  }
  __syncthreads();
  double tauv = bc[0];
  {
    double scal = bc[1];
    for (int r=t; r<512; r+=256){
      double v = 0.0;
      if (r==1) v = 1.0;
      else if (r>1) v = (tauv==0.0) ? 0.0 : col2[r]*scal;
      vv[r]=v;
      if (r>=1 && (r & (NB-1))==g) V[r] = v;   // distributed V write
    }
  }
  __syncthreads();
  if (g==0){
    for (int r=1+t; r<512; r+=256) AST(&col0[r], (double)G[(size_t)r*512 + 1]);
  }
  // init matvec on owned rows (r>=1, r%NB==g) -> acc0
  {
    int r0 = 1 + ((g - 1) & (NB-1));
    for (int r = r0 + NB*wave; r < 512; r += 4*NB){
      const double* Ar = Arows[r>>5];
      double p = 0.0;
      for (int c=lane; c<512; c+=64) p += Ar[c]*vv[c];
      #pragma unroll
      for (int off=32; off; off>>=1) p += __shfl_down(p, off, 64);
      if (lane==0) AST(&acc0[r], p);
    }
  }

  // ---------- main loop (fused phases) ----------
  for (int i=0; i<510; i++){
    gbar2(slots, sg, g, (unsigned)(i+1));
    int lo=i+1, lo2=i+2;
    double* accR = (i&1) ? acc1 : acc0;
    double* colR = (i&1) ? col1 : col0;
    double* accW = (i&1) ? acc0 : acc1;
    double* colW = (i&1) ? col0 : col1;
    // pass1: read acc/col + dot partial
    double part = 0.0;
    for (int r=lo+t; r<512; r+=256){
      double a_ = ALD(&accR[r]);
      double c_ = ALD(&colR[r]);
      acc[r]=a_; col2[r]=c_;
      part += (tauv*a_)*vv[r];
    }
    #pragma unroll
    for (int off=32; off; off>>=1) part += __shfl_down(part, off, 64);
    if (lane==0) red[wave]=part;
    __syncthreads();
    if (t==0){ double dot=red[0]+red[1]+red[2]+red[3]; bc[2] = -0.5*tauv*dot; }
    __syncthreads();
    // pass2: w = tau*acc + alpha2*v ; col2 -= v*wlo + w*vlo
    {
      double alpha2 = bc[2];
      double vlo = vv[lo];
      double wlo = fma(alpha2, vlo, tauv*acc[lo]);
      for (int r=lo+t; r<512; r+=256){
        double wr = fma(alpha2, vv[r], tauv*acc[r]);
        wv[r]=wr;
        col2[r] = col2[r] - vv[r]*wlo - wr*vlo;
      }
    }
    __syncthreads();
    // pass2b: xsq over r>=lo2+1
    part = 0.0;
    for (int r=lo2+1+t; r<512; r+=256) part += col2[r]*col2[r];
    #pragma unroll
    for (int off=32; off; off>>=1) part += __shfl_down(part, off, 64);
    if (lane==0) red[wave]=part;
    __syncthreads();
    if (t==0){
      double xsq = red[0]+red[1]+red[2]+red[3];
      double alpha = col2[lo2];
      double beta,tau2,scal2;
      if (xsq == 0.0){ beta=alpha; tau2=0.0; scal2=0.0; }
      else {
        beta = -copysign(sqrt(alpha*alpha + xsq), alpha);
        tau2 = (beta - alpha)/beta;
        scal2 = 1.0/(alpha - beta);
      }
      if (g==0){ e[lo]=beta; tu[lo]=tau2; }
      bc[0]=tau2; bc[1]=scal2;
    }
    __syncthreads();
    double tau2 = bc[0], scal2 = bc[1];
    // sweep over owned rows (LDS): A -= v w^T + w v^T ; acc = A_new*v2
    // (v2 derived on the fly); export column lo2 into colW.
    {
      double vvc[8], wvc[8], v2c[8];
      #pragma unroll
      for (int j=0;j<8;j++){
        int c = lo + lane + 64*j;
        bool ok = c < 512;
        vvc[j] = ok ? vv[c] : 0.0;
        wvc[j] = ok ? wv[c] : 0.0;
        double v2v = 0.0;
        if (ok){
          if (c==lo2) v2v = 1.0;
          else if (c>lo2) v2v = (tau2==0.0) ? 0.0 : col2[c]*scal2;
        }
        v2c[j] = v2v;
      }
      int r0 = lo + ((g - lo) & (NB-1));
      for (int r = r0 + NB*wave; r < 512; r += 4*NB){
        double* Ar = Arows[r>>5];
        double vr = vv[r], wr = wv[r];
        double p = 0.0;
        #pragma unroll
        for (int j=0;j<8;j++){
          int c = lo + lane + 64*j;
          if (c < 512){
            double an = Ar[c] - vr*wvc[j] - wr*vvc[j];
            Ar[c] = an;
            p += an * v2c[j];
            if (c == lo2) AST(&colW[r], an);
          }
        }
        #pragma unroll
        for (int off=32; off; off>>=1) p += __shfl_down(p, off, 64);
        if (lane==0) AST(&accW[r], p);
      }
    }
    __syncthreads();
    // vv <- v2 (in place) ; distributed V write (owned rows)
    for (int r=t; r<512; r+=256){
      double v = 0.0;
      if (r==lo2) v = 1.0;
      else if (r>lo2) v = (tau2==0.0) ? 0.0 : col2[r]*scal2;
      vv[r]=v;
      if (r>=lo2 && (r & (NB-1))==g) V[(size_t)lo*512 + r] = v;
    }
    tauv = tau2;
  }
  // diag from owned rows (LDS-resident)
  if (t < 16){
    int r = 32*t + g;
    d[r] = Arows[t][r];
  }
}

// sstedc-style pre-scale: org = max(|d|,|e|); d,e /= org
__global__ void k_scale(double* smalls, int sbase){
  int sg = sbase + blockIdx.x, t = threadIdx.x;
  double* d = smalls + (size_t)sg*512;
  double* e = smalls + 4096 + (size_t)sg*512;
  __shared__ double red[256];
  double m = 0.0;
  for (int i=t;i<512;i+=256) m = fmax(m, fabs(d[i]));
  for (int i=t;i<511;i+=256) m = fmax(m, fabs(e[i]));
  red[t]=m; __syncthreads();
  for (int off=128; off; off>>=1){ if (t<off) red[t]=fmax(red[t],red[t+off]); __syncthreads(); }
  double org = red[0]; if (org == 0.0) org = 1.0;
  if (t==0) smalls[12288+sg] = org;
  double inv = 1.0/org;
  __syncthreads();
  for (int i=t;i<512;i+=256) d[i] *= inv;
  for (int i=t;i<511;i+=256) e[i] *= inv;
}

__global__ void k_tear(double* smalls, int sbase){
  int t = threadIdx.x;           // 128 threads: s = t>>5, k = (t&31)+1
  int sg = sbase + (t >> 5), k = (t & 31) + 1;
  if (k <= 31){
    double* d = smalls + (size_t)sg*512;
    double* e = smalls + 4096 + (size_t)sg*512;
    double ae = fabs(e[16*k - 1]);
    d[16*k - 1] -= ae;
    d[16*k]     -= ae;
  }
}

// 32 leaves of 16 per matrix; 8 leaves per block, threads 0..7 active
__global__ __launch_bounds__(64) void k_leaves(double* smalls, double* Zb, int sbase){
  __shared__ double LA[8][256];
  __shared__ double LQ[8][256];
  int t = threadIdx.x;
  if (t < 8){
    int bid = blockIdx.x;        // 0..15
    int s_local = bid >> 2;
    int sg = sbase + s_local;
    int leaf = (bid & 3)*8 + t;  // 0..31
    double* d = smalls + (size_t)sg*512;
    double* e = smalls + 4096 + (size_t)sg*512;
    double* Z = Zb + (size_t)s_local*MATSZ;
    int base = leaf*16;
    double* A = LA[t]; double* Q = LQ[t];
    for (int i=0;i<256;i++){ A[i]=0.0; Q[i]=0.0; }
    for (int i=0;i<16;i++){ A[i*17] = d[base+i]; Q[i*17] = 1.0; }
    for (int i=0;i<15;i++){ double ee = e[base+i]; A[i*16+i+1] = ee; A[(i+1)*16+i] = ee; }
    double nrm = 0.0;
    for (int i=0;i<256;i++) nrm += A[i]*A[i];
    double thr = nrm*1e-30 + 1e-300;
    for (int sweep=0; sweep<60; sweep++){
      double off = 0.0;
      for (int p=0;p<15;p++) for (int q=p+1;q<16;q++){
        double apq = A[p*16+q];
        off += 2.0*apq*apq;
        if (apq == 0.0) continue;
        double theta = 0.5*(A[q*17]-A[p*17])/apq;
        double tt;
        if (fabs(theta) > 1e18) tt = 0.5/theta;
        else tt = copysign(1.0, theta)/(fabs(theta)+sqrt(theta*theta+1.0));
        double cc = 1.0/sqrt(tt*tt+1.0), ss = tt*cc;
        for (int k=0;k<16;k++){
          double akp=A[k*16+p], akq=A[k*16+q];
          A[k*16+p] = cc*akp - ss*akq;
          A[k*16+q] = ss*akp + cc*akq;
        }
        for (int k=0;k<16;k++){
          double apk=A[p*16+k], aqk=A[q*16+k];
          A[p*16+k] = cc*apk - ss*aqk;
          A[q*16+k] = ss*apk + cc*aqk;
        }
        for (int k=0;k<16;k++){
          double qkp=Q[k*16+p], qkq=Q[k*16+q];
          Q[k*16+p] = cc*qkp - ss*qkq;
          Q[k*16+q] = ss*qkp + cc*qkq;
        }
      }
      if (off < thr) break;
    }
    for (int i=0;i<16;i++){
      int mi=i;
      for (int j=i+1;j<16;j++) if (A[j*17] < A[mi*17]) mi=j;
      if (mi!=i){
        double tmp=A[i*17]; A[i*17]=A[mi*17]; A[mi*17]=tmp;
        for (int k=0;k<16;k++){ double q1=Q[k*16+i]; Q[k*16+i]=Q[k*16+mi]; Q[k*16+mi]=q1; }
      }
    }
    for (int i=0;i<16;i++) d[base+i] = A[i*17];
    for (int r=0;r<16;r++)
      for (int c=0;c<16;c++)
        Z[(size_t)(base+r)*512 + base + c] = Q[r*16+c];
  }
}

// one block per merge: LAPACK slaed2 deflation + secular solve + Gu-Eisenstat
__global__ __launch_bounds__(256) void k_secular(double* smalls, const double* Zsrc_b,
                                                 double* Sm_b, int level, int sbase){
  const double EPS32 = 5.9604644775390625e-8;   // SLAMCH('E') for f32
  const double ISQ2  = 0.70710678118654752440;
  int s_local = blockIdx.x;
  int sg = sbase + s_local;
  int hh = 16 << level, n = hh << 1;
  int merge = blockIdx.y, start = merge*n;
  double* d = smalls + (size_t)sg*512;
  const double* e = smalls + 4096 + (size_t)sg*512;
  const double* Z = Zsrc_b + (size_t)s_local*MATSZ;
  double* Sm = Sm_b + (size_t)s_local*MATSZ;
  double* rotg = smalls + 12544 + (size_t)(sg*32+merge)*1024;
  __shared__ double ds[512], zl[512], dk[512], zk[512], tauk[512], zh[512], outlam[512];
  __shared__ double rc[256], rs[256];
  __shared__ double red[256];
  __shared__ double sv[2];
  __shared__ int perm[512], kidx[512], Ksk[512], didx[512], outid[512];
  __shared__ int rp[256], rq[256];
  __shared__ int counts[3];
  int t = threadIdx.x;
  if (t == 0){
    int i=0, j=hh, k=0;
    while (i < hh && j < n){
      if (d[start+i] <= d[start+j]) perm[k++]=i++; else perm[k++]=j++;
    }
    while (i < hh) perm[k++]=i++;
    while (j < n)  perm[k++]=j++;
  }
  __syncthreads();
  double eb = e[start+hh-1];
  double rho = 2.0*fabs(eb);
  double sgn = (eb < 0.0) ? -1.0 : 1.0;
  for (int i=t; i<n; i+=NT){
    int p = perm[i];
    ds[i] = d[start+p];
    double zr = (p < hh) ? Z[(size_t)(start+hh-1)*512 + start + p]
                         : sgn * Z[(size_t)(start+hh)*512 + start + p];
    zl[i] = zr * ISQ2;
  }
  __syncthreads();
  double m = 0.0;
  for (int i=t;i<n;i+=NT) m = fmax(m, fabs(zl[i]));
  red[t]=m; __syncthreads();
  for (int off=128; off; off>>=1){ if (t<off) red[t]=fmax(red[t],red[t+off]); __syncthreads(); }
  if (t==0) sv[0] = red[0];
  __syncthreads();
  m = 0.0;
  for (int i=t;i<n;i+=NT) m = fmax(m, fabs(ds[i]));
  red[t]=m; __syncthreads();
  for (int off=128; off; off>>=1){ if (t<off) red[t]=fmax(red[t],red[t+off]); __syncthreads(); }
  if (t==0) sv[1] = red[0];
  __syncthreads();
  double zmaxv = sv[0];
  double tol = 8.0*EPS32*fmax(sv[1], zmaxv);

  if (t == 0){
    int K=0, nd=0, nrot=0;
    if (rho*zmaxv <= tol){
      for (int j=0;j<n;j++) didx[nd++]=j;
    } else {
      int pj = -1;
      for (int j=0;j<n;j++){
        if (rho*fabs(zl[j]) <= tol){
          didx[nd++]=j;
        } else if (pj < 0){
          pj = j;
        } else {
          double s_ = zl[pj], c_ = zl[j];
          double tau2 = sqrt(c_*c_ + s_*s_);
          double tdf = ds[j] - ds[pj];
          double cc = c_/tau2, sr = -s_/tau2;
          if (fabs(tdf*cc*sr) <= tol){
            zl[j] = tau2; zl[pj] = 0.0;
            if (nrot < 256){
              rp[nrot]=perm[pj]; rq[nrot]=perm[j]; rc[nrot]=cc; rs[nrot]=sr; nrot++;
            }
            double tn = ds[pj]*cc*cc + ds[j]*sr*sr;
            ds[j]  = ds[pj]*sr*sr + ds[j]*cc*cc;
            ds[pj] = tn;
            didx[nd++] = pj;
            pj = j;
          } else {
            kidx[K++] = pj;
            pj = j;
          }
        }
      }
      if (pj >= 0) kidx[K++] = pj;
    }
    for (int a=1;a<nd;a++){
      int v = didx[a]; double dv = ds[v]; int b = a-1;
      while (b >= 0 && ds[didx[b]] > dv){ didx[b+1]=didx[b]; b--; }
      didx[b+1] = v;
    }
    counts[0]=K; counts[1]=nd; counts[2]=nrot;
    rotg[0] = (double)nrot;
    for (int i=0;i<nrot;i++){
      rotg[1+4*i]=(double)rp[i]; rotg[2+4*i]=(double)rq[i];
      rotg[3+4*i]=rc[i]; rotg[4+4*i]=rs[i];
    }
  }
  __syncthreads();
  int K = counts[0], nd = counts[1];

  for (int k=t; k<K; k+=NT){ dk[k]=ds[kidx[k]]; zk[k]=zl[kidx[k]]; }
  __syncthreads();

  for (int j2=t; j2<K; j2+=NT){
    int Kb; double lo, hi;
    if (j2 < K-1){
      double mid = 0.5*(dk[j2+1]-dk[j2]);
      double gg = 1.0;
      for (int i=0;i<K;i++){ double dif=(dk[i]-dk[j2])-mid; gg += rho*zk[i]*zk[i]/dif; }
      if (gg >= 0.0){ Kb=j2;   lo=0.0;  hi=mid; }
      else          { Kb=j2+1; lo=-mid; hi=0.0; }
    } else {
      double sz=0.0;
      for (int i=0;i<K;i++) sz += zk[i]*zk[i];
      Kb=K-1; lo=0.0; hi=rho*sz + 1e-300;
    }
    double dK = dk[Kb];
    for (int it=0; it<72; it++){
      double mid = 0.5*(lo+hi);
      if (mid==lo || mid==hi) break;
      double gg = 1.0;
      for (int i=0;i<K;i++){ double dif=(dk[i]-dK)-mid; gg += rho*zk[i]*zk[i]/dif; }
      if (gg < 0.0) lo=mid; else hi=mid;
    }
    Ksk[j2]=Kb; tauk[j2]=0.5*(lo+hi);
  }
  __syncthreads();
  for (int i=t; i<K; i+=NT){
    double P = (Ksk[i]==i) ? tauk[i] : (dk[Ksk[i]]-dk[i]) + tauk[i];
    for (int j=0;j<K;j++){
      if (j==i) continue;
      double num = (dk[Ksk[j]]-dk[i]) + tauk[j];
      double den = dk[j]-dk[i];
      P *= num/den;
    }
    zh[i] = copysign(sqrt(fabs(P/rho)), zk[i]);
  }
  __syncthreads();
  if (t == 0){
    int a=0, b=0;
    for (int j=0;j<n;j++){
      double la = (a<K)  ? (dk[Ksk[a]]+tauk[a]) : 1e300;
      double lb = (b<nd) ? ds[didx[b]]          : 1e300;
      if (la <= lb){ outid[j]=a;     outlam[j]=la; a++; }
      else         { outid[j]=512+b; outlam[j]=lb; b++; }
    }
  }
  __syncthreads();
  for (int j=t; j<n; j+=NT) d[start+j] = outlam[j];
  for (int j=t; j<n; j+=NT){
    double* col = Sm + (size_t)(start+j)*512;
    int id = outid[j];
    for (int i=0;i<n;i++) col[i]=0.0;
    if (id >= 512){
      col[perm[didx[id-512]]] = 1.0;
    } else {
      int k = id;
      double ss_ = 0.0;
      for (int i=0;i<K;i++){
        double dif = (dk[i]-dk[Ksk[k]]) - tauk[k];
        if (dif == 0.0) dif = 1e-300;
        double v = zh[i]/dif;
        col[perm[kidx[i]]] = v; ss_ += v*v;
      }
      double inv = 1.0/sqrt(ss_);
      for (int i=0;i<K;i++) col[perm[kidx[i]]] *= inv;
    }
  }
}

// apply recorded Givens rotations to S rows (reverse order)
__global__ __launch_bounds__(256) void k_rot(double* Sm_b, const double* smalls,
                                             int level, int sbase){
  int s_local = blockIdx.x, merge = blockIdx.y;
  int sg = sbase + s_local;
  int hh = 16 << level, n = hh << 1, start = merge*n;
  const double* rotg = smalls + 12544 + (size_t)(sg*32+merge)*1024;
  double* Sm = Sm_b + (size_t)s_local*MATSZ;
  int cnt = (int)rotg[0];
  for (int i=cnt-1; i>=0; i--){
    int p = (int)rotg[1+4*i], q = (int)rotg[2+4*i];
    double c = rotg[3+4*i], sr = rotg[4+4*i];
    for (int j=threadIdx.x; j<n; j+=256){
      double* col = Sm + (size_t)(start+j)*512;
      double a = col[p], b = col[q];
      col[p] = c*a - sr*b;
      col[q] = sr*a + c*b;
    }
    __syncthreads();
  }
}

// Zdst[merge square] = Zsrc[:,local-cols] * S
__global__ __launch_bounds__(256) void k_gemm64(const double* Zsrc_b, const double* Sm_b,
                                                double* Zdst_b, int level){
  int hh = 16 << level, n = hh << 1;
  int mpm = 512 / n;
  int bz = blockIdx.z;
  int s = bz / mpm, merge = bz % mpm;
  int start = merge*n;
  const double* Zs = Zsrc_b + (size_t)s*MATSZ;
  const double* Sm = Sm_b + (size_t)s*MATSZ;
  double* Zd = Zdst_b + (size_t)s*MATSZ;
  int row0 = start + blockIdx.y*32, col0 = start + blockIdx.x*32;
  int t = threadIdx.x;
  int tr = t >> 4, tc = t & 15;
  __shared__ double As[32][33];
  __shared__ double Bs[32][33];
  double a00=0,a01=0,a10=0,a11=0;
  for (int q0=0; q0<n; q0+=32){
    #pragma unroll
    for (int it=0; it<4; it++){
      int idx = t + it*256;
      int r = idx >> 5, q = idx & 31;
      As[r][q] = Zs[(size_t)(row0+r)*512 + start + q0 + q];
    }
    #pragma unroll
    for (int it=0; it<4; it++){
      int idx = t + it*256;
      int c = idx >> 5, q = idx & 31;
      Bs[q][c] = Sm[(size_t)(col0+c)*512 + q0 + q];
    }
    __syncthreads();
    #pragma unroll 8
    for (int q=0;q<32;q++){
      double ar0=As[tr][q], ar1=As[tr+16][q];
      double bc0=Bs[q][tc], bc1=Bs[q][tc+16];
      a00 = fma(ar0,bc0,a00); a01 = fma(ar0,bc1,a01);
      a10 = fma(ar1,bc0,a10); a11 = fma(ar1,bc1,a11);
    }
    __syncthreads();
  }
  Zd[(size_t)(row0+tr)*512 + col0+tc]       = a00;
  Zd[(size_t)(row0+tr)*512 + col0+tc+16]    = a01;
  Zd[(size_t)(row0+tr+16)*512 + col0+tc]    = a10;
  Zd[(size_t)(row0+tr+16)*512 + col0+tc+16] = a11;
}

// apply Q = H(1)...H(n-1) to Z from the left (reverse reflector order)
__global__ __launch_bounds__(256) void k_backq(double* Z2_b, const double* Vh_b,
                                               const double* smalls, int sbase){
  int s_local = blockIdx.x, cb = blockIdx.y;
  int sg = sbase + s_local;
  double* Z = Z2_b + (size_t)s_local*MATSZ;
  const double* V = Vh_b + (size_t)sg*MATSZ;
  const double* tu = smalls + 8192 + (size_t)sg*512;
  int cg = threadIdx.x >> 5, lane = threadIdx.x & 31;
  int c = cb*8 + cg;
  __shared__ double zc[8][512];
  for (int r=lane; r<512; r+=32) zc[cg][r] = Z[(size_t)r*512 + c];
  for (int i=509; i>=0; i--){
    double tv = tu[i];
    if (tv == 0.0) continue;
    double wp = 0.0;
    for (int r=i+1+lane; r<512; r+=32) wp += V[(size_t)i*512 + r]*zc[cg][r];
    #pragma unroll
    for (int off=16; off; off>>=1) wp += __shfl_down(wp, off, 32);
    double w = __shfl(wp, 0, 32);
    double tw = tv*w;
    for (int r=i+1+lane; r<512; r+=32) zc[cg][r] -= tw*V[(size_t)i*512 + r];
  }
  for (int r=lane; r<512; r+=32) Z[(size_t)r*512 + c] = zc[cg][r];
}

__global__ void k_finalize(const double* Z2_b, const double* smalls,
                           float* Vt_pass, float* eig, int pass, int sbase){
  int s_local = blockIdx.x;
  int sg = sbase + s_local;
  const double* Z = Z2_b + (size_t)s_local*MATSZ;
  double org = smalls[12288+sg];
  int idx = blockIdx.y*256 + threadIdx.x;   // < 262144
  int r = idx >> 9, c = idx & 511;
  Vt_pass[(size_t)s_local*MATSZ + (size_t)c*512 + r] = (float)Z[(size_t)r*512 + c];
  if (idx < 512)
    eig[(size_t)(pass*4+s_local)*512 + idx] = (float)(smalls[(size_t)sg*512 + idx]*org);
}

// --------------------------- diffusion (f32) --------------------------------
struct KArgs {
  const float* Vt;      // speaker Vt32 (4 slots)
  const float* Vt2;     // temporal Vt32 (4 slots)
  float *xspec, *hbuf, *x, *E;
  const float *W1s, *W1t, *W2s, *W2t;
  const float *b2s, *b2t, *wts, *wtt, *b1s, *b1t, *wes, *wet;
  const float *cond, *Wcs, *Wct;
  const float *eig;
  const float *rec, *recW, *recb;
  float* out;
  float t, a, bc;
  unsigned nk0, nk1, nk2, nk3;   // threefry step keys (speaker, temporal)
  int mode;
};

__global__ __launch_bounds__(256) void k_gemm32(KArgs P){
  int t = threadIdx.x;
  int tr = t >> 4, tc = t & 15;
  int bz = blockIdx.z;
  int m0 = blockIdx.y << 6, n0 = blockIdx.x << 6;
  const float *A, *B; float *C;
  int lda, K, chain = 0;
  if (P.mode == 0){
    A = (bz < 4) ? (P.Vt + (size_t)bz*MATSZ) : (P.Vt2 + (size_t)(bz-4)*MATSZ);
    lda = 512; K = 512;
    B = P.x + (size_t)bz*SZF; C = P.xspec + (size_t)bz*SZF;
  } else if (P.mode == 1){
    chain = bz >> 2;
    A = P.xspec + (size_t)bz*SZF; lda = 256; K = 256;
    B = chain ? P.W1t : P.W1s; C = P.hbuf + (size_t)bz*SZF;
  } else if (P.mode == 2){
    chain = bz >> 2;
    A = P.hbuf + (size_t)bz*SZF; lda = 256; K = 256;
    B = chain ? P.W2t : P.W2s; C = P.x + (size_t)bz*SZF;
  } else if (P.mode == 3){
    chain = bz;
    A = P.cond; lda = 256; K = 256;
    B = chain ? P.Wct : P.Wcs; C = P.E + (size_t)chain*4*SZF;
  } else {
    A = P.rec; lda = 256; K = 256;
    B = P.recW; C = P.out;
  }
  __shared__ float As[16][65];
  __shared__ float Bs[16][65];
  float acc[4][4] = {{0}};
  for (int k0=0; k0<K; k0+=16){
    #pragma unroll
    for (int it=0; it<4; it++){
      int idx = t + it*256;
      int r = idx >> 4, kk = idx & 15;
      As[kk][r] = A[(size_t)(m0 + r)*lda + k0 + kk];
    }
    #pragma unroll
    for (int it=0; it<4; it++){
      int idx = t + it*256;
      int c = idx & 63, kk = idx >> 6;
      Bs[kk][c] = B[(size_t)(k0 + kk)*256 + n0 + c];
    }
    __syncthreads();
    #pragma unroll
    for (int kk=0; kk<16; kk++){
      float ar[4], bv[4];
      #pragma unroll
      for (int q=0;q<4;q++){ ar[q] = As[kk][tr + (q<<4)]; bv[q] = Bs[kk][tc + (q<<4)]; }
      #pragma unroll
      for (int q=0;q<4;q++)
        #pragma unroll
        for (int p=0;p<4;p++)
          acc[q][p] = fmaf(ar[q], bv[p], acc[q][p]);
    }
    __syncthreads();
  }
  #pragma unroll
  for (int q=0;q<4;q++){
    #pragma unroll
    for (int p=0;p<4;p++){
      int r = m0 + tr + (q<<4);
      int c = n0 + tc + (p<<4);
      size_t oi = (size_t)r*256 + c;
      float v = acc[q][p];
      if (P.mode == 1){
        v += P.E[(size_t)bz*SZF + oi] + P.t * ((chain ? P.wtt : P.wts)[c]);
        float sg = 1.0f/(1.0f + expf(-v));
        v = v * sg;
      } else if (P.mode == 2){
        float bias = (chain ? P.b2t : P.b2s)[c];
        unsigned j = ((unsigned)(bz & 3))*131072u + (unsigned)oi;
        unsigned kk0 = chain ? P.nk2 : P.nk0;
        unsigned kk1 = chain ? P.nk3 : P.nk1;
        unsigned y0, y1;
        tf2x32(kk0, kk1, 0u, j, &y0, &y1);
        float nz = bits_to_normal(y0 ^ y1);
        v = C[oi] + P.a*(v + bias) + P.bc*nz;
      } else if (P.mode == 3){
        int bb = r >> 9, s2 = r & 511;
        v += (chain ? P.b1t : P.b1s)[c]
           + P.eig[(size_t)(chain*4 + bb)*512 + s2] * ((chain ? P.wet : P.wes)[c]);
      } else if (P.mode == 4){
        v += P.recb[c];
      }
      C[oi] = v;
    }
  }
}

__global__ void k_cond(float* cond, const float* a, const float* v){
  size_t i = (size_t)blockIdx.x*256 + threadIdx.x;
  cond[i] = 0.5f*(a[i] + v[i]);
}

__global__ void k_xinit(float* x, const float* xT){
  size_t i = (size_t)blockIdx.x*256 + threadIdx.x;
  size_t b = i >> 17, off = i & 131071;
  x[i] = xT[((b & 3) << 17) + off];
}

__global__ void k_rec(float* rec, const float* x){
  size_t i = (size_t)blockIdx.x*256 + threadIdx.x;
  rec[i] = 0.5f*(x[i] + x[i + 524288]);
}

__global__ void k_copy(float* out, const float* a, const float* v){
  size_t i = (size_t)blockIdx.x*256 + threadIdx.x;
  out[524288 + i] = (i < 524288) ? a[i] : v[i - 524288];
}

// ------------------------------- host --------------------------------------
extern "C" void kernel_launch(void* const* d_in, const int* in_sizes, int n_in,
                              void* d_out, int out_size, void* d_ws, size_t ws_size,
                              hipStream_t stream){
  const float* f_audio   = (const float*)d_in[1];
  const float* f_visual  = (const float*)d_in[2];
  const float* g_speaker = (const float*)d_in[3];
  const float* g_temporal= (const float*)d_in[4];
  const float* x_T       = (const float*)d_in[6];
  const float* tsW1=(const float*)d_in[7],  *tswe=(const float*)d_in[8],
             * tswt=(const float*)d_in[9],  *tsb1=(const float*)d_in[10],
             * tsWc=(const float*)d_in[11], *tsW2=(const float*)d_in[12],
             * tsb2=(const float*)d_in[13];
  const float* ttW1=(const float*)d_in[14], *ttwe=(const float*)d_in[15],
             * ttwt=(const float*)d_in[16], *ttb1=(const float*)d_in[17],
             * ttWc=(const float*)d_in[18], *ttW2=(const float*)d_in[19],
             * ttb2=(const float*)d_in[20];
  const float* recW=(const float*)d_in[21], *recb=(const float*)d_in[22];
  float* out = (float*)d_out;

  const size_t MB = 1ull << 20;
  if (ws_size < 43*MB) return;

  char* ws = (char*)d_ws;
  double* Vh     = (double*)(ws + 0);        // 8 slots, 16 MB
  double* A64    = (double*)(ws + 16*MB);
  double* Zb     = (double*)(ws + 24*MB);
  double* Sm     = (double*)(ws + 32*MB);
  double* smalls = (double*)(ws + 40*MB);
  unsigned* slots = (unsigned*)(smalls + 291072);
  float* Vt32_s  = (float*)(ws + 0);         // overlays V slots 0-1 (pass0)
  float* Vt32_t  = (float*)(ws + 8*MB);      // overlays V slots 4-5 (pass1)
  float* eig32   = (float*)(ws + 42*MB + 512*1024);
  // diffusion overlay (dead A64/Zb region after eigh)
  float* cond  = (float*)(ws + 16*MB);
  float* E     = (float*)(ws + 18*MB);
  float* xall  = (float*)(ws + 22*MB);
  float* xspec = (float*)(ws + 26*MB);
  float* hbuf  = (float*)(ws + 30*MB);

  // ---- jax.random key schedule (host, exact threefry, PARTITIONABLE) ----
  unsigned f0, f1;
  tf2x32(0u, 42u, 0u, 0u, &f0, &f1);                 // fold_in(key(42), 0)
  unsigned s0,s1,t0,t1;
  tf2x32(f0, f1, 0u, 0u, &s0, &s1);                  // k_s = split[0]
  tf2x32(f0, f1, 0u, 1u, &t0, &t1);                  // k_t = split[1]
  unsigned skeys[100][2], tkeys[100][2];
  for (int k=0; k<100; k++){
    tf2x32(s0, s1, 0u, (unsigned)k, &skeys[k][0], &skeys[k][1]);
    tf2x32(t0, t1, 0u, (unsigned)k, &tkeys[k][0], &tkeys[k][1]);
  }

  hipMemsetAsync(slots, 0, 16384, stream);

  // ---- eigh: all 8 matrices tridiagonalized concurrently (256 blocks) ----
  k_sytd2_lds<<<8*NB, 256, 0, stream>>>(g_speaker, g_temporal, Vh, smalls, slots);

  for (int pass=0; pass<2; pass++){
    int sbase = 4*pass;
    k_scale<<<4, 256, 0, stream>>>(smalls, sbase);
    hipMemsetAsync(Zb, 0, 8*MB, stream);
    hipMemsetAsync(A64, 0, 8*MB, stream);
    k_tear<<<1, 128, 0, stream>>>(smalls, sbase);
    k_leaves<<<16, 64, 0, stream>>>(smalls, Zb, sbase);
    for (int level=0; level<5; level++){
      int n = 32 << level, mpm = 512/n;
      double* src = (level & 1) ? A64 : Zb;
      double* dst = (level & 1) ? Zb  : A64;
      k_secular<<<dim3(4, mpm), 256, 0, stream>>>(smalls, src, Sm, level, sbase);
      k_rot<<<dim3(4, mpm), 256, 0, stream>>>(Sm, smalls, level, sbase);
      k_gemm64<<<dim3(n/32, n/32, 4*mpm), 256, 0, stream>>>(src, Sm, dst, level);
    }
    k_backq<<<dim3(4, 64), 256, 0, stream>>>(A64, Vh, smalls, sbase);
    k_finalize<<<dim3(4, 1024), 256, 0, stream>>>(A64, smalls,
                                                  pass ? Vt32_t : Vt32_s,
                                                  eig32, pass, sbase);
  }

  // ---- diffusion ----
  k_cond<<<2048, 256, 0, stream>>>(cond, f_audio, f_visual);
  k_xinit<<<4096, 256, 0, stream>>>(xall, x_T);

  KArgs P;
  P.Vt = Vt32_s; P.Vt2 = Vt32_t;
  P.xspec = xspec; P.hbuf = hbuf; P.x = xall; P.E = E;
  P.W1s = tsW1; P.W1t = ttW1; P.W2s = tsW2; P.W2t = ttW2;
  P.b2s = tsb2; P.b2t = ttb2; P.wts = tswt; P.wtt = ttwt;
  P.b1s = tsb1; P.b1t = ttb1; P.wes = tswe; P.wet = ttwe;
  P.cond = cond; P.Wcs = tsWc; P.Wct = ttWc;
  P.eig = eig32; P.rec = xspec; P.recW = recW; P.recb = recb; P.out = out;
  P.t = 0.f; P.a = 0.f; P.bc = 0.f;
  P.nk0 = 0; P.nk1 = 0; P.nk2 = 0; P.nk3 = 0;

  P.mode = 3;
  k_gemm32<<<dim3(4, 32, 2), 256, 0, stream>>>(P);

  for (int k=0; k<100; k++){
    float tf = (float)(1.0 - (double)k/99.0);
    float av = (float)(pow(25.0, 2.0*(double)tf) * 0.01);
    float bcv = (float)(pow(25.0, (double)tf) * 0.1);
    P.nk0 = skeys[k][0]; P.nk1 = skeys[k][1];
    P.nk2 = tkeys[k][0]; P.nk3 = tkeys[k][1];
    P.mode = 0;
    k_gemm32<<<dim3(4, 8, 8), 256, 0, stream>>>(P);
    P.mode = 1; P.t = tf;
    k_gemm32<<<dim3(4, 8, 8), 256, 0, stream>>>(P);
    P.mode = 2; P.a = av; P.bc = bcv;
    k_gemm32<<<dim3(4, 8, 8), 256, 0, stream>>>(P);
  }

  k_rec<<<2048, 256, 0, stream>>>(xspec, xall);
  P.mode = 4; P.rec = xspec;
  k_gemm32<<<dim3(4, 32, 1), 256, 0, stream>>>(P);
  k_copy<<<4096, 256, 0, stream>>>(out, f_audio, f_visual);
}